// Round 4
// baseline (664.561 us; speedup 1.0000x reference)
//
#include <hip/hip_runtime.h>
#include <cstddef>
#include <cstdint>

#define BB 4
#define NN 6144
#define DD 64
#define HID 512
#define OUTD 64
#define CAP 512

typedef unsigned long long ull;
typedef unsigned int u32;
typedef unsigned short u16;
typedef __attribute__((ext_vector_type(8))) short short8_t;
typedef __attribute__((ext_vector_type(4))) float floatx4;
typedef __attribute__((ext_vector_type(4))) unsigned short ushort4_t;

// ---- ws layout (byte offsets) ----
#define OFF_ROWFIN 0
#define OFF_COLFIN 196608
#define OFF_WT     393216
#define OFF_F1T    2162688
#define OFF_F2T    5308416
#define OFF_RBM    8454144
#define OFF_CBM    10813440
#define OFF_CNTR   13172736
#define OFF_CNTC   13173504
#define OFF_LISTR  13174272
#define OFF_LISTC  13567488

#define WT1_OFF 0
#define WT2_OFF 65536
#define WT3_OFF 327680
#define WT4_OFF 589824
#define WT5_OFF 851968
#define WT_TOTAL 884736

__device__ __forceinline__ unsigned int fkey(float v) {
    unsigned int u = __float_as_uint(v);
    return (u & 0x80000000u) ? ~u : (u | 0x80000000u);
}

__device__ __forceinline__ float inv16(u32 k16) {
    u32 u = k16 << 16;
    return (u & 0x80000000u) ? __uint_as_float(u & 0x7fffffffu)
                             : __uint_as_float(~u);
}

__device__ __forceinline__ u16 f2bf(float f) {
    unsigned int u = __float_as_uint(f);
    u += 0x7FFFu + ((u >> 16) & 1u);
    return (u16)(u >> 16);
}

__global__ void init_ws_kernel(ull* finals, int* cnts) {
    int i = blockIdx.x * blockDim.x + threadIdx.x;
    if (i < 2 * BB * NN) finals[i] = 0ULL;
    if (i < 384) cnts[i] = 0;
}

// ---- weights fp32 -> bf16, MFMA-fragment-tiled (proven layout from r2) ----
__global__ __launch_bounds__(256) void convert_wt_kernel(
    const float* __restrict__ w1, const float* __restrict__ w2,
    const float* __restrict__ w3, const float* __restrict__ w4,
    const float* __restrict__ w5, u16* __restrict__ wt)
{
    int idx = blockIdx.x * 256 + threadIdx.x;
    if (idx >= WT_TOTAL) return;
    const float* w; u16* o; int K, nsh, li;
    if (idx < 65536)        { w = w1; o = wt + WT1_OFF; K = 128; nsh = 9; li = idx; }
    else if (idx < 327680)  { w = w2; o = wt + WT2_OFF; K = 512; nsh = 9; li = idx - 65536; }
    else if (idx < 589824)  { w = w3; o = wt + WT3_OFF; K = 512; nsh = 9; li = idx - 327680; }
    else if (idx < 851968)  { w = w4; o = wt + WT4_OFF; K = 512; nsh = 9; li = idx - 589824; }
    else                    { w = w5; o = wt + WT5_OFF; K = 512; nsh = 6; li = idx - 851968; }
    int k = li >> nsh;
    int n = li & ((1 << nsh) - 1);
    u16 v = f2bf(w[li]);
    int lane = (n & 15) | (((k >> 3) & 3) << 4);
    o[(((n >> 4) * (K >> 5) + (k >> 5)) * 64 + lane) * 8 + (k & 7)] = v;
}

// ---- feats fp32 -> bf16 fragment-tiled: per 128-row tile of 8192 elems ----
__global__ __launch_bounds__(256) void convert_f_kernel(
    const float* __restrict__ f1, const float* __restrict__ f2,
    u16* __restrict__ f1t, u16* __restrict__ f2t)
{
    int idx = blockIdx.x * 256 + threadIdx.x;
    const int TE = BB * NN * DD;
    const float* src; u16* dst; int e;
    if (idx < TE) { src = f1; dst = f1t; e = idx; }
    else          { src = f2; dst = f2t; e = idx - TE; }
    int k  = e & 63;
    int rn = e >> 6;
    int b  = rn / NN;
    int r  = rn - b * NN;
    int R  = r >> 7, rb = (r >> 4) & 7;
    int kb = k >> 5, lane = (r & 15) | (((k >> 3) & 3) << 4), j = k & 7;
    dst[(size_t)(b * 48 + R) * 8192 + ((rb * 2 + kb) * 64 + lane) * 8 + j] = f2bf(src[e]);
}

// ---- Kernel A: bf16 MFMA sim, 128x256 tile, block maxima -> rbm/cbm ----
__global__ __launch_bounds__(256, 2) void simb_kernel(
    const u16* __restrict__ f1t, const u16* __restrict__ f2t,
    u16* __restrict__ rbm, u16* __restrict__ cbm)
{
    __shared__ __align__(16) u16 sA[8192];
    __shared__ __align__(16) u16 sB[16384];
    __shared__ float cv[2][2][128];
    const int R = blockIdx.x, C2 = blockIdx.y, b = blockIdx.z;
    const int t = threadIdx.x, lane = t & 63, w = t >> 6;
    const int wr = w >> 1, wc = w & 1;
    const int l15 = lane & 15, l4 = lane >> 4;

    const u16* Ag = f1t + (size_t)(b * 48 + R) * 8192;
    const u16* Bg = f2t + (size_t)(b * 48 + C2 * 2) * 8192;  // two contiguous tiles

    #pragma unroll
    for (int rnd = 0; rnd < 4; ++rnd) {
        int c = rnd * 256 + t;
        *reinterpret_cast<uint4*>(&sA[c * 8]) = *reinterpret_cast<const uint4*>(Ag + c * 8);
    }
    #pragma unroll
    for (int rnd = 0; rnd < 8; ++rnd) {
        int c = rnd * 256 + t;
        *reinterpret_cast<uint4*>(&sB[c * 8]) = *reinterpret_cast<const uint4*>(Bg + c * 8);
    }
    __syncthreads();

    floatx4 acc[4][8];
    #pragma unroll
    for (int i = 0; i < 4; ++i)
        #pragma unroll
        for (int j = 0; j < 8; ++j) acc[i][j] = (floatx4)(0.0f);

    #pragma unroll
    for (int kb = 0; kb < 2; ++kb) {
        short8_t afr[4], bfr[8];
        #pragma unroll
        for (int i = 0; i < 4; ++i)
            afr[i] = *reinterpret_cast<const short8_t*>(
                &sA[(((wr * 4 + i) * 2 + kb) * 64 + lane) * 8]);
        #pragma unroll
        for (int j = 0; j < 8; ++j) {
            int cb = wc * 8 + j;
            bfr[j] = *reinterpret_cast<const short8_t*>(
                &sB[(cb >> 3) * 8192 + (((cb & 7) * 2 + kb) * 64 + lane) * 8]);
        }
        #pragma unroll
        for (int i = 0; i < 4; ++i)
            #pragma unroll
            for (int j = 0; j < 8; ++j)
                acc[i][j] = __builtin_amdgcn_mfma_f32_16x16x32_bf16(
                    afr[i], bfr[j], acc[i][j], 0, 0, 0);
    }

    // per-row max over this wave's 128 cols (one 128-col block: C = C2*2+wc)
    const int Cme = C2 * 2 + wc;
    #pragma unroll
    for (int i = 0; i < 4; ++i) {
        #pragma unroll
        for (int reg = 0; reg < 4; ++reg) {
            float v = acc[i][0][reg];
            #pragma unroll
            for (int j = 1; j < 8; ++j) v = fmaxf(v, acc[i][j][reg]);
            v = fmaxf(v, __shfl_xor(v, 1));
            v = fmaxf(v, __shfl_xor(v, 2));
            v = fmaxf(v, __shfl_xor(v, 4));
            v = fmaxf(v, __shfl_xor(v, 8));
            if (l15 == 0) {
                int row = R * 128 + wr * 64 + i * 16 + l4 * 4 + reg;
                rbm[((size_t)b * NN + row) * 48 + Cme] = (u16)(fkey(v) >> 16);
            }
        }
    }

    // per-col max: wave-local (64 rows) then merge the two wr-waves via LDS
    #pragma unroll
    for (int j = 0; j < 8; ++j) {
        float v = acc[0][j][0];
        #pragma unroll
        for (int i = 0; i < 4; ++i)
            #pragma unroll
            for (int reg = 0; reg < 4; ++reg) v = fmaxf(v, acc[i][j][reg]);
        v = fmaxf(v, __shfl_xor(v, 16));
        v = fmaxf(v, __shfl_xor(v, 32));
        if (l4 == 0) cv[wc][wr][j * 16 + l15] = v;
    }
    __syncthreads();
    {
        int wcc = t >> 7, col0 = t & 127;
        float v = fmaxf(cv[wcc][0][col0], cv[wcc][1][col0]);
        int col = C2 * 256 + wcc * 128 + col0;
        cbm[((size_t)b * NN + col) * 48 + R] = (u16)(fkey(v) >> 16);
    }
}

// ---- scan: per (b,n) find block-max, append candidate blocks within margin ----
__global__ __launch_bounds__(256) void scan_kernel(
    const u16* __restrict__ bm, int* __restrict__ cnt, int* __restrict__ list)
{
    int idx = blockIdx.x * 256 + threadIdx.x;
    if (idx >= BB * NN) return;
    int b = idx / NN;
    int n = idx - b * NN;
    u16 ks[48];
    const uint4* p4 = reinterpret_cast<const uint4*>(bm + (size_t)idx * 48);
    #pragma unroll
    for (int q = 0; q < 6; ++q) {
        uint4 u = p4[q];
        ks[q * 8 + 0] = (u16)(u.x & 0xffff); ks[q * 8 + 1] = (u16)(u.x >> 16);
        ks[q * 8 + 2] = (u16)(u.y & 0xffff); ks[q * 8 + 3] = (u16)(u.y >> 16);
        ks[q * 8 + 4] = (u16)(u.z & 0xffff); ks[q * 8 + 5] = (u16)(u.z >> 16);
        ks[q * 8 + 6] = (u16)(u.w & 0xffff); ks[q * 8 + 7] = (u16)(u.w >> 16);
    }
    u16 mx = 0;
    #pragma unroll
    for (int c = 0; c < 48; ++c) mx = ks[c] > mx ? ks[c] : mx;
    float thr = inv16(mx) - 0.024f;   // >= 1.5x worst-case bf16 error bound
    #pragma unroll
    for (int c = 0; c < 48; ++c) {
        if (inv16((u32)ks[c] + 1) >= thr) {
            int pos = atomicAdd(&cnt[b * 48 + c], 1);
            if (pos < CAP) list[(b * 48 + c) * CAP + pos] = n;
        }
    }
}

// ---- exact fp32 refine over candidate (query, 128-target-block) pairs ----
__global__ __launch_bounds__(256, 2) void refine_kernel(
    const float* __restrict__ qfeat, const float* __restrict__ tfeat,
    const int* __restrict__ cnt, const int* __restrict__ list,
    ull* __restrict__ fin)
{
    const int b = blockIdx.x / 48;
    const int C = blockIdx.x - b * 48;
    int n_items = cnt[b * 48 + C];
    if (n_items > CAP) n_items = CAP;
    if (n_items == 0) return;
    __shared__ float s2f[128 * 68];
    const int t = threadIdx.x;
    const float* tb = tfeat + ((size_t)b * NN + C * 128) * 64;
    #pragma unroll
    for (int p = 0; p < 8; ++p) {
        int idx = p * 256 + t;
        int row = idx >> 4, c4 = idx & 15;
        *reinterpret_cast<float4*>(&s2f[row * 68 + c4 * 4]) =
            *reinterpret_cast<const float4*>(tb + row * 64 + c4 * 4);
    }
    __syncthreads();
    const int rs = t >> 4, cg = t & 15;
    const int* mylist = list + (b * 48 + C) * CAP;
    for (int base = 0; base < n_items; base += 16) {
        int li = base + rs;
        bool valid = li < n_items;
        int n = valid ? mylist[li] : 0;
        const float* q = qfeat + ((size_t)b * NN + n) * 64;
        float dot[8];
        #pragma unroll
        for (int c8 = 0; c8 < 8; ++c8) dot[c8] = 0.0f;
        #pragma unroll 4
        for (int kq = 0; kq < 16; ++kq) {
            float4 a4 = *reinterpret_cast<const float4*>(q + kq * 4);
            #pragma unroll
            for (int c8 = 0; c8 < 8; ++c8) {
                float4 s4 = *reinterpret_cast<const float4*>(&s2f[(cg + 16 * c8) * 68 + kq * 4]);
                dot[c8] = fmaf(a4.x, s4.x, dot[c8]);
                dot[c8] = fmaf(a4.y, s4.y, dot[c8]);
                dot[c8] = fmaf(a4.z, s4.z, dot[c8]);
                dot[c8] = fmaf(a4.w, s4.w, dot[c8]);
            }
        }
        float bv = dot[0]; int bc = cg;
        #pragma unroll
        for (int c8 = 1; c8 < 8; ++c8) {
            if (dot[c8] > bv) { bv = dot[c8]; bc = cg + 16 * c8; }
        }
        ull pk = ((ull)fkey(bv) << 32) | (u32)(~(u32)(C * 128 + bc));
        ull qq;
        qq = __shfl_xor(pk, 1); pk = pk > qq ? pk : qq;
        qq = __shfl_xor(pk, 2); pk = pk > qq ? pk : qq;
        qq = __shfl_xor(pk, 4); pk = pk > qq ? pk : qq;
        qq = __shfl_xor(pk, 8); pk = pk > qq ? pk : qq;
        if (cg == 0 && valid) atomicMax(&fin[(size_t)b * NN + n], pk);
    }
}

// ---- Kernel B: bf16 MFMA MLP (unchanged from r2, passed) ----
template<int K>
__device__ __forceinline__ void mlp_layer(
    u16* act, const u16* __restrict__ wt,
    const float* __restrict__ bias, int lane, int wid)
{
    floatx4 acc[8][4];
    #pragma unroll
    for (int ia = 0; ia < 8; ++ia)
        #pragma unroll
        for (int jb = 0; jb < 4; ++jb)
            acc[ia][jb] = (floatx4)(0.0f);

    const int l15 = lane & 15, l4 = lane >> 4;
    const int chBlk0 = wid * 8;

    #pragma unroll 2
    for (int kb = 0; kb < K / 32; ++kb) {
        short8_t bfr[4];
        #pragma unroll
        for (int jb = 0; jb < 4; ++jb) {
            int pt = jb * 16 + l15;
            int chk = (kb * 4 + l4) ^ (pt & 7);
            bfr[jb] = *reinterpret_cast<const short8_t*>(act + (pt * 64 + chk) * 8);
        }
        short8_t afr[8];
        #pragma unroll
        for (int ia = 0; ia < 8; ++ia)
            afr[ia] = *reinterpret_cast<const short8_t*>(
                wt + (((chBlk0 + ia) * (K / 32) + kb) * 64 + lane) * 8);
        #pragma unroll
        for (int ia = 0; ia < 8; ++ia)
            #pragma unroll
            for (int jb = 0; jb < 4; ++jb)
                acc[ia][jb] = __builtin_amdgcn_mfma_f32_16x16x32_bf16(
                    afr[ia], bfr[jb], acc[ia][jb], 0, 0, 0);
    }
    __syncthreads();

    const int ch0 = wid * 128;
    #pragma unroll
    for (int ia = 0; ia < 8; ++ia) {
        int cb = ia * 16 + l4 * 4;
        float4 bv = *reinterpret_cast<const float4*>(bias + ch0 + cb);
        #pragma unroll
        for (int jb = 0; jb < 4; ++jb) {
            int pt = jb * 16 + l15;
            ushort4_t h;
            h[0] = f2bf(fmaxf(acc[ia][jb][0] + bv.x, 0.0f));
            h[1] = f2bf(fmaxf(acc[ia][jb][1] + bv.y, 0.0f));
            h[2] = f2bf(fmaxf(acc[ia][jb][2] + bv.z, 0.0f));
            h[3] = f2bf(fmaxf(acc[ia][jb][3] + bv.w, 0.0f));
            int chk = ((ch0 + cb) >> 3) ^ (pt & 7);
            *reinterpret_cast<ushort4_t*>(act + (pt * 64 + chk) * 8 + (cb & 7)) = h;
        }
    }
    __syncthreads();
}

__global__ __launch_bounds__(256, 2) void mlp_mfma_kernel(
    const float* __restrict__ f1, const float* __restrict__ f2,
    const float* __restrict__ kps1, const float* __restrict__ kps2,
    const float* __restrict__ scales1,
    const float* __restrict__ b1, const float* __restrict__ b2,
    const float* __restrict__ b3, const float* __restrict__ b4,
    const float* __restrict__ b5,
    const u16* __restrict__ wt,
    const ull* __restrict__ rowfin, const ull* __restrict__ colfin,
    float* __restrict__ out)
{
    __shared__ __align__(16) unsigned char lds_raw[65536];
    u16* act = reinterpret_cast<u16*>(lds_raw);
    float* logf = reinterpret_cast<float*>(lds_raw);

    const int t = threadIdx.x;
    const int lane = t & 63, wid = t >> 6;
    const int base = blockIdx.x * 64;
    const int b = base / NN;
    const int n0 = base % NN;

    {
        const int pt = t & 63, seg = t >> 6;
        const int n = n0 + pt;
        ull rm = rowfin[(size_t)b * NN + n];
        const int m = (int)(~(unsigned int)(rm & 0xffffffffULL));
        const float* src = (seg < 2)
            ? (f1 + ((size_t)b * NN + n) * DD + (seg & 1) * 32)
            : (f2 + ((size_t)b * NN + m) * DD + (seg & 1) * 32);
        #pragma unroll
        for (int q = 0; q < 4; ++q) {
            float4 v0 = *reinterpret_cast<const float4*>(src + q * 8);
            float4 v1 = *reinterpret_cast<const float4*>(src + q * 8 + 4);
            short8_t h;
            h[0] = (short)f2bf(v0.x); h[1] = (short)f2bf(v0.y);
            h[2] = (short)f2bf(v0.z); h[3] = (short)f2bf(v0.w);
            h[4] = (short)f2bf(v1.x); h[5] = (short)f2bf(v1.y);
            h[6] = (short)f2bf(v1.z); h[7] = (short)f2bf(v1.w);
            int chk = (seg * 4 + q) ^ (pt & 7);
            *reinterpret_cast<short8_t*>(act + (pt * 64 + chk) * 8) = h;
        }
    }
    __syncthreads();

    mlp_layer<128>(act, wt + WT1_OFF, b1, lane, wid);
    mlp_layer<512>(act, wt + WT2_OFF, b2, lane, wid);
    mlp_layer<512>(act, wt + WT3_OFF, b3, lane, wid);
    mlp_layer<512>(act, wt + WT4_OFF, b4, lane, wid);

    {
        const int l15 = lane & 15, l4 = lane >> 4;
        floatx4 acc5[4];
        #pragma unroll
        for (int jb = 0; jb < 4; ++jb) acc5[jb] = (floatx4)(0.0f);
        #pragma unroll 2
        for (int kb = 0; kb < 16; ++kb) {
            short8_t bfr[4];
            #pragma unroll
            for (int jb = 0; jb < 4; ++jb) {
                int pt = jb * 16 + l15;
                int chk = (kb * 4 + l4) ^ (pt & 7);
                bfr[jb] = *reinterpret_cast<const short8_t*>(act + (pt * 64 + chk) * 8);
            }
            short8_t afr = *reinterpret_cast<const short8_t*>(
                wt + WT5_OFF + ((wid * 16 + kb) * 64 + lane) * 8);
            #pragma unroll
            for (int jb = 0; jb < 4; ++jb)
                acc5[jb] = __builtin_amdgcn_mfma_f32_16x16x32_bf16(
                    afr, bfr[jb], acc5[jb], 0, 0, 0);
        }
        __syncthreads();
        int cb = wid * 16 + l4 * 4;
        float4 bv = *reinterpret_cast<const float4*>(b5 + cb);
        #pragma unroll
        for (int jb = 0; jb < 4; ++jb) {
            int pt = jb * 16 + l15;
            float4 o;
            o.x = acc5[jb][0] + bv.x;
            o.y = acc5[jb][1] + bv.y;
            o.z = acc5[jb][2] + bv.z;
            o.w = acc5[jb][3] + bv.w;
            *reinterpret_cast<float4*>(&logf[pt * 68 + cb]) = o;
        }
        __syncthreads();
    }

    if (t < 64) {
        const int pt = t;
        const int n = n0 + pt;
        const float* lrow = &logf[pt * 68];
        float mx = -1e30f;
        #pragma unroll 8
        for (int j = 0; j < OUTD; ++j) mx = fmaxf(mx, 3.0f * lrow[j]);
        float s = 0.0f, cx = 0.0f, cy = 0.0f;
        #pragma unroll 8
        for (int j = 0; j < OUTD; ++j) {
            float e = __expf(3.0f * lrow[j] - mx);
            s  += e;
            cx += e * (float)((j & 7) - 4);
            cy += e * (float)((j >> 3) - 4);
        }
        float conf = 1.0f / s;
        cx /= s; cy /= s;
        ull rm = rowfin[(size_t)b * NN + n];
        int m = (int)(~(unsigned int)(rm & 0xffffffffULL));
        ull cm = colfin[(size_t)b * NN + m];
        int back = (int)(~(unsigned int)(cm & 0xffffffffULL));
        bool mutual = (back == n);
        float sc = scales1[(size_t)b * NN + n];
        float x0 = kps1[((size_t)b * NN + n) * 2 + 0] + cx * sc;
        float y0 = kps1[((size_t)b * NN + n) * 2 + 1] + cy * sc;
        float x1 = kps2[((size_t)b * NN + m) * 2 + 0];
        float y1 = kps2[((size_t)b * NN + m) * 2 + 1];
        float* mt = out + ((size_t)b * NN + n) * 4;
        mt[0] = x0; mt[1] = y0; mt[2] = x1; mt[3] = y1;
        out[(size_t)BB * NN * 4 + (size_t)b * NN + n] =
            (mutual && conf > 0.25f) ? 1.0f : 0.0f;
    }
}

extern "C" void kernel_launch(void* const* d_in, const int* in_sizes, int n_in,
                              void* d_out, int out_size, void* d_ws, size_t ws_size,
                              hipStream_t stream)
{
    const float* f1  = (const float*)d_in[0];
    const float* f2  = (const float*)d_in[1];
    const float* kp1 = (const float*)d_in[2];
    const float* kp2 = (const float*)d_in[3];
    const float* sc1 = (const float*)d_in[4];
    const float* w1  = (const float*)d_in[5];
    const float* b1  = (const float*)d_in[6];
    const float* w2  = (const float*)d_in[7];
    const float* b2  = (const float*)d_in[8];
    const float* w3  = (const float*)d_in[9];
    const float* b3  = (const float*)d_in[10];
    const float* w4  = (const float*)d_in[11];
    const float* b4  = (const float*)d_in[12];
    const float* w5  = (const float*)d_in[13];
    const float* b5  = (const float*)d_in[14];

    char* ws = (char*)d_ws;
    ull* rowfin = (ull*)(ws + OFF_ROWFIN);
    ull* colfin = (ull*)(ws + OFF_COLFIN);
    u16* wt     = (u16*)(ws + OFF_WT);
    u16* f1t    = (u16*)(ws + OFF_F1T);
    u16* f2t    = (u16*)(ws + OFF_F2T);
    u16* rbm    = (u16*)(ws + OFF_RBM);
    u16* cbm    = (u16*)(ws + OFF_CBM);
    int* cntR   = (int*)(ws + OFF_CNTR);
    int* cntC   = (int*)(ws + OFF_CNTC);
    int* listR  = (int*)(ws + OFF_LISTR);
    int* listC  = (int*)(ws + OFF_LISTC);
    float* out  = (float*)d_out;

    init_ws_kernel<<<(2 * BB * NN + 255) / 256, 256, 0, stream>>>(rowfin, cntR);
    convert_wt_kernel<<<(WT_TOTAL + 255) / 256, 256, 0, stream>>>(w1, w2, w3, w4, w5, wt);
    convert_f_kernel<<<(2 * BB * NN * DD) / 256, 256, 0, stream>>>(f1, f2, f1t, f2t);

    dim3 gS(48, 24, BB);
    simb_kernel<<<gS, 256, 0, stream>>>(f1t, f2t, rbm, cbm);

    scan_kernel<<<(BB * NN) / 256, 256, 0, stream>>>(rbm, cntR, listR);
    scan_kernel<<<(BB * NN) / 256, 256, 0, stream>>>(cbm, cntC, listC);

    refine_kernel<<<BB * 48, 256, 0, stream>>>(f1, f2, cntR, listR, rowfin);
    refine_kernel<<<BB * 48, 256, 0, stream>>>(f2, f1, cntC, listC, colfin);

    mlp_mfma_kernel<<<(BB * NN) / 64, 256, 0, stream>>>(
        f1, f2, kp1, kp2, sc1, b1, b2, b3, b4, b5, wt, rowfin, colfin, out);
}

// Round 5
// 234.551 us; speedup vs baseline: 2.8333x; 2.8333x over previous
//
#include <hip/hip_runtime.h>
#include <cstddef>
#include <cstdint>

#define BB 4
#define NN 6144
#define DD 64
#define HID 512
#define OUTD 64
#define CAP 512
#define RSPLIT 4

typedef unsigned long long ull;
typedef unsigned int u32;
typedef unsigned short u16;
typedef __attribute__((ext_vector_type(8))) short short8_t;
typedef __attribute__((ext_vector_type(4))) float floatx4;
typedef __attribute__((ext_vector_type(4))) unsigned short ushort4_t;

// ---- ws layout (byte offsets) ----
#define OFF_ROWFIN 0
#define OFF_COLFIN 196608
#define OFF_WT     393216
#define OFF_F1T    2162688
#define OFF_F2T    5308416
#define OFF_RBM    8454144
#define OFF_CBM    10813440
#define OFF_CNTR   13172736
#define OFF_CNTC   13173504
#define OFF_LISTR  13174272
#define OFF_LISTC  13567488

#define WT1_OFF 0
#define WT2_OFF 65536
#define WT3_OFF 327680
#define WT4_OFF 589824
#define WT5_OFF 851968
#define WT_TOTAL 884736

__device__ __forceinline__ unsigned int fkey(float v) {
    unsigned int u = __float_as_uint(v);
    return (u & 0x80000000u) ? ~u : (u | 0x80000000u);
}

__device__ __forceinline__ float inv16(u32 k16) {
    u32 u = k16 << 16;
    return (u & 0x80000000u) ? __uint_as_float(u & 0x7fffffffu)
                             : __uint_as_float(~u);
}

__device__ __forceinline__ u16 f2bf(float f) {
    unsigned int u = __float_as_uint(f);
    u += 0x7FFFu + ((u >> 16) & 1u);
    return (u16)(u >> 16);
}

__global__ void init_ws_kernel(ull* finals, int* cnts) {
    int i = blockIdx.x * blockDim.x + threadIdx.x;
    if (i < 2 * BB * NN) finals[i] = 0ULL;
    if (i < 384) cnts[i] = 0;
}

// ---- weights fp32 -> bf16, MFMA-fragment-tiled ----
__global__ __launch_bounds__(256) void convert_wt_kernel(
    const float* __restrict__ w1, const float* __restrict__ w2,
    const float* __restrict__ w3, const float* __restrict__ w4,
    const float* __restrict__ w5, u16* __restrict__ wt)
{
    int idx = blockIdx.x * 256 + threadIdx.x;
    if (idx >= WT_TOTAL) return;
    const float* w; u16* o; int K, nsh, li;
    if (idx < 65536)        { w = w1; o = wt + WT1_OFF; K = 128; nsh = 9; li = idx; }
    else if (idx < 327680)  { w = w2; o = wt + WT2_OFF; K = 512; nsh = 9; li = idx - 65536; }
    else if (idx < 589824)  { w = w3; o = wt + WT3_OFF; K = 512; nsh = 9; li = idx - 327680; }
    else if (idx < 851968)  { w = w4; o = wt + WT4_OFF; K = 512; nsh = 9; li = idx - 589824; }
    else                    { w = w5; o = wt + WT5_OFF; K = 512; nsh = 6; li = idx - 851968; }
    int k = li >> nsh;
    int n = li & ((1 << nsh) - 1);
    u16 v = f2bf(w[li]);
    int lane = (n & 15) | (((k >> 3) & 3) << 4);
    o[(((n >> 4) * (K >> 5) + (k >> 5)) * 64 + lane) * 8 + (k & 7)] = v;
}

// ---- feats fp32 -> bf16 fragment-tiled ----
__global__ __launch_bounds__(256) void convert_f_kernel(
    const float* __restrict__ f1, const float* __restrict__ f2,
    u16* __restrict__ f1t, u16* __restrict__ f2t)
{
    int idx = blockIdx.x * 256 + threadIdx.x;
    const int TE = BB * NN * DD;
    const float* src; u16* dst; int e;
    if (idx < TE) { src = f1; dst = f1t; e = idx; }
    else          { src = f2; dst = f2t; e = idx - TE; }
    int k  = e & 63;
    int rn = e >> 6;
    int b  = rn / NN;
    int r  = rn - b * NN;
    int R  = r >> 7, rb = (r >> 4) & 7;
    int kb = k >> 5, lane = (r & 15) | (((k >> 3) & 3) << 4), j = k & 7;
    dst[(size_t)(b * 48 + R) * 8192 + ((rb * 2 + kb) * 64 + lane) * 8 + j] = f2bf(src[e]);
}

// ---- Kernel A: bf16 MFMA sim, 128x256 tile, block maxima -> rbm/cbm ----
__global__ __launch_bounds__(256, 2) void simb_kernel(
    const u16* __restrict__ f1t, const u16* __restrict__ f2t,
    u16* __restrict__ rbm, u16* __restrict__ cbm)
{
    __shared__ __align__(16) u16 sA[8192];
    __shared__ __align__(16) u16 sB[16384];
    __shared__ float cv[2][2][128];
    const int R = blockIdx.x, C2 = blockIdx.y, b = blockIdx.z;
    const int t = threadIdx.x, lane = t & 63, w = t >> 6;
    const int wr = w >> 1, wc = w & 1;
    const int l15 = lane & 15, l4 = lane >> 4;

    const u16* Ag = f1t + (size_t)(b * 48 + R) * 8192;
    const u16* Bg = f2t + (size_t)(b * 48 + C2 * 2) * 8192;

    #pragma unroll
    for (int rnd = 0; rnd < 4; ++rnd) {
        int c = rnd * 256 + t;
        *reinterpret_cast<uint4*>(&sA[c * 8]) = *reinterpret_cast<const uint4*>(Ag + c * 8);
    }
    #pragma unroll
    for (int rnd = 0; rnd < 8; ++rnd) {
        int c = rnd * 256 + t;
        *reinterpret_cast<uint4*>(&sB[c * 8]) = *reinterpret_cast<const uint4*>(Bg + c * 8);
    }
    __syncthreads();

    floatx4 acc[4][8];
    #pragma unroll
    for (int i = 0; i < 4; ++i)
        #pragma unroll
        for (int j = 0; j < 8; ++j) acc[i][j] = (floatx4)(0.0f);

    #pragma unroll
    for (int kb = 0; kb < 2; ++kb) {
        short8_t afr[4], bfr[8];
        #pragma unroll
        for (int i = 0; i < 4; ++i)
            afr[i] = *reinterpret_cast<const short8_t*>(
                &sA[(((wr * 4 + i) * 2 + kb) * 64 + lane) * 8]);
        #pragma unroll
        for (int j = 0; j < 8; ++j) {
            int cb = wc * 8 + j;
            bfr[j] = *reinterpret_cast<const short8_t*>(
                &sB[(cb >> 3) * 8192 + (((cb & 7) * 2 + kb) * 64 + lane) * 8]);
        }
        #pragma unroll
        for (int i = 0; i < 4; ++i)
            #pragma unroll
            for (int j = 0; j < 8; ++j)
                acc[i][j] = __builtin_amdgcn_mfma_f32_16x16x32_bf16(
                    afr[i], bfr[j], acc[i][j], 0, 0, 0);
    }

    const int Cme = C2 * 2 + wc;
    #pragma unroll
    for (int i = 0; i < 4; ++i) {
        #pragma unroll
        for (int reg = 0; reg < 4; ++reg) {
            float v = acc[i][0][reg];
            #pragma unroll
            for (int j = 1; j < 8; ++j) v = fmaxf(v, acc[i][j][reg]);
            v = fmaxf(v, __shfl_xor(v, 1));
            v = fmaxf(v, __shfl_xor(v, 2));
            v = fmaxf(v, __shfl_xor(v, 4));
            v = fmaxf(v, __shfl_xor(v, 8));
            if (l15 == 0) {
                int row = R * 128 + wr * 64 + i * 16 + l4 * 4 + reg;
                rbm[((size_t)b * NN + row) * 48 + Cme] = (u16)(fkey(v) >> 16);
            }
        }
    }

    #pragma unroll
    for (int j = 0; j < 8; ++j) {
        float v = acc[0][j][0];
        #pragma unroll
        for (int i = 0; i < 4; ++i)
            #pragma unroll
            for (int reg = 0; reg < 4; ++reg) v = fmaxf(v, acc[i][j][reg]);
        v = fmaxf(v, __shfl_xor(v, 16));
        v = fmaxf(v, __shfl_xor(v, 32));
        if (l4 == 0) cv[wc][wr][j * 16 + l15] = v;
    }
    __syncthreads();
    {
        int wcc = t >> 7, col0 = t & 127;
        float v = fmaxf(cv[wcc][0][col0], cv[wcc][1][col0]);
        int col = C2 * 256 + wcc * 128 + col0;
        cbm[((size_t)b * NN + col) * 48 + R] = (u16)(fkey(v) >> 16);
    }
}

// ---- scan: block-aggregated candidate append (LDS atomics + 48 global RMW/block) ----
__global__ __launch_bounds__(256) void scan_kernel(
    const u16* __restrict__ bm, int* __restrict__ cnt, int* __restrict__ list)
{
    __shared__ int lcnt[48];
    __shared__ int lbase[48];
    const int t = threadIdx.x;
    if (t < 48) lcnt[t] = 0;
    const int idx = blockIdx.x * 256 + t;
    const int b = (blockIdx.x * 256) / NN;   // 24 blocks per batch, uniform in block
    const int n = idx - b * NN;

    u16 ks[48];
    const uint4* p4 = reinterpret_cast<const uint4*>(bm + (size_t)idx * 48);
    #pragma unroll
    for (int q = 0; q < 6; ++q) {
        uint4 u = p4[q];
        ks[q * 8 + 0] = (u16)(u.x & 0xffff); ks[q * 8 + 1] = (u16)(u.x >> 16);
        ks[q * 8 + 2] = (u16)(u.y & 0xffff); ks[q * 8 + 3] = (u16)(u.y >> 16);
        ks[q * 8 + 4] = (u16)(u.z & 0xffff); ks[q * 8 + 5] = (u16)(u.z >> 16);
        ks[q * 8 + 6] = (u16)(u.w & 0xffff); ks[q * 8 + 7] = (u16)(u.w >> 16);
    }
    u16 mx = 0;
    #pragma unroll
    for (int c = 0; c < 48; ++c) mx = ks[c] > mx ? ks[c] : mx;
    float thr = inv16(mx) - 0.024f;   // >= 1.5x worst-case bf16 error bound
    u32 m0 = 0, m1 = 0;
    #pragma unroll
    for (int c = 0; c < 48; ++c) {
        if (inv16((u32)ks[c] + 1) >= thr) {
            if (c < 32) m0 |= 1u << c; else m1 |= 1u << (c - 32);
        }
    }
    __syncthreads();
    {
        u32 a = m0;
        while (a) { int c = __builtin_ctz(a); a &= a - 1; atomicAdd(&lcnt[c], 1); }
        a = m1;
        while (a) { int c = 32 + __builtin_ctz(a); a &= a - 1; atomicAdd(&lcnt[c], 1); }
    }
    __syncthreads();
    if (t < 48) { lbase[t] = atomicAdd(&cnt[b * 48 + t], lcnt[t]); lcnt[t] = 0; }
    __syncthreads();
    {
        u32 a = m0;
        while (a) {
            int c = __builtin_ctz(a); a &= a - 1;
            int pos = lbase[c] + atomicAdd(&lcnt[c], 1);
            if (pos < CAP) list[(b * 48 + c) * CAP + pos] = n;
        }
        a = m1;
        while (a) {
            int c = 32 + __builtin_ctz(a); a &= a - 1;
            int pos = lbase[c] + atomicAdd(&lcnt[c], 1);
            if (pos < CAP) list[(b * 48 + c) * CAP + pos] = n;
        }
    }
}

// ---- exact fp32 refine over candidate (query, 128-target-block) pairs ----
__global__ __launch_bounds__(256, 2) void refine_kernel(
    const float* __restrict__ qfeat, const float* __restrict__ tfeat,
    const int* __restrict__ cnt, const int* __restrict__ list,
    ull* __restrict__ fin)
{
    const int b = blockIdx.x / 48;
    const int C = blockIdx.x - b * 48;
    const int sub = blockIdx.y;
    int n_items = cnt[b * 48 + C];
    if (n_items > CAP) n_items = CAP;
    int chunk = (n_items + RSPLIT - 1) / RSPLIT;
    int lo = sub * chunk;
    int hi = lo + chunk; if (hi > n_items) hi = n_items;
    if (lo >= hi) return;

    __shared__ float s2f[128 * 68];
    const int t = threadIdx.x;
    const float* tb = tfeat + ((size_t)b * NN + C * 128) * 64;
    #pragma unroll
    for (int p = 0; p < 8; ++p) {
        int idx = p * 256 + t;
        int row = idx >> 4, c4 = idx & 15;
        *reinterpret_cast<float4*>(&s2f[row * 68 + c4 * 4]) =
            *reinterpret_cast<const float4*>(tb + row * 64 + c4 * 4);
    }
    __syncthreads();
    const int rs = t >> 4, cg = t & 15;
    const int* mylist = list + (b * 48 + C) * CAP;
    for (int base = lo; base < hi; base += 16) {
        int li = base + rs;
        bool valid = li < hi;
        int n = valid ? mylist[li] : mylist[lo];
        const float* q = qfeat + ((size_t)b * NN + n) * 64;
        float dot[8];
        #pragma unroll
        for (int c8 = 0; c8 < 8; ++c8) dot[c8] = 0.0f;
        #pragma unroll 4
        for (int kq = 0; kq < 16; ++kq) {
            float4 a4 = *reinterpret_cast<const float4*>(q + kq * 4);
            #pragma unroll
            for (int c8 = 0; c8 < 8; ++c8) {
                float4 s4 = *reinterpret_cast<const float4*>(&s2f[(cg + 16 * c8) * 68 + kq * 4]);
                dot[c8] = fmaf(a4.x, s4.x, dot[c8]);
                dot[c8] = fmaf(a4.y, s4.y, dot[c8]);
                dot[c8] = fmaf(a4.z, s4.z, dot[c8]);
                dot[c8] = fmaf(a4.w, s4.w, dot[c8]);
            }
        }
        float bv = dot[0]; int bc = cg;
        #pragma unroll
        for (int c8 = 1; c8 < 8; ++c8) {
            if (dot[c8] > bv) { bv = dot[c8]; bc = cg + 16 * c8; }
        }
        ull pk = ((ull)fkey(bv) << 32) | (u32)(~(u32)(C * 128 + bc));
        ull qq;
        qq = __shfl_xor(pk, 1); pk = pk > qq ? pk : qq;
        qq = __shfl_xor(pk, 2); pk = pk > qq ? pk : qq;
        qq = __shfl_xor(pk, 4); pk = pk > qq ? pk : qq;
        qq = __shfl_xor(pk, 8); pk = pk > qq ? pk : qq;
        if (cg == 0 && valid) atomicMax(&fin[(size_t)b * NN + n], pk);
    }
}

// ---- Kernel B: bf16 MFMA MLP (unchanged, passed) ----
template<int K>
__device__ __forceinline__ void mlp_layer(
    u16* act, const u16* __restrict__ wt,
    const float* __restrict__ bias, int lane, int wid)
{
    floatx4 acc[8][4];
    #pragma unroll
    for (int ia = 0; ia < 8; ++ia)
        #pragma unroll
        for (int jb = 0; jb < 4; ++jb)
            acc[ia][jb] = (floatx4)(0.0f);

    const int l15 = lane & 15, l4 = lane >> 4;
    const int chBlk0 = wid * 8;

    #pragma unroll 2
    for (int kb = 0; kb < K / 32; ++kb) {
        short8_t bfr[4];
        #pragma unroll
        for (int jb = 0; jb < 4; ++jb) {
            int pt = jb * 16 + l15;
            int chk = (kb * 4 + l4) ^ (pt & 7);
            bfr[jb] = *reinterpret_cast<const short8_t*>(act + (pt * 64 + chk) * 8);
        }
        short8_t afr[8];
        #pragma unroll
        for (int ia = 0; ia < 8; ++ia)
            afr[ia] = *reinterpret_cast<const short8_t*>(
                wt + (((chBlk0 + ia) * (K / 32) + kb) * 64 + lane) * 8);
        #pragma unroll
        for (int ia = 0; ia < 8; ++ia)
            #pragma unroll
            for (int jb = 0; jb < 4; ++jb)
                acc[ia][jb] = __builtin_amdgcn_mfma_f32_16x16x32_bf16(
                    afr[ia], bfr[jb], acc[ia][jb], 0, 0, 0);
    }
    __syncthreads();

    const int ch0 = wid * 128;
    #pragma unroll
    for (int ia = 0; ia < 8; ++ia) {
        int cb = ia * 16 + l4 * 4;
        float4 bv = *reinterpret_cast<const float4*>(bias + ch0 + cb);
        #pragma unroll
        for (int jb = 0; jb < 4; ++jb) {
            int pt = jb * 16 + l15;
            ushort4_t h;
            h[0] = f2bf(fmaxf(acc[ia][jb][0] + bv.x, 0.0f));
            h[1] = f2bf(fmaxf(acc[ia][jb][1] + bv.y, 0.0f));
            h[2] = f2bf(fmaxf(acc[ia][jb][2] + bv.z, 0.0f));
            h[3] = f2bf(fmaxf(acc[ia][jb][3] + bv.w, 0.0f));
            int chk = ((ch0 + cb) >> 3) ^ (pt & 7);
            *reinterpret_cast<ushort4_t*>(act + (pt * 64 + chk) * 8 + (cb & 7)) = h;
        }
    }
    __syncthreads();
}

__global__ __launch_bounds__(256, 2) void mlp_mfma_kernel(
    const float* __restrict__ f1, const float* __restrict__ f2,
    const float* __restrict__ kps1, const float* __restrict__ kps2,
    const float* __restrict__ scales1,
    const float* __restrict__ b1, const float* __restrict__ b2,
    const float* __restrict__ b3, const float* __restrict__ b4,
    const float* __restrict__ b5,
    const u16* __restrict__ wt,
    const ull* __restrict__ rowfin, const ull* __restrict__ colfin,
    float* __restrict__ out)
{
    __shared__ __align__(16) unsigned char lds_raw[65536];
    u16* act = reinterpret_cast<u16*>(lds_raw);
    float* logf = reinterpret_cast<float*>(lds_raw);

    const int t = threadIdx.x;
    const int lane = t & 63, wid = t >> 6;
    const int base = blockIdx.x * 64;
    const int b = base / NN;
    const int n0 = base % NN;

    {
        const int pt = t & 63, seg = t >> 6;
        const int n = n0 + pt;
        ull rm = rowfin[(size_t)b * NN + n];
        const int m = (int)(~(unsigned int)(rm & 0xffffffffULL));
        const float* src = (seg < 2)
            ? (f1 + ((size_t)b * NN + n) * DD + (seg & 1) * 32)
            : (f2 + ((size_t)b * NN + m) * DD + (seg & 1) * 32);
        #pragma unroll
        for (int q = 0; q < 4; ++q) {
            float4 v0 = *reinterpret_cast<const float4*>(src + q * 8);
            float4 v1 = *reinterpret_cast<const float4*>(src + q * 8 + 4);
            short8_t h;
            h[0] = (short)f2bf(v0.x); h[1] = (short)f2bf(v0.y);
            h[2] = (short)f2bf(v0.z); h[3] = (short)f2bf(v0.w);
            h[4] = (short)f2bf(v1.x); h[5] = (short)f2bf(v1.y);
            h[6] = (short)f2bf(v1.z); h[7] = (short)f2bf(v1.w);
            int chk = (seg * 4 + q) ^ (pt & 7);
            *reinterpret_cast<short8_t*>(act + (pt * 64 + chk) * 8) = h;
        }
    }
    __syncthreads();

    mlp_layer<128>(act, wt + WT1_OFF, b1, lane, wid);
    mlp_layer<512>(act, wt + WT2_OFF, b2, lane, wid);
    mlp_layer<512>(act, wt + WT3_OFF, b3, lane, wid);
    mlp_layer<512>(act, wt + WT4_OFF, b4, lane, wid);

    {
        const int l15 = lane & 15, l4 = lane >> 4;
        floatx4 acc5[4];
        #pragma unroll
        for (int jb = 0; jb < 4; ++jb) acc5[jb] = (floatx4)(0.0f);
        #pragma unroll 2
        for (int kb = 0; kb < 16; ++kb) {
            short8_t bfr[4];
            #pragma unroll
            for (int jb = 0; jb < 4; ++jb) {
                int pt = jb * 16 + l15;
                int chk = (kb * 4 + l4) ^ (pt & 7);
                bfr[jb] = *reinterpret_cast<const short8_t*>(act + (pt * 64 + chk) * 8);
            }
            short8_t afr = *reinterpret_cast<const short8_t*>(
                wt + WT5_OFF + ((wid * 16 + kb) * 64 + lane) * 8);
            #pragma unroll
            for (int jb = 0; jb < 4; ++jb)
                acc5[jb] = __builtin_amdgcn_mfma_f32_16x16x32_bf16(
                    afr, bfr[jb], acc5[jb], 0, 0, 0);
        }
        __syncthreads();
        int cb = wid * 16 + l4 * 4;
        float4 bv = *reinterpret_cast<const float4*>(b5 + cb);
        #pragma unroll
        for (int jb = 0; jb < 4; ++jb) {
            int pt = jb * 16 + l15;
            float4 o;
            o.x = acc5[jb][0] + bv.x;
            o.y = acc5[jb][1] + bv.y;
            o.z = acc5[jb][2] + bv.z;
            o.w = acc5[jb][3] + bv.w;
            *reinterpret_cast<float4*>(&logf[pt * 68 + cb]) = o;
        }
        __syncthreads();
    }

    if (t < 64) {
        const int pt = t;
        const int n = n0 + pt;
        const float* lrow = &logf[pt * 68];
        float mx = -1e30f;
        #pragma unroll 8
        for (int j = 0; j < OUTD; ++j) mx = fmaxf(mx, 3.0f * lrow[j]);
        float s = 0.0f, cx = 0.0f, cy = 0.0f;
        #pragma unroll 8
        for (int j = 0; j < OUTD; ++j) {
            float e = __expf(3.0f * lrow[j] - mx);
            s  += e;
            cx += e * (float)((j & 7) - 4);
            cy += e * (float)((j >> 3) - 4);
        }
        float conf = 1.0f / s;
        cx /= s; cy /= s;
        ull rm = rowfin[(size_t)b * NN + n];
        int m = (int)(~(unsigned int)(rm & 0xffffffffULL));
        ull cm = colfin[(size_t)b * NN + m];
        int back = (int)(~(unsigned int)(cm & 0xffffffffULL));
        bool mutual = (back == n);
        float sc = scales1[(size_t)b * NN + n];
        float x0 = kps1[((size_t)b * NN + n) * 2 + 0] + cx * sc;
        float y0 = kps1[((size_t)b * NN + n) * 2 + 1] + cy * sc;
        float x1 = kps2[((size_t)b * NN + m) * 2 + 0];
        float y1 = kps2[((size_t)b * NN + m) * 2 + 1];
        float* mt = out + ((size_t)b * NN + n) * 4;
        mt[0] = x0; mt[1] = y0; mt[2] = x1; mt[3] = y1;
        out[(size_t)BB * NN * 4 + (size_t)b * NN + n] =
            (mutual && conf > 0.25f) ? 1.0f : 0.0f;
    }
}

extern "C" void kernel_launch(void* const* d_in, const int* in_sizes, int n_in,
                              void* d_out, int out_size, void* d_ws, size_t ws_size,
                              hipStream_t stream)
{
    const float* f1  = (const float*)d_in[0];
    const float* f2  = (const float*)d_in[1];
    const float* kp1 = (const float*)d_in[2];
    const float* kp2 = (const float*)d_in[3];
    const float* sc1 = (const float*)d_in[4];
    const float* w1  = (const float*)d_in[5];
    const float* b1  = (const float*)d_in[6];
    const float* w2  = (const float*)d_in[7];
    const float* b2  = (const float*)d_in[8];
    const float* w3  = (const float*)d_in[9];
    const float* b3  = (const float*)d_in[10];
    const float* w4  = (const float*)d_in[11];
    const float* b4  = (const float*)d_in[12];
    const float* w5  = (const float*)d_in[13];
    const float* b5  = (const float*)d_in[14];

    char* ws = (char*)d_ws;
    ull* rowfin = (ull*)(ws + OFF_ROWFIN);
    ull* colfin = (ull*)(ws + OFF_COLFIN);
    u16* wt     = (u16*)(ws + OFF_WT);
    u16* f1t    = (u16*)(ws + OFF_F1T);
    u16* f2t    = (u16*)(ws + OFF_F2T);
    u16* rbm    = (u16*)(ws + OFF_RBM);
    u16* cbm    = (u16*)(ws + OFF_CBM);
    int* cntR   = (int*)(ws + OFF_CNTR);
    int* cntC   = (int*)(ws + OFF_CNTC);
    int* listR  = (int*)(ws + OFF_LISTR);
    int* listC  = (int*)(ws + OFF_LISTC);
    float* out  = (float*)d_out;

    init_ws_kernel<<<(2 * BB * NN + 255) / 256, 256, 0, stream>>>(rowfin, cntR);
    convert_wt_kernel<<<(WT_TOTAL + 255) / 256, 256, 0, stream>>>(w1, w2, w3, w4, w5, wt);
    convert_f_kernel<<<(2 * BB * NN * DD) / 256, 256, 0, stream>>>(f1, f2, f1t, f2t);

    dim3 gS(48, 24, BB);
    simb_kernel<<<gS, 256, 0, stream>>>(f1t, f2t, rbm, cbm);

    scan_kernel<<<(BB * NN) / 256, 256, 0, stream>>>(rbm, cntR, listR);
    scan_kernel<<<(BB * NN) / 256, 256, 0, stream>>>(cbm, cntC, listC);

    dim3 gR(BB * 48, RSPLIT);
    refine_kernel<<<gR, 256, 0, stream>>>(f1, f2, cntR, listR, rowfin);
    refine_kernel<<<gR, 256, 0, stream>>>(f2, f1, cntC, listC, colfin);

    mlp_mfma_kernel<<<(BB * NN) / 64, 256, 0, stream>>>(
        f1, f2, kp1, kp2, sc1, b1, b2, b3, b4, b5, wt, rowfin, colfin, out);
}

// Round 7
// 233.679 us; speedup vs baseline: 2.8439x; 1.0037x over previous
//
#include <hip/hip_runtime.h>
#include <cstddef>
#include <cstdint>

#define BB 4
#define NN 6144
#define DD 64
#define HID 512
#define OUTD 64
#define CAP 512
#define RSPLIT 4

typedef unsigned long long ull;
typedef unsigned int u32;
typedef unsigned short u16;
typedef __attribute__((ext_vector_type(8))) short short8_t;
typedef __attribute__((ext_vector_type(4))) float floatx4;
typedef __attribute__((ext_vector_type(4))) unsigned short ushort4_t;

// ---- ws layout (byte offsets) ----
#define OFF_ROWFIN 0
#define OFF_COLFIN 196608
#define OFF_WT     393216
#define OFF_F1T    2162688
#define OFF_F2T    5308416
#define OFF_RBM    8454144
#define OFF_CBM    10813440
#define OFF_CNTR   13172736
#define OFF_CNTC   13173504
#define OFF_LISTR  13174272
#define OFF_LISTC  13567488

#define WT1_OFF 0
#define WT2_OFF 65536
#define WT3_OFF 327680
#define WT4_OFF 589824
#define WT5_OFF 851968
#define WT_TOTAL 884736

__device__ __forceinline__ unsigned int fkey(float v) {
    unsigned int u = __float_as_uint(v);
    return (u & 0x80000000u) ? ~u : (u | 0x80000000u);
}

__device__ __forceinline__ float inv16(u32 k16) {
    u32 u = k16 << 16;
    return (u & 0x80000000u) ? __uint_as_float(u & 0x7fffffffu)
                             : __uint_as_float(~u);
}

__device__ __forceinline__ u16 f2bf(float f) {
    unsigned int u = __float_as_uint(f);
    u += 0x7FFFu + ((u >> 16) & 1u);
    return (u16)(u >> 16);
}

// ---- prep: ws init + weights->bf16 tiled + feats->bf16 tiled, one launch ----
__global__ __launch_bounds__(256) void prep_kernel(
    const float* __restrict__ w1, const float* __restrict__ w2,
    const float* __restrict__ w3, const float* __restrict__ w4,
    const float* __restrict__ w5,
    const float* __restrict__ f1, const float* __restrict__ f2,
    u16* __restrict__ wt, u16* __restrict__ f1t, u16* __restrict__ f2t,
    ull* __restrict__ finals, int* __restrict__ cnts)
{
    int idx = blockIdx.x * 256 + threadIdx.x;

    if (idx < 2 * BB * NN) finals[idx] = 0ULL;
    if (idx < 384) cnts[idx] = 0;

    if (idx < WT_TOTAL) {
        const float* w; u16* o; int K, nsh, li;
        if (idx < 65536)        { w = w1; o = wt + WT1_OFF; K = 128; nsh = 9; li = idx; }
        else if (idx < 327680)  { w = w2; o = wt + WT2_OFF; K = 512; nsh = 9; li = idx - 65536; }
        else if (idx < 589824)  { w = w3; o = wt + WT3_OFF; K = 512; nsh = 9; li = idx - 327680; }
        else if (idx < 851968)  { w = w4; o = wt + WT4_OFF; K = 512; nsh = 9; li = idx - 589824; }
        else                    { w = w5; o = wt + WT5_OFF; K = 512; nsh = 6; li = idx - 851968; }
        int k = li >> nsh;
        int n = li & ((1 << nsh) - 1);
        u16 v = f2bf(w[li]);
        int lane = (n & 15) | (((k >> 3) & 3) << 4);
        o[(((n >> 4) * (K >> 5) + (k >> 5)) * 64 + lane) * 8 + (k & 7)] = v;
    }

    {
        const int TE = BB * NN * DD;
        const float* src; u16* dst; int e;
        if (idx < TE) { src = f1; dst = f1t; e = idx; }
        else          { src = f2; dst = f2t; e = idx - TE; }
        int k  = e & 63;
        int rn = e >> 6;
        int b  = rn / NN;
        int r  = rn - b * NN;
        int R  = r >> 7, rb = (r >> 4) & 7;
        int kb = k >> 5, lane = (r & 15) | (((k >> 3) & 3) << 4), j = k & 7;
        dst[(size_t)(b * 48 + R) * 8192 + ((rb * 2 + kb) * 64 + lane) * 8 + j] = f2bf(src[e]);
    }
}

// ---- Kernel A: bf16 MFMA sim, 128x256 tile, block maxima -> rbm/cbm ----
__global__ __launch_bounds__(256, 2) void simb_kernel(
    const u16* __restrict__ f1t, const u16* __restrict__ f2t,
    u16* __restrict__ rbm, u16* __restrict__ cbm)
{
    __shared__ __align__(16) u16 sA[8192];
    __shared__ __align__(16) u16 sB[16384];
    __shared__ float cv[2][2][128];
    const int R = blockIdx.x, C2 = blockIdx.y, b = blockIdx.z;
    const int t = threadIdx.x, lane = t & 63, w = t >> 6;
    const int wr = w >> 1, wc = w & 1;
    const int l15 = lane & 15, l4 = lane >> 4;

    const u16* Ag = f1t + (size_t)(b * 48 + R) * 8192;
    const u16* Bg = f2t + (size_t)(b * 48 + C2 * 2) * 8192;

    #pragma unroll
    for (int rnd = 0; rnd < 4; ++rnd) {
        int c = rnd * 256 + t;
        *reinterpret_cast<uint4*>(&sA[c * 8]) = *reinterpret_cast<const uint4*>(Ag + c * 8);
    }
    #pragma unroll
    for (int rnd = 0; rnd < 8; ++rnd) {
        int c = rnd * 256 + t;
        *reinterpret_cast<uint4*>(&sB[c * 8]) = *reinterpret_cast<const uint4*>(Bg + c * 8);
    }
    __syncthreads();

    floatx4 acc[4][8];
    #pragma unroll
    for (int i = 0; i < 4; ++i)
        #pragma unroll
        for (int j = 0; j < 8; ++j) acc[i][j] = (floatx4)(0.0f);

    #pragma unroll
    for (int kb = 0; kb < 2; ++kb) {
        short8_t afr[4], bfr[8];
        #pragma unroll
        for (int i = 0; i < 4; ++i)
            afr[i] = *reinterpret_cast<const short8_t*>(
                &sA[(((wr * 4 + i) * 2 + kb) * 64 + lane) * 8]);
        #pragma unroll
        for (int j = 0; j < 8; ++j) {
            int cb = wc * 8 + j;
            bfr[j] = *reinterpret_cast<const short8_t*>(
                &sB[(cb >> 3) * 8192 + (((cb & 7) * 2 + kb) * 64 + lane) * 8]);
        }
        #pragma unroll
        for (int i = 0; i < 4; ++i)
            #pragma unroll
            for (int j = 0; j < 8; ++j)
                acc[i][j] = __builtin_amdgcn_mfma_f32_16x16x32_bf16(
                    afr[i], bfr[j], acc[i][j], 0, 0, 0);
    }

    const int Cme = C2 * 2 + wc;
    #pragma unroll
    for (int i = 0; i < 4; ++i) {
        #pragma unroll
        for (int reg = 0; reg < 4; ++reg) {
            float v = acc[i][0][reg];
            #pragma unroll
            for (int j = 1; j < 8; ++j) v = fmaxf(v, acc[i][j][reg]);
            v = fmaxf(v, __shfl_xor(v, 1));
            v = fmaxf(v, __shfl_xor(v, 2));
            v = fmaxf(v, __shfl_xor(v, 4));
            v = fmaxf(v, __shfl_xor(v, 8));
            if (l15 == 0) {
                int row = R * 128 + wr * 64 + i * 16 + l4 * 4 + reg;
                rbm[((size_t)b * NN + row) * 48 + Cme] = (u16)(fkey(v) >> 16);
            }
        }
    }

    #pragma unroll
    for (int j = 0; j < 8; ++j) {
        float v = acc[0][j][0];
        #pragma unroll
        for (int i = 0; i < 4; ++i)
            #pragma unroll
            for (int reg = 0; reg < 4; ++reg) v = fmaxf(v, acc[i][j][reg]);
        v = fmaxf(v, __shfl_xor(v, 16));
        v = fmaxf(v, __shfl_xor(v, 32));
        if (l4 == 0) cv[wc][wr][j * 16 + l15] = v;
    }
    __syncthreads();
    {
        int wcc = t >> 7, col0 = t & 127;
        float v = fmaxf(cv[wcc][0][col0], cv[wcc][1][col0]);
        int col = C2 * 256 + wcc * 128 + col0;
        cbm[((size_t)b * NN + col) * 48 + R] = (u16)(fkey(v) >> 16);
    }
}

// ---- scan (merged row/col via blockIdx.y): block-aggregated candidate append ----
__global__ __launch_bounds__(256) void scan_kernel(
    const u16* __restrict__ rbm, const u16* __restrict__ cbm,
    int* __restrict__ cntR, int* __restrict__ cntC,
    int* __restrict__ listR, int* __restrict__ listC)
{
    const u16* bm = blockIdx.y ? cbm : rbm;
    int* cnt  = blockIdx.y ? cntC : cntR;
    int* list = blockIdx.y ? listC : listR;

    __shared__ int lcnt[48];
    __shared__ int lbase[48];
    const int t = threadIdx.x;
    if (t < 48) lcnt[t] = 0;
    const int idx = blockIdx.x * 256 + t;
    const int b = (blockIdx.x * 256) / NN;
    const int n = idx - b * NN;

    u16 ks[48];
    const uint4* p4 = reinterpret_cast<const uint4*>(bm + (size_t)idx * 48);
    #pragma unroll
    for (int q = 0; q < 6; ++q) {
        uint4 u = p4[q];
        ks[q * 8 + 0] = (u16)(u.x & 0xffff); ks[q * 8 + 1] = (u16)(u.x >> 16);
        ks[q * 8 + 2] = (u16)(u.y & 0xffff); ks[q * 8 + 3] = (u16)(u.y >> 16);
        ks[q * 8 + 4] = (u16)(u.z & 0xffff); ks[q * 8 + 5] = (u16)(u.z >> 16);
        ks[q * 8 + 6] = (u16)(u.w & 0xffff); ks[q * 8 + 7] = (u16)(u.w >> 16);
    }
    u16 mx = 0;
    #pragma unroll
    for (int c = 0; c < 48; ++c) mx = ks[c] > mx ? ks[c] : mx;
    float thr = inv16(mx) - 0.024f;   // >= 1.5x worst-case bf16 error bound
    u32 m0 = 0, m1 = 0;
    #pragma unroll
    for (int c = 0; c < 48; ++c) {
        if (inv16((u32)ks[c] + 1) >= thr) {
            if (c < 32) m0 |= 1u << c; else m1 |= 1u << (c - 32);
        }
    }
    __syncthreads();
    {
        u32 a = m0;
        while (a) { int c = __builtin_ctz(a); a &= a - 1; atomicAdd(&lcnt[c], 1); }
        a = m1;
        while (a) { int c = 32 + __builtin_ctz(a); a &= a - 1; atomicAdd(&lcnt[c], 1); }
    }
    __syncthreads();
    if (t < 48) { lbase[t] = atomicAdd(&cnt[b * 48 + t], lcnt[t]); lcnt[t] = 0; }
    __syncthreads();
    {
        u32 a = m0;
        while (a) {
            int c = __builtin_ctz(a); a &= a - 1;
            int pos = lbase[c] + atomicAdd(&lcnt[c], 1);
            if (pos < CAP) list[(b * 48 + c) * CAP + pos] = n;
        }
        a = m1;
        while (a) {
            int c = 32 + __builtin_ctz(a); a &= a - 1;
            int pos = lbase[c] + atomicAdd(&lcnt[c], 1);
            if (pos < CAP) list[(b * 48 + c) * CAP + pos] = n;
        }
    }
}

// ---- exact fp32 refine (merged row/col via blockIdx.z) ----
__global__ __launch_bounds__(256, 2) void refine_kernel(
    const float* __restrict__ f1, const float* __restrict__ f2,
    const int* __restrict__ cntR, const int* __restrict__ cntC,
    const int* __restrict__ listR, const int* __restrict__ listC,
    ull* __restrict__ rowfin, ull* __restrict__ colfin)
{
    const float* qfeat = blockIdx.z ? f2 : f1;
    const float* tfeat = blockIdx.z ? f1 : f2;
    const int* cnt  = blockIdx.z ? cntC : cntR;
    const int* list = blockIdx.z ? listC : listR;
    ull* fin = blockIdx.z ? colfin : rowfin;

    const int b = blockIdx.x / 48;
    const int C = blockIdx.x - b * 48;
    const int sub = blockIdx.y;
    int n_items = cnt[b * 48 + C];
    if (n_items > CAP) n_items = CAP;
    int chunk = (n_items + RSPLIT - 1) / RSPLIT;
    int lo = sub * chunk;
    int hi = lo + chunk; if (hi > n_items) hi = n_items;
    if (lo >= hi) return;

    __shared__ float s2f[128 * 68];
    const int t = threadIdx.x;
    const float* tb = tfeat + ((size_t)b * NN + C * 128) * 64;
    #pragma unroll
    for (int p = 0; p < 8; ++p) {
        int idx = p * 256 + t;
        int row = idx >> 4, c4 = idx & 15;
        *reinterpret_cast<float4*>(&s2f[row * 68 + c4 * 4]) =
            *reinterpret_cast<const float4*>(tb + row * 64 + c4 * 4);
    }
    __syncthreads();
    const int rs = t >> 4, cg = t & 15;
    const int* mylist = list + (b * 48 + C) * CAP;
    for (int base = lo; base < hi; base += 16) {
        int li = base + rs;
        bool valid = li < hi;
        int n = valid ? mylist[li] : mylist[lo];
        const float* q = qfeat + ((size_t)b * NN + n) * 64;
        float dot[8];
        #pragma unroll
        for (int c8 = 0; c8 < 8; ++c8) dot[c8] = 0.0f;
        #pragma unroll 4
        for (int kq = 0; kq < 16; ++kq) {
            float4 a4 = *reinterpret_cast<const float4*>(q + kq * 4);
            #pragma unroll
            for (int c8 = 0; c8 < 8; ++c8) {
                float4 s4 = *reinterpret_cast<const float4*>(&s2f[(cg + 16 * c8) * 68 + kq * 4]);
                dot[c8] = fmaf(a4.x, s4.x, dot[c8]);
                dot[c8] = fmaf(a4.y, s4.y, dot[c8]);
                dot[c8] = fmaf(a4.z, s4.z, dot[c8]);
                dot[c8] = fmaf(a4.w, s4.w, dot[c8]);
            }
        }
        float bv = dot[0]; int bc = cg;
        #pragma unroll
        for (int c8 = 1; c8 < 8; ++c8) {
            if (dot[c8] > bv) { bv = dot[c8]; bc = cg + 16 * c8; }
        }
        ull pk = ((ull)fkey(bv) << 32) | (u32)(~(u32)(C * 128 + bc));
        ull qq;
        qq = __shfl_xor(pk, 1); pk = pk > qq ? pk : qq;
        qq = __shfl_xor(pk, 2); pk = pk > qq ? pk : qq;
        qq = __shfl_xor(pk, 4); pk = pk > qq ? pk : qq;
        qq = __shfl_xor(pk, 8); pk = pk > qq ? pk : qq;
        if (cg == 0 && valid) atomicMax(&fin[(size_t)b * NN + n], pk);
    }
}

// ---- Kernel B: bf16 MFMA MLP, 512 threads / 8 waves, 64ch-slice per wave,
//      explicit weight prefetch (a_nxt) ----
template<int K>
__device__ __forceinline__ void mlp_layer8(
    u16* act, const u16* __restrict__ wt,
    const float* __restrict__ bias, int lane, int wid)
{
    constexpr int NKB = K / 32;
    floatx4 acc[4][4];
    #pragma unroll
    for (int ia = 0; ia < 4; ++ia)
        #pragma unroll
        for (int jb = 0; jb < 4; ++jb)
            acc[ia][jb] = (floatx4)(0.0f);

    const int l15 = lane & 15, l4 = lane >> 4;
    const int chBlk0 = wid * 4;   // (wid*64)/16

    short8_t a_cur[4], a_nxt[4];
    #pragma unroll
    for (int ia = 0; ia < 4; ++ia)
        a_cur[ia] = *reinterpret_cast<const short8_t*>(
            wt + (((chBlk0 + ia) * NKB + 0) * 64 + lane) * 8);

    #pragma unroll
    for (int kb = 0; kb < NKB; ++kb) {
        if (kb + 1 < NKB) {
            #pragma unroll
            for (int ia = 0; ia < 4; ++ia)
                a_nxt[ia] = *reinterpret_cast<const short8_t*>(
                    wt + (((chBlk0 + ia) * NKB + kb + 1) * 64 + lane) * 8);
        }
        #pragma unroll
        for (int jb = 0; jb < 4; ++jb) {
            int pt = jb * 16 + l15;
            int chk = (kb * 4 + l4) ^ (pt & 7);
            short8_t bfr = *reinterpret_cast<const short8_t*>(act + (pt * 64 + chk) * 8);
            #pragma unroll
            for (int ia = 0; ia < 4; ++ia)
                acc[ia][jb] = __builtin_amdgcn_mfma_f32_16x16x32_bf16(
                    a_cur[ia], bfr, acc[ia][jb], 0, 0, 0);
        }
        if (kb + 1 < NKB) {
            #pragma unroll
            for (int ia = 0; ia < 4; ++ia) a_cur[ia] = a_nxt[ia];
        }
    }
    __syncthreads();   // all reads done before in-place overwrite

    const int ch0 = wid * 64;
    #pragma unroll
    for (int ia = 0; ia < 4; ++ia) {
        int cb = ia * 16 + l4 * 4;
        float4 bv = *reinterpret_cast<const float4*>(bias + ch0 + cb);
        #pragma unroll
        for (int jb = 0; jb < 4; ++jb) {
            int pt = jb * 16 + l15;
            ushort4_t h;
            h[0] = f2bf(fmaxf(acc[ia][jb][0] + bv.x, 0.0f));
            h[1] = f2bf(fmaxf(acc[ia][jb][1] + bv.y, 0.0f));
            h[2] = f2bf(fmaxf(acc[ia][jb][2] + bv.z, 0.0f));
            h[3] = f2bf(fmaxf(acc[ia][jb][3] + bv.w, 0.0f));
            int chk = ((ch0 + cb) >> 3) ^ (pt & 7);
            *reinterpret_cast<ushort4_t*>(act + (pt * 64 + chk) * 8 + (cb & 7)) = h;
        }
    }
    __syncthreads();
}

__global__ __launch_bounds__(512, 4) void mlp_mfma_kernel(
    const float* __restrict__ f1, const float* __restrict__ f2,
    const float* __restrict__ kps1, const float* __restrict__ kps2,
    const float* __restrict__ scales1,
    const float* __restrict__ b1, const float* __restrict__ b2,
    const float* __restrict__ b3, const float* __restrict__ b4,
    const float* __restrict__ b5,
    const u16* __restrict__ wt,
    const ull* __restrict__ rowfin, const ull* __restrict__ colfin,
    float* __restrict__ out)
{
    __shared__ __align__(16) unsigned char lds_raw[65536];
    u16* act = reinterpret_cast<u16*>(lds_raw);
    float* logf = reinterpret_cast<float*>(lds_raw);

    const int t = threadIdx.x;
    const int lane = t & 63, wid = t >> 6;
    const int base = blockIdx.x * 64;
    const int b = base / NN;
    const int n0 = base % NN;

    // stage concat(f1[n], f2[match12[n]]) as bf16, swizzled; 512 threads
    {
        const int pt = t & 63, seg = t >> 6;   // 8 segs * 16 floats
        const int n = n0 + pt;
        ull rm = rowfin[(size_t)b * NN + n];
        const int m = (int)(~(unsigned int)(rm & 0xffffffffULL));
        const float* src = (seg < 4)
            ? (f1 + ((size_t)b * NN + n) * DD + seg * 16)
            : (f2 + ((size_t)b * NN + m) * DD + (seg - 4) * 16);
        #pragma unroll
        for (int q = 0; q < 2; ++q) {
            float4 v0 = *reinterpret_cast<const float4*>(src + q * 8);
            float4 v1 = *reinterpret_cast<const float4*>(src + q * 8 + 4);
            short8_t h;
            h[0] = (short)f2bf(v0.x); h[1] = (short)f2bf(v0.y);
            h[2] = (short)f2bf(v0.z); h[3] = (short)f2bf(v0.w);
            h[4] = (short)f2bf(v1.x); h[5] = (short)f2bf(v1.y);
            h[6] = (short)f2bf(v1.z); h[7] = (short)f2bf(v1.w);
            int chk = (seg * 2 + q) ^ (pt & 7);
            *reinterpret_cast<short8_t*>(act + (pt * 64 + chk) * 8) = h;
        }
    }
    __syncthreads();

    mlp_layer8<128>(act, wt + WT1_OFF, b1, lane, wid);
    mlp_layer8<512>(act, wt + WT2_OFF, b2, lane, wid);
    mlp_layer8<512>(act, wt + WT3_OFF, b3, lane, wid);
    mlp_layer8<512>(act, wt + WT4_OFF, b4, lane, wid);

    // layer 5: 512 -> 64, no relu; waves 0-3 handle 16 out-ch each
    {
        const int l15 = lane & 15, l4 = lane >> 4;
        floatx4 acc5[4];
        #pragma unroll
        for (int jb = 0; jb < 4; ++jb) acc5[jb] = (floatx4)(0.0f);
        if (wid < 4) {
            short8_t a_cur = *reinterpret_cast<const short8_t*>(
                wt + WT5_OFF + ((wid * 16 + 0) * 64 + lane) * 8);
            short8_t a_nxt;
            #pragma unroll
            for (int kb = 0; kb < 16; ++kb) {
                if (kb + 1 < 16)
                    a_nxt = *reinterpret_cast<const short8_t*>(
                        wt + WT5_OFF + ((wid * 16 + kb + 1) * 64 + lane) * 8);
                #pragma unroll
                for (int jb = 0; jb < 4; ++jb) {
                    int pt = jb * 16 + l15;
                    int chk = (kb * 4 + l4) ^ (pt & 7);
                    short8_t bfr = *reinterpret_cast<const short8_t*>(act + (pt * 64 + chk) * 8);
                    acc5[jb] = __builtin_amdgcn_mfma_f32_16x16x32_bf16(
                        a_cur, bfr, acc5[jb], 0, 0, 0);
                }
                if (kb + 1 < 16) a_cur = a_nxt;
            }
        }
        __syncthreads();   // all act reads done; lds_raw becomes logits f32
        if (wid < 4) {
            int cb = wid * 16 + l4 * 4;
            float4 bv = *reinterpret_cast<const float4*>(b5 + cb);
            #pragma unroll
            for (int jb = 0; jb < 4; ++jb) {
                int pt = jb * 16 + l15;
                float4 o;
                o.x = acc5[jb][0] + bv.x;
                o.y = acc5[jb][1] + bv.y;
                o.z = acc5[jb][2] + bv.z;
                o.w = acc5[jb][3] + bv.w;
                *reinterpret_cast<float4*>(&logf[pt * 68 + cb]) = o;
            }
        }
        __syncthreads();
    }

    if (t < 64) {
        const int pt = t;
        const int n = n0 + pt;
        const float* lrow = &logf[pt * 68];
        float mx = -1e30f;
        #pragma unroll 8
        for (int j = 0; j < OUTD; ++j) mx = fmaxf(mx, 3.0f * lrow[j]);
        float s = 0.0f, cx = 0.0f, cy = 0.0f;
        #pragma unroll 8
        for (int j = 0; j < OUTD; ++j) {
            float e = __expf(3.0f * lrow[j] - mx);
            s  += e;
            cx += e * (float)((j & 7) - 4);
            cy += e * (float)((j >> 3) - 4);
        }
        float conf = 1.0f / s;
        cx /= s; cy /= s;
        ull rm = rowfin[(size_t)b * NN + n];
        int m = (int)(~(unsigned int)(rm & 0xffffffffULL));
        ull cm = colfin[(size_t)b * NN + m];
        int back = (int)(~(unsigned int)(cm & 0xffffffffULL));
        bool mutual = (back == n);
        float sc = scales1[(size_t)b * NN + n];
        float x0 = kps1[((size_t)b * NN + n) * 2 + 0] + cx * sc;
        float y0 = kps1[((size_t)b * NN + n) * 2 + 1] + cy * sc;
        float x1 = kps2[((size_t)b * NN + m) * 2 + 0];
        float y1 = kps2[((size_t)b * NN + m) * 2 + 1];
        float* mt = out + ((size_t)b * NN + n) * 4;
        mt[0] = x0; mt[1] = y0; mt[2] = x1; mt[3] = y1;
        out[(size_t)BB * NN * 4 + (size_t)b * NN + n] =
            (mutual && conf > 0.25f) ? 1.0f : 0.0f;
    }
}

extern "C" void kernel_launch(void* const* d_in, const int* in_sizes, int n_in,
                              void* d_out, int out_size, void* d_ws, size_t ws_size,
                              hipStream_t stream)
{
    const float* f1  = (const float*)d_in[0];
    const float* f2  = (const float*)d_in[1];
    const float* kp1 = (const float*)d_in[2];
    const float* kp2 = (const float*)d_in[3];
    const float* sc1 = (const float*)d_in[4];
    const float* w1  = (const float*)d_in[5];
    const float* b1  = (const float*)d_in[6];
    const float* w2  = (const float*)d_in[7];
    const float* b2  = (const float*)d_in[8];
    const float* w3  = (const float*)d_in[9];
    const float* b3  = (const float*)d_in[10];
    const float* w4  = (const float*)d_in[11];
    const float* b4  = (const float*)d_in[12];
    const float* w5  = (const float*)d_in[13];
    const float* b5  = (const float*)d_in[14];

    char* ws = (char*)d_ws;
    ull* rowfin = (ull*)(ws + OFF_ROWFIN);
    ull* colfin = (ull*)(ws + OFF_COLFIN);
    u16* wt     = (u16*)(ws + OFF_WT);
    u16* f1t    = (u16*)(ws + OFF_F1T);
    u16* f2t    = (u16*)(ws + OFF_F2T);
    u16* rbm    = (u16*)(ws + OFF_RBM);
    u16* cbm    = (u16*)(ws + OFF_CBM);
    int* cntR   = (int*)(ws + OFF_CNTR);
    int* cntC   = (int*)(ws + OFF_CNTC);
    int* listR  = (int*)(ws + OFF_LISTR);
    int* listC  = (int*)(ws + OFF_LISTC);
    float* out  = (float*)d_out;

    prep_kernel<<<(2 * BB * NN * DD) / 256, 256, 0, stream>>>(
        w1, w2, w3, w4, w5, f1, f2, wt, f1t, f2t, rowfin, cntR);

    dim3 gS(48, 24, BB);
    simb_kernel<<<gS, 256, 0, stream>>>(f1t, f2t, rbm, cbm);

    dim3 gScan((BB * NN) / 256, 2);
    scan_kernel<<<gScan, 256, 0, stream>>>(rbm, cbm, cntR, cntC, listR, listC);

    dim3 gR(BB * 48, RSPLIT, 2);
    refine_kernel<<<gR, 256, 0, stream>>>(f1, f2, cntR, cntC, listR, listC,
                                          rowfin, colfin);

    mlp_mfma_kernel<<<(BB * NN) / 64, 512, 0, stream>>>(
        f1, f2, kp1, kp2, sc1, b1, b2, b3, b4, b5, wt, rowfin, colfin, out);
}

// Round 9
// 209.567 us; speedup vs baseline: 3.1711x; 1.1151x over previous
//
#include <hip/hip_runtime.h>
#include <cstddef>
#include <cstdint>

#define BB 4
#define NN 6144
#define DD 64
#define HID 512
#define OUTD 64
#define CAP 512
#define RSPLIT 4

typedef unsigned long long ull;
typedef unsigned int u32;
typedef unsigned short u16;
typedef __attribute__((ext_vector_type(8))) short short8_t;
typedef __attribute__((ext_vector_type(4))) float floatx4;
typedef __attribute__((ext_vector_type(4))) unsigned short ushort4_t;

// ---- ws layout (byte offsets) ----
#define OFF_ROWFIN 0
#define OFF_COLFIN 196608
#define OFF_WT     393216
#define OFF_F1T    2162688
#define OFF_F2T    5308416
#define OFF_RBM    8454144
#define OFF_CBM    10813440
#define OFF_CNTR   13172736
#define OFF_CNTC   13173504
#define OFF_LISTR  13174272
#define OFF_LISTC  13567488

#define WT1_OFF 0
#define WT2_OFF 65536
#define WT3_OFF 327680
#define WT4_OFF 589824
#define WT5_OFF 851968
#define WT_TOTAL 884736

__device__ __forceinline__ unsigned int fkey(float v) {
    unsigned int u = __float_as_uint(v);
    return (u & 0x80000000u) ? ~u : (u | 0x80000000u);
}

__device__ __forceinline__ float inv16(u32 k16) {
    u32 u = k16 << 16;
    return (u & 0x80000000u) ? __uint_as_float(u & 0x7fffffffu)
                             : __uint_as_float(~u);
}

__device__ __forceinline__ u16 f2bf(float f) {
    unsigned int u = __float_as_uint(f);
    u += 0x7FFFu + ((u >> 16) & 1u);
    return (u16)(u >> 16);
}

// ---- prep: ws init + weights->bf16 tiled + feats->bf16 tiled, one launch ----
__global__ __launch_bounds__(256) void prep_kernel(
    const float* __restrict__ w1, const float* __restrict__ w2,
    const float* __restrict__ w3, const float* __restrict__ w4,
    const float* __restrict__ w5,
    const float* __restrict__ f1, const float* __restrict__ f2,
    u16* __restrict__ wt, u16* __restrict__ f1t, u16* __restrict__ f2t,
    ull* __restrict__ finals, int* __restrict__ cnts)
{
    int idx = blockIdx.x * 256 + threadIdx.x;

    if (idx < 2 * BB * NN) finals[idx] = 0ULL;
    if (idx < 384) cnts[idx] = 0;

    if (idx < WT_TOTAL) {
        const float* w; u16* o; int K, nsh, li;
        if (idx < 65536)        { w = w1; o = wt + WT1_OFF; K = 128; nsh = 9; li = idx; }
        else if (idx < 327680)  { w = w2; o = wt + WT2_OFF; K = 512; nsh = 9; li = idx - 65536; }
        else if (idx < 589824)  { w = w3; o = wt + WT3_OFF; K = 512; nsh = 9; li = idx - 327680; }
        else if (idx < 851968)  { w = w4; o = wt + WT4_OFF; K = 512; nsh = 9; li = idx - 589824; }
        else                    { w = w5; o = wt + WT5_OFF; K = 512; nsh = 6; li = idx - 851968; }
        int k = li >> nsh;
        int n = li & ((1 << nsh) - 1);
        u16 v = f2bf(w[li]);
        int lane = (n & 15) | (((k >> 3) & 3) << 4);
        o[(((n >> 4) * (K >> 5) + (k >> 5)) * 64 + lane) * 8 + (k & 7)] = v;
    }

    {
        const int TE = BB * NN * DD;
        const float* src; u16* dst; int e;
        if (idx < TE) { src = f1; dst = f1t; e = idx; }
        else          { src = f2; dst = f2t; e = idx - TE; }
        int k  = e & 63;
        int rn = e >> 6;
        int b  = rn / NN;
        int r  = rn - b * NN;
        int R  = r >> 7, rb = (r >> 4) & 7;
        int kb = k >> 5, lane = (r & 15) | (((k >> 3) & 3) << 4), j = k & 7;
        dst[(size_t)(b * 48 + R) * 8192 + ((rb * 2 + kb) * 64 + lane) * 8 + j] = f2bf(src[e]);
    }
}

// ---- Kernel A: bf16 MFMA sim, 128x256 tile, block maxima -> rbm/cbm ----
__global__ __launch_bounds__(256, 2) void simb_kernel(
    const u16* __restrict__ f1t, const u16* __restrict__ f2t,
    u16* __restrict__ rbm, u16* __restrict__ cbm)
{
    __shared__ __align__(16) u16 sA[8192];
    __shared__ __align__(16) u16 sB[16384];
    __shared__ float cv[2][2][128];
    const int R = blockIdx.x, C2 = blockIdx.y, b = blockIdx.z;
    const int t = threadIdx.x, lane = t & 63, w = t >> 6;
    const int wr = w >> 1, wc = w & 1;
    const int l15 = lane & 15, l4 = lane >> 4;

    const u16* Ag = f1t + (size_t)(b * 48 + R) * 8192;
    const u16* Bg = f2t + (size_t)(b * 48 + C2 * 2) * 8192;

    #pragma unroll
    for (int rnd = 0; rnd < 4; ++rnd) {
        int c = rnd * 256 + t;
        *reinterpret_cast<uint4*>(&sA[c * 8]) = *reinterpret_cast<const uint4*>(Ag + c * 8);
    }
    #pragma unroll
    for (int rnd = 0; rnd < 8; ++rnd) {
        int c = rnd * 256 + t;
        *reinterpret_cast<uint4*>(&sB[c * 8]) = *reinterpret_cast<const uint4*>(Bg + c * 8);
    }
    __syncthreads();

    floatx4 acc[4][8];
    #pragma unroll
    for (int i = 0; i < 4; ++i)
        #pragma unroll
        for (int j = 0; j < 8; ++j) acc[i][j] = (floatx4)(0.0f);

    #pragma unroll
    for (int kb = 0; kb < 2; ++kb) {
        short8_t afr[4], bfr[8];
        #pragma unroll
        for (int i = 0; i < 4; ++i)
            afr[i] = *reinterpret_cast<const short8_t*>(
                &sA[(((wr * 4 + i) * 2 + kb) * 64 + lane) * 8]);
        #pragma unroll
        for (int j = 0; j < 8; ++j) {
            int cb = wc * 8 + j;
            bfr[j] = *reinterpret_cast<const short8_t*>(
                &sB[(cb >> 3) * 8192 + (((cb & 7) * 2 + kb) * 64 + lane) * 8]);
        }
        #pragma unroll
        for (int i = 0; i < 4; ++i)
            #pragma unroll
            for (int j = 0; j < 8; ++j)
                acc[i][j] = __builtin_amdgcn_mfma_f32_16x16x32_bf16(
                    afr[i], bfr[j], acc[i][j], 0, 0, 0);
    }

    const int Cme = C2 * 2 + wc;
    #pragma unroll
    for (int i = 0; i < 4; ++i) {
        #pragma unroll
        for (int reg = 0; reg < 4; ++reg) {
            float v = acc[i][0][reg];
            #pragma unroll
            for (int j = 1; j < 8; ++j) v = fmaxf(v, acc[i][j][reg]);
            v = fmaxf(v, __shfl_xor(v, 1));
            v = fmaxf(v, __shfl_xor(v, 2));
            v = fmaxf(v, __shfl_xor(v, 4));
            v = fmaxf(v, __shfl_xor(v, 8));
            if (l15 == 0) {
                int row = R * 128 + wr * 64 + i * 16 + l4 * 4 + reg;
                rbm[((size_t)b * NN + row) * 48 + Cme] = (u16)(fkey(v) >> 16);
            }
        }
    }

    #pragma unroll
    for (int j = 0; j < 8; ++j) {
        float v = acc[0][j][0];
        #pragma unroll
        for (int i = 0; i < 4; ++i)
            #pragma unroll
            for (int reg = 0; reg < 4; ++reg) v = fmaxf(v, acc[i][j][reg]);
        v = fmaxf(v, __shfl_xor(v, 16));
        v = fmaxf(v, __shfl_xor(v, 32));
        if (l4 == 0) cv[wc][wr][j * 16 + l15] = v;
    }
    __syncthreads();
    {
        int wcc = t >> 7, col0 = t & 127;
        float v = fmaxf(cv[wcc][0][col0], cv[wcc][1][col0]);
        int col = C2 * 256 + wcc * 128 + col0;
        cbm[((size_t)b * NN + col) * 48 + R] = (u16)(fkey(v) >> 16);
    }
}

// ---- scan (merged row/col via blockIdx.y): block-aggregated candidate append ----
__global__ __launch_bounds__(256) void scan_kernel(
    const u16* __restrict__ rbm, const u16* __restrict__ cbm,
    int* __restrict__ cntR, int* __restrict__ cntC,
    int* __restrict__ listR, int* __restrict__ listC)
{
    const u16* bm = blockIdx.y ? cbm : rbm;
    int* cnt  = blockIdx.y ? cntC : cntR;
    int* list = blockIdx.y ? listC : listR;

    __shared__ int lcnt[48];
    __shared__ int lbase[48];
    const int t = threadIdx.x;
    if (t < 48) lcnt[t] = 0;
    const int idx = blockIdx.x * 256 + t;
    const int b = (blockIdx.x * 256) / NN;
    const int n = idx - b * NN;

    u16 ks[48];
    const uint4* p4 = reinterpret_cast<const uint4*>(bm + (size_t)idx * 48);
    #pragma unroll
    for (int q = 0; q < 6; ++q) {
        uint4 u = p4[q];
        ks[q * 8 + 0] = (u16)(u.x & 0xffff); ks[q * 8 + 1] = (u16)(u.x >> 16);
        ks[q * 8 + 2] = (u16)(u.y & 0xffff); ks[q * 8 + 3] = (u16)(u.y >> 16);
        ks[q * 8 + 4] = (u16)(u.z & 0xffff); ks[q * 8 + 5] = (u16)(u.z >> 16);
        ks[q * 8 + 6] = (u16)(u.w & 0xffff); ks[q * 8 + 7] = (u16)(u.w >> 16);
    }
    u16 mx = 0;
    #pragma unroll
    for (int c = 0; c < 48; ++c) mx = ks[c] > mx ? ks[c] : mx;
    float thr = inv16(mx) - 0.024f;   // >= 1.5x worst-case bf16 error bound
    u32 m0 = 0, m1 = 0;
    #pragma unroll
    for (int c = 0; c < 48; ++c) {
        if (inv16((u32)ks[c] + 1) >= thr) {
            if (c < 32) m0 |= 1u << c; else m1 |= 1u << (c - 32);
        }
    }
    __syncthreads();
    {
        u32 a = m0;
        while (a) { int c = __builtin_ctz(a); a &= a - 1; atomicAdd(&lcnt[c], 1); }
        a = m1;
        while (a) { int c = 32 + __builtin_ctz(a); a &= a - 1; atomicAdd(&lcnt[c], 1); }
    }
    __syncthreads();
    if (t < 48) { lbase[t] = atomicAdd(&cnt[b * 48 + t], lcnt[t]); lcnt[t] = 0; }
    __syncthreads();
    {
        u32 a = m0;
        while (a) {
            int c = __builtin_ctz(a); a &= a - 1;
            int pos = lbase[c] + atomicAdd(&lcnt[c], 1);
            if (pos < CAP) list[(b * 48 + c) * CAP + pos] = n;
        }
        a = m1;
        while (a) {
            int c = 32 + __builtin_ctz(a); a &= a - 1;
            int pos = lbase[c] + atomicAdd(&lcnt[c], 1);
            if (pos < CAP) list[(b * 48 + c) * CAP + pos] = n;
        }
    }
}

// ---- exact fp32 refine (merged row/col via blockIdx.z) ----
__global__ __launch_bounds__(256, 2) void refine_kernel(
    const float* __restrict__ f1, const float* __restrict__ f2,
    const int* __restrict__ cntR, const int* __restrict__ cntC,
    const int* __restrict__ listR, const int* __restrict__ listC,
    ull* __restrict__ rowfin, ull* __restrict__ colfin)
{
    const float* qfeat = blockIdx.z ? f2 : f1;
    const float* tfeat = blockIdx.z ? f1 : f2;
    const int* cnt  = blockIdx.z ? cntC : cntR;
    const int* list = blockIdx.z ? listC : listR;
    ull* fin = blockIdx.z ? colfin : rowfin;

    const int b = blockIdx.x / 48;
    const int C = blockIdx.x - b * 48;
    const int sub = blockIdx.y;
    int n_items = cnt[b * 48 + C];
    if (n_items > CAP) n_items = CAP;
    int chunk = (n_items + RSPLIT - 1) / RSPLIT;
    int lo = sub * chunk;
    int hi = lo + chunk; if (hi > n_items) hi = n_items;
    if (lo >= hi) return;

    __shared__ float s2f[128 * 68];
    const int t = threadIdx.x;
    const float* tb = tfeat + ((size_t)b * NN + C * 128) * 64;
    #pragma unroll
    for (int p = 0; p < 8; ++p) {
        int idx = p * 256 + t;
        int row = idx >> 4, c4 = idx & 15;
        *reinterpret_cast<float4*>(&s2f[row * 68 + c4 * 4]) =
            *reinterpret_cast<const float4*>(tb + row * 64 + c4 * 4);
    }
    __syncthreads();
    const int rs = t >> 4, cg = t & 15;
    const int* mylist = list + (b * 48 + C) * CAP;
    for (int base = lo; base < hi; base += 16) {
        int li = base + rs;
        bool valid = li < hi;
        int n = valid ? mylist[li] : mylist[lo];
        const float* q = qfeat + ((size_t)b * NN + n) * 64;
        float dot[8];
        #pragma unroll
        for (int c8 = 0; c8 < 8; ++c8) dot[c8] = 0.0f;
        #pragma unroll 4
        for (int kq = 0; kq < 16; ++kq) {
            float4 a4 = *reinterpret_cast<const float4*>(q + kq * 4);
            #pragma unroll
            for (int c8 = 0; c8 < 8; ++c8) {
                float4 s4 = *reinterpret_cast<const float4*>(&s2f[(cg + 16 * c8) * 68 + kq * 4]);
                dot[c8] = fmaf(a4.x, s4.x, dot[c8]);
                dot[c8] = fmaf(a4.y, s4.y, dot[c8]);
                dot[c8] = fmaf(a4.z, s4.z, dot[c8]);
                dot[c8] = fmaf(a4.w, s4.w, dot[c8]);
            }
        }
        float bv = dot[0]; int bc = cg;
        #pragma unroll
        for (int c8 = 1; c8 < 8; ++c8) {
            if (dot[c8] > bv) { bv = dot[c8]; bc = cg + 16 * c8; }
        }
        ull pk = ((ull)fkey(bv) << 32) | (u32)(~(u32)(C * 128 + bc));
        ull qq;
        qq = __shfl_xor(pk, 1); pk = pk > qq ? pk : qq;
        qq = __shfl_xor(pk, 2); pk = pk > qq ? pk : qq;
        qq = __shfl_xor(pk, 4); pk = pk > qq ? pk : qq;
        qq = __shfl_xor(pk, 8); pk = pk > qq ? pk : qq;
        if (cg == 0 && valid) atomicMax(&fin[(size_t)b * NN + n], pk);
    }
}

// ---- Kernel B: bf16 MFMA MLP, 512 threads / 8 waves, 64ch-slice per wave,
//      3-buffer statically-indexed weight prefetch, launch_bounds(512,2) ----

// One kb step: 4 LDS act reads + 16 MFMA with BUF, then prefetch kb+3 into BUF
#define MLP_STEP(BUF, KB)                                                      \
    {                                                                          \
        _Pragma("unroll")                                                      \
        for (int jb = 0; jb < 4; ++jb) {                                       \
            int pt = jb * 16 + l15;                                            \
            int chk = ((KB) * 4 + l4) ^ (pt & 7);                              \
            short8_t bfr = *reinterpret_cast<const short8_t*>(                 \
                act + (pt * 64 + chk) * 8);                                    \
            _Pragma("unroll")                                                  \
            for (int ia = 0; ia < 4; ++ia)                                     \
                acc[ia][jb] = __builtin_amdgcn_mfma_f32_16x16x32_bf16(         \
                    BUF[ia], bfr, acc[ia][jb], 0, 0, 0);                       \
        }                                                                      \
        if ((KB) + 3 < NKB) {                                                  \
            _Pragma("unroll")                                                  \
            for (int ia = 0; ia < 4; ++ia)                                     \
                BUF[ia] = *reinterpret_cast<const short8_t*>(                  \
                    wt + (((chBlk0 + ia) * NKB + (KB) + 3) * 64 + lane) * 8);  \
        }                                                                      \
    }

template<int K>
__device__ __forceinline__ void mlp_layer8(
    u16* act, const u16* __restrict__ wt,
    const float* __restrict__ bias, int lane, int wid)
{
    constexpr int NKB = K / 32;
    floatx4 acc[4][4];
    #pragma unroll
    for (int ia = 0; ia < 4; ++ia)
        #pragma unroll
        for (int jb = 0; jb < 4; ++jb)
            acc[ia][jb] = (floatx4)(0.0f);

    const int l15 = lane & 15, l4 = lane >> 4;
    const int chBlk0 = wid * 4;   // (wid*64)/16

    short8_t a0[4], a1[4], a2[4];
    #pragma unroll
    for (int ia = 0; ia < 4; ++ia)
        a0[ia] = *reinterpret_cast<const short8_t*>(
            wt + (((chBlk0 + ia) * NKB + 0) * 64 + lane) * 8);
    #pragma unroll
    for (int ia = 0; ia < 4; ++ia)
        a1[ia] = *reinterpret_cast<const short8_t*>(
            wt + (((chBlk0 + ia) * NKB + 1) * 64 + lane) * 8);
    #pragma unroll
    for (int ia = 0; ia < 4; ++ia)
        a2[ia] = *reinterpret_cast<const short8_t*>(
            wt + (((chBlk0 + ia) * NKB + 2) * 64 + lane) * 8);

    #pragma unroll
    for (int kb = 0; kb < NKB; ++kb) {
        if ((kb % 3) == 0)      MLP_STEP(a0, kb)
        else if ((kb % 3) == 1) MLP_STEP(a1, kb)
        else                    MLP_STEP(a2, kb)
    }
    __syncthreads();   // all reads done before in-place overwrite

    const int ch0 = wid * 64;
    #pragma unroll
    for (int ia = 0; ia < 4; ++ia) {
        int cb = ia * 16 + l4 * 4;
        float4 bv = *reinterpret_cast<const float4*>(bias + ch0 + cb);
        #pragma unroll
        for (int jb = 0; jb < 4; ++jb) {
            int pt = jb * 16 + l15;
            ushort4_t h;
            h[0] = f2bf(fmaxf(acc[ia][jb][0] + bv.x, 0.0f));
            h[1] = f2bf(fmaxf(acc[ia][jb][1] + bv.y, 0.0f));
            h[2] = f2bf(fmaxf(acc[ia][jb][2] + bv.z, 0.0f));
            h[3] = f2bf(fmaxf(acc[ia][jb][3] + bv.w, 0.0f));
            int chk = ((ch0 + cb) >> 3) ^ (pt & 7);
            *reinterpret_cast<ushort4_t*>(act + (pt * 64 + chk) * 8 + (cb & 7)) = h;
        }
    }
    __syncthreads();
}

__global__ __launch_bounds__(512, 2) void mlp_mfma_kernel(
    const float* __restrict__ f1, const float* __restrict__ f2,
    const float* __restrict__ kps1, const float* __restrict__ kps2,
    const float* __restrict__ scales1,
    const float* __restrict__ b1, const float* __restrict__ b2,
    const float* __restrict__ b3, const float* __restrict__ b4,
    const float* __restrict__ b5,
    const u16* __restrict__ wt,
    const ull* __restrict__ rowfin, const ull* __restrict__ colfin,
    float* __restrict__ out)
{
    __shared__ __align__(16) unsigned char lds_raw[65536];
    u16* act = reinterpret_cast<u16*>(lds_raw);
    float* logf = reinterpret_cast<float*>(lds_raw);

    const int t = threadIdx.x;
    const int lane = t & 63, wid = t >> 6;
    const int base = blockIdx.x * 64;
    const int b = base / NN;
    const int n0 = base % NN;

    // stage concat(f1[n], f2[match12[n]]) as bf16, swizzled; 512 threads
    {
        const int pt = t & 63, seg = t >> 6;   // 8 segs * 16 floats
        const int n = n0 + pt;
        ull rm = rowfin[(size_t)b * NN + n];
        const int m = (int)(~(unsigned int)(rm & 0xffffffffULL));
        const float* src = (seg < 4)
            ? (f1 + ((size_t)b * NN + n) * DD + seg * 16)
            : (f2 + ((size_t)b * NN + m) * DD + (seg - 4) * 16);
        #pragma unroll
        for (int q = 0; q < 2; ++q) {
            float4 v0 = *reinterpret_cast<const float4*>(src + q * 8);
            float4 v1 = *reinterpret_cast<const float4*>(src + q * 8 + 4);
            short8_t h;
            h[0] = (short)f2bf(v0.x); h[1] = (short)f2bf(v0.y);
            h[2] = (short)f2bf(v0.z); h[3] = (short)f2bf(v0.w);
            h[4] = (short)f2bf(v1.x); h[5] = (short)f2bf(v1.y);
            h[6] = (short)f2bf(v1.z); h[7] = (short)f2bf(v1.w);
            int chk = (seg * 2 + q) ^ (pt & 7);
            *reinterpret_cast<short8_t*>(act + (pt * 64 + chk) * 8) = h;
        }
    }
    __syncthreads();

    mlp_layer8<128>(act, wt + WT1_OFF, b1, lane, wid);
    mlp_layer8<512>(act, wt + WT2_OFF, b2, lane, wid);
    mlp_layer8<512>(act, wt + WT3_OFF, b3, lane, wid);
    mlp_layer8<512>(act, wt + WT4_OFF, b4, lane, wid);

    // layer 5: 512 -> 64, no relu; waves 0-3 handle 16 out-ch each
    {
        const int l15 = lane & 15, l4 = lane >> 4;
        floatx4 acc5[4];
        #pragma unroll
        for (int jb = 0; jb < 4; ++jb) acc5[jb] = (floatx4)(0.0f);
        if (wid < 4) {
            short8_t a_cur = *reinterpret_cast<const short8_t*>(
                wt + WT5_OFF + ((wid * 16 + 0) * 64 + lane) * 8);
            short8_t a_nxt;
            #pragma unroll
            for (int kb = 0; kb < 16; ++kb) {
                if (kb + 1 < 16)
                    a_nxt = *reinterpret_cast<const short8_t*>(
                        wt + WT5_OFF + ((wid * 16 + kb + 1) * 64 + lane) * 8);
                #pragma unroll
                for (int jb = 0; jb < 4; ++jb) {
                    int pt = jb * 16 + l15;
                    int chk = (kb * 4 + l4) ^ (pt & 7);
                    short8_t bfr = *reinterpret_cast<const short8_t*>(act + (pt * 64 + chk) * 8);
                    acc5[jb] = __builtin_amdgcn_mfma_f32_16x16x32_bf16(
                        a_cur, bfr, acc5[jb], 0, 0, 0);
                }
                if (kb + 1 < 16) a_cur = a_nxt;
            }
        }
        __syncthreads();   // all act reads done; lds_raw becomes logits f32
        if (wid < 4) {
            int cb = wid * 16 + l4 * 4;
            float4 bv = *reinterpret_cast<const float4*>(b5 + cb);
            #pragma unroll
            for (int jb = 0; jb < 4; ++jb) {
                int pt = jb * 16 + l15;
                float4 o;
                o.x = acc5[jb][0] + bv.x;
                o.y = acc5[jb][1] + bv.y;
                o.z = acc5[jb][2] + bv.z;
                o.w = acc5[jb][3] + bv.w;
                *reinterpret_cast<float4*>(&logf[pt * 68 + cb]) = o;
            }
        }
        __syncthreads();
    }

    if (t < 64) {
        const int pt = t;
        const int n = n0 + pt;
        const float* lrow = &logf[pt * 68];
        float mx = -1e30f;
        #pragma unroll 8
        for (int j = 0; j < OUTD; ++j) mx = fmaxf(mx, 3.0f * lrow[j]);
        float s = 0.0f, cx = 0.0f, cy = 0.0f;
        #pragma unroll 8
        for (int j = 0; j < OUTD; ++j) {
            float e = __expf(3.0f * lrow[j] - mx);
            s  += e;
            cx += e * (float)((j & 7) - 4);
            cy += e * (float)((j >> 3) - 4);
        }
        float conf = 1.0f / s;
        cx /= s; cy /= s;
        ull rm = rowfin[(size_t)b * NN + n];
        int m = (int)(~(unsigned int)(rm & 0xffffffffULL));
        ull cm = colfin[(size_t)b * NN + m];
        int back = (int)(~(unsigned int)(cm & 0xffffffffULL));
        bool mutual = (back == n);
        float sc = scales1[(size_t)b * NN + n];
        float x0 = kps1[((size_t)b * NN + n) * 2 + 0] + cx * sc;
        float y0 = kps1[((size_t)b * NN + n) * 2 + 1] + cy * sc;
        float x1 = kps2[((size_t)b * NN + m) * 2 + 0];
        float y1 = kps2[((size_t)b * NN + m) * 2 + 1];
        float* mt = out + ((size_t)b * NN + n) * 4;
        mt[0] = x0; mt[1] = y0; mt[2] = x1; mt[3] = y1;
        out[(size_t)BB * NN * 4 + (size_t)b * NN + n] =
            (mutual && conf > 0.25f) ? 1.0f : 0.0f;
    }
}

extern "C" void kernel_launch(void* const* d_in, const int* in_sizes, int n_in,
                              void* d_out, int out_size, void* d_ws, size_t ws_size,
                              hipStream_t stream)
{
    const float* f1  = (const float*)d_in[0];
    const float* f2  = (const float*)d_in[1];
    const float* kp1 = (const float*)d_in[2];
    const float* kp2 = (const float*)d_in[3];
    const float* sc1 = (const float*)d_in[4];
    const float* w1  = (const float*)d_in[5];
    const float* b1  = (const float*)d_in[6];
    const float* w2  = (const float*)d_in[7];
    const float* b2  = (const float*)d_in[8];
    const float* w3  = (const float*)d_in[9];
    const float* b3  = (const float*)d_in[10];
    const float* w4  = (const float*)d_in[11];
    const float* b4  = (const float*)d_in[12];
    const float* w5  = (const float*)d_in[13];
    const float* b5  = (const float*)d_in[14];

    char* ws = (char*)d_ws;
    ull* rowfin = (ull*)(ws + OFF_ROWFIN);
    ull* colfin = (ull*)(ws + OFF_COLFIN);
    u16* wt     = (u16*)(ws + OFF_WT);
    u16* f1t    = (u16*)(ws + OFF_F1T);
    u16* f2t    = (u16*)(ws + OFF_F2T);
    u16* rbm    = (u16*)(ws + OFF_RBM);
    u16* cbm    = (u16*)(ws + OFF_CBM);
    int* cntR   = (int*)(ws + OFF_CNTR);
    int* cntC   = (int*)(ws + OFF_CNTC);
    int* listR  = (int*)(ws + OFF_LISTR);
    int* listC  = (int*)(ws + OFF_LISTC);
    float* out  = (float*)d_out;

    prep_kernel<<<(2 * BB * NN * DD) / 256, 256, 0, stream>>>(
        w1, w2, w3, w4, w5, f1, f2, wt, f1t, f2t, rowfin, cntR);

    dim3 gS(48, 24, BB);
    simb_kernel<<<gS, 256, 0, stream>>>(f1t, f2t, rbm, cbm);

    dim3 gScan((BB * NN) / 256, 2);
    scan_kernel<<<gScan, 256, 0, stream>>>(rbm, cbm, cntR, cntC, listR, listC);

    dim3 gR(BB * 48, RSPLIT, 2);
    refine_kernel<<<gR, 256, 0, stream>>>(f1, f2, cntR, cntC, listR, listC,
                                          rowfin, colfin);

    mlp_mfma_kernel<<<(BB * NN) / 64, 512, 0, stream>>>(
        f1, f2, kp1, kp2, sc1, b1, b2, b3, b4, b5, wt, rowfin, colfin, out);
}

// Round 10
// 199.922 us; speedup vs baseline: 3.3241x; 1.0482x over previous
//
#include <hip/hip_runtime.h>
#include <cstddef>
#include <cstdint>

#define BB 4
#define NN 6144
#define DD 64
#define HID 512
#define OUTD 64
#define CAP 512
#define RSPLIT 4

typedef unsigned long long ull;
typedef unsigned int u32;
typedef unsigned short u16;
typedef __attribute__((ext_vector_type(8))) short short8_t;
typedef __attribute__((ext_vector_type(4))) float floatx4;
typedef __attribute__((ext_vector_type(4))) unsigned short ushort4_t;

// ---- ws layout (byte offsets) ----
#define OFF_ROWFIN 0
#define OFF_COLFIN 196608
#define OFF_WT     393216
#define OFF_F1T    2162688
#define OFF_F2T    5308416
#define OFF_RBM    8454144
#define OFF_CBM    10813440
#define OFF_CNTR   13172736
#define OFF_CNTC   13173504
#define OFF_LISTR  13174272
#define OFF_LISTC  13567488

#define WT1_OFF 0
#define WT2_OFF 65536
#define WT3_OFF 327680
#define WT4_OFF 589824
#define WT5_OFF 851968
#define WT_TOTAL 884736

__device__ __forceinline__ unsigned int fkey(float v) {
    unsigned int u = __float_as_uint(v);
    return (u & 0x80000000u) ? ~u : (u | 0x80000000u);
}

__device__ __forceinline__ float inv16(u32 k16) {
    u32 u = k16 << 16;
    return (u & 0x80000000u) ? __uint_as_float(u & 0x7fffffffu)
                             : __uint_as_float(~u);
}

__device__ __forceinline__ u16 f2bf(float f) {
    unsigned int u = __float_as_uint(f);
    u += 0x7FFFu + ((u >> 16) & 1u);
    return (u16)(u >> 16);
}

// ---- prep: ws init + weights->bf16 tiled + feats->bf16 tiled, one launch ----
__global__ __launch_bounds__(256) void prep_kernel(
    const float* __restrict__ w1, const float* __restrict__ w2,
    const float* __restrict__ w3, const float* __restrict__ w4,
    const float* __restrict__ w5,
    const float* __restrict__ f1, const float* __restrict__ f2,
    u16* __restrict__ wt, u16* __restrict__ f1t, u16* __restrict__ f2t,
    ull* __restrict__ finals, int* __restrict__ cnts)
{
    int idx = blockIdx.x * 256 + threadIdx.x;

    if (idx < 2 * BB * NN) finals[idx] = 0ULL;
    if (idx < 384) cnts[idx] = 0;

    if (idx < WT_TOTAL) {
        const float* w; u16* o; int K, nsh, li;
        if (idx < 65536)        { w = w1; o = wt + WT1_OFF; K = 128; nsh = 9; li = idx; }
        else if (idx < 327680)  { w = w2; o = wt + WT2_OFF; K = 512; nsh = 9; li = idx - 65536; }
        else if (idx < 589824)  { w = w3; o = wt + WT3_OFF; K = 512; nsh = 9; li = idx - 327680; }
        else if (idx < 851968)  { w = w4; o = wt + WT4_OFF; K = 512; nsh = 9; li = idx - 589824; }
        else                    { w = w5; o = wt + WT5_OFF; K = 512; nsh = 6; li = idx - 851968; }
        int k = li >> nsh;
        int n = li & ((1 << nsh) - 1);
        u16 v = f2bf(w[li]);
        int lane = (n & 15) | (((k >> 3) & 3) << 4);
        o[(((n >> 4) * (K >> 5) + (k >> 5)) * 64 + lane) * 8 + (k & 7)] = v;
    }

    {
        const int TE = BB * NN * DD;
        const float* src; u16* dst; int e;
        if (idx < TE) { src = f1; dst = f1t; e = idx; }
        else          { src = f2; dst = f2t; e = idx - TE; }
        int k  = e & 63;
        int rn = e >> 6;
        int b  = rn / NN;
        int r  = rn - b * NN;
        int R  = r >> 7, rb = (r >> 4) & 7;
        int kb = k >> 5, lane = (r & 15) | (((k >> 3) & 3) << 4), j = k & 7;
        dst[(size_t)(b * 48 + R) * 8192 + ((rb * 2 + kb) * 64 + lane) * 8 + j] = f2bf(src[e]);
    }
}

// ---- Kernel A: bf16 MFMA sim, 128x256 tile, block maxima -> rbm/cbm ----
__global__ __launch_bounds__(256, 2) void simb_kernel(
    const u16* __restrict__ f1t, const u16* __restrict__ f2t,
    u16* __restrict__ rbm, u16* __restrict__ cbm)
{
    __shared__ __align__(16) u16 sA[8192];
    __shared__ __align__(16) u16 sB[16384];
    __shared__ float cv[2][2][128];
    const int R = blockIdx.x, C2 = blockIdx.y, b = blockIdx.z;
    const int t = threadIdx.x, lane = t & 63, w = t >> 6;
    const int wr = w >> 1, wc = w & 1;
    const int l15 = lane & 15, l4 = lane >> 4;

    const u16* Ag = f1t + (size_t)(b * 48 + R) * 8192;
    const u16* Bg = f2t + (size_t)(b * 48 + C2 * 2) * 8192;

    #pragma unroll
    for (int rnd = 0; rnd < 4; ++rnd) {
        int c = rnd * 256 + t;
        *reinterpret_cast<uint4*>(&sA[c * 8]) = *reinterpret_cast<const uint4*>(Ag + c * 8);
    }
    #pragma unroll
    for (int rnd = 0; rnd < 8; ++rnd) {
        int c = rnd * 256 + t;
        *reinterpret_cast<uint4*>(&sB[c * 8]) = *reinterpret_cast<const uint4*>(Bg + c * 8);
    }
    __syncthreads();

    floatx4 acc[4][8];
    #pragma unroll
    for (int i = 0; i < 4; ++i)
        #pragma unroll
        for (int j = 0; j < 8; ++j) acc[i][j] = (floatx4)(0.0f);

    #pragma unroll
    for (int kb = 0; kb < 2; ++kb) {
        short8_t afr[4], bfr[8];
        #pragma unroll
        for (int i = 0; i < 4; ++i)
            afr[i] = *reinterpret_cast<const short8_t*>(
                &sA[(((wr * 4 + i) * 2 + kb) * 64 + lane) * 8]);
        #pragma unroll
        for (int j = 0; j < 8; ++j) {
            int cb = wc * 8 + j;
            bfr[j] = *reinterpret_cast<const short8_t*>(
                &sB[(cb >> 3) * 8192 + (((cb & 7) * 2 + kb) * 64 + lane) * 8]);
        }
        #pragma unroll
        for (int i = 0; i < 4; ++i)
            #pragma unroll
            for (int j = 0; j < 8; ++j)
                acc[i][j] = __builtin_amdgcn_mfma_f32_16x16x32_bf16(
                    afr[i], bfr[j], acc[i][j], 0, 0, 0);
    }

    const int Cme = C2 * 2 + wc;
    #pragma unroll
    for (int i = 0; i < 4; ++i) {
        #pragma unroll
        for (int reg = 0; reg < 4; ++reg) {
            float v = acc[i][0][reg];
            #pragma unroll
            for (int j = 1; j < 8; ++j) v = fmaxf(v, acc[i][j][reg]);
            v = fmaxf(v, __shfl_xor(v, 1));
            v = fmaxf(v, __shfl_xor(v, 2));
            v = fmaxf(v, __shfl_xor(v, 4));
            v = fmaxf(v, __shfl_xor(v, 8));
            if (l15 == 0) {
                int row = R * 128 + wr * 64 + i * 16 + l4 * 4 + reg;
                rbm[((size_t)b * NN + row) * 48 + Cme] = (u16)(fkey(v) >> 16);
            }
        }
    }

    #pragma unroll
    for (int j = 0; j < 8; ++j) {
        float v = acc[0][j][0];
        #pragma unroll
        for (int i = 0; i < 4; ++i)
            #pragma unroll
            for (int reg = 0; reg < 4; ++reg) v = fmaxf(v, acc[i][j][reg]);
        v = fmaxf(v, __shfl_xor(v, 16));
        v = fmaxf(v, __shfl_xor(v, 32));
        if (l4 == 0) cv[wc][wr][j * 16 + l15] = v;
    }
    __syncthreads();
    {
        int wcc = t >> 7, col0 = t & 127;
        float v = fmaxf(cv[wcc][0][col0], cv[wcc][1][col0]);
        int col = C2 * 256 + wcc * 128 + col0;
        cbm[((size_t)b * NN + col) * 48 + R] = (u16)(fkey(v) >> 16);
    }
}

// ---- scan (merged row/col via blockIdx.y): block-aggregated candidate append ----
__global__ __launch_bounds__(256) void scan_kernel(
    const u16* __restrict__ rbm, const u16* __restrict__ cbm,
    int* __restrict__ cntR, int* __restrict__ cntC,
    int* __restrict__ listR, int* __restrict__ listC)
{
    const u16* bm = blockIdx.y ? cbm : rbm;
    int* cnt  = blockIdx.y ? cntC : cntR;
    int* list = blockIdx.y ? listC : listR;

    __shared__ int lcnt[48];
    __shared__ int lbase[48];
    const int t = threadIdx.x;
    if (t < 48) lcnt[t] = 0;
    const int idx = blockIdx.x * 256 + t;
    const int b = (blockIdx.x * 256) / NN;
    const int n = idx - b * NN;

    u16 ks[48];
    const uint4* p4 = reinterpret_cast<const uint4*>(bm + (size_t)idx * 48);
    #pragma unroll
    for (int q = 0; q < 6; ++q) {
        uint4 u = p4[q];
        ks[q * 8 + 0] = (u16)(u.x & 0xffff); ks[q * 8 + 1] = (u16)(u.x >> 16);
        ks[q * 8 + 2] = (u16)(u.y & 0xffff); ks[q * 8 + 3] = (u16)(u.y >> 16);
        ks[q * 8 + 4] = (u16)(u.z & 0xffff); ks[q * 8 + 5] = (u16)(u.z >> 16);
        ks[q * 8 + 6] = (u16)(u.w & 0xffff); ks[q * 8 + 7] = (u16)(u.w >> 16);
    }
    u16 mx = 0;
    #pragma unroll
    for (int c = 0; c < 48; ++c) mx = ks[c] > mx ? ks[c] : mx;
    float thr = inv16(mx) - 0.024f;   // >= 1.5x worst-case bf16 error bound
    u32 m0 = 0, m1 = 0;
    #pragma unroll
    for (int c = 0; c < 48; ++c) {
        if (inv16((u32)ks[c] + 1) >= thr) {
            if (c < 32) m0 |= 1u << c; else m1 |= 1u << (c - 32);
        }
    }
    __syncthreads();
    {
        u32 a = m0;
        while (a) { int c = __builtin_ctz(a); a &= a - 1; atomicAdd(&lcnt[c], 1); }
        a = m1;
        while (a) { int c = 32 + __builtin_ctz(a); a &= a - 1; atomicAdd(&lcnt[c], 1); }
    }
    __syncthreads();
    if (t < 48) { lbase[t] = atomicAdd(&cnt[b * 48 + t], lcnt[t]); lcnt[t] = 0; }
    __syncthreads();
    {
        u32 a = m0;
        while (a) {
            int c = __builtin_ctz(a); a &= a - 1;
            int pos = lbase[c] + atomicAdd(&lcnt[c], 1);
            if (pos < CAP) list[(b * 48 + c) * CAP + pos] = n;
        }
        a = m1;
        while (a) {
            int c = 32 + __builtin_ctz(a); a &= a - 1;
            int pos = lbase[c] + atomicAdd(&lcnt[c], 1);
            if (pos < CAP) list[(b * 48 + c) * CAP + pos] = n;
        }
    }
}

// ---- exact fp32 refine (merged row/col via blockIdx.z) ----
__global__ __launch_bounds__(256, 2) void refine_kernel(
    const float* __restrict__ f1, const float* __restrict__ f2,
    const int* __restrict__ cntR, const int* __restrict__ cntC,
    const int* __restrict__ listR, const int* __restrict__ listC,
    ull* __restrict__ rowfin, ull* __restrict__ colfin)
{
    const float* qfeat = blockIdx.z ? f2 : f1;
    const float* tfeat = blockIdx.z ? f1 : f2;
    const int* cnt  = blockIdx.z ? cntC : cntR;
    const int* list = blockIdx.z ? listC : listR;
    ull* fin = blockIdx.z ? colfin : rowfin;

    const int b = blockIdx.x / 48;
    const int C = blockIdx.x - b * 48;
    const int sub = blockIdx.y;
    int n_items = cnt[b * 48 + C];
    if (n_items > CAP) n_items = CAP;
    int chunk = (n_items + RSPLIT - 1) / RSPLIT;
    int lo = sub * chunk;
    int hi = lo + chunk; if (hi > n_items) hi = n_items;
    if (lo >= hi) return;

    __shared__ float s2f[128 * 68];
    const int t = threadIdx.x;
    const float* tb = tfeat + ((size_t)b * NN + C * 128) * 64;
    #pragma unroll
    for (int p = 0; p < 8; ++p) {
        int idx = p * 256 + t;
        int row = idx >> 4, c4 = idx & 15;
        *reinterpret_cast<float4*>(&s2f[row * 68 + c4 * 4]) =
            *reinterpret_cast<const float4*>(tb + row * 64 + c4 * 4);
    }
    __syncthreads();
    const int rs = t >> 4, cg = t & 15;
    const int* mylist = list + (b * 48 + C) * CAP;
    for (int base = lo; base < hi; base += 16) {
        int li = base + rs;
        bool valid = li < hi;
        int n = valid ? mylist[li] : mylist[lo];
        const float* q = qfeat + ((size_t)b * NN + n) * 64;
        float dot[8];
        #pragma unroll
        for (int c8 = 0; c8 < 8; ++c8) dot[c8] = 0.0f;
        #pragma unroll 4
        for (int kq = 0; kq < 16; ++kq) {
            float4 a4 = *reinterpret_cast<const float4*>(q + kq * 4);
            #pragma unroll
            for (int c8 = 0; c8 < 8; ++c8) {
                float4 s4 = *reinterpret_cast<const float4*>(&s2f[(cg + 16 * c8) * 68 + kq * 4]);
                dot[c8] = fmaf(a4.x, s4.x, dot[c8]);
                dot[c8] = fmaf(a4.y, s4.y, dot[c8]);
                dot[c8] = fmaf(a4.z, s4.z, dot[c8]);
                dot[c8] = fmaf(a4.w, s4.w, dot[c8]);
            }
        }
        float bv = dot[0]; int bc = cg;
        #pragma unroll
        for (int c8 = 1; c8 < 8; ++c8) {
            if (dot[c8] > bv) { bv = dot[c8]; bc = cg + 16 * c8; }
        }
        ull pk = ((ull)fkey(bv) << 32) | (u32)(~(u32)(C * 128 + bc));
        ull qq;
        qq = __shfl_xor(pk, 1); pk = pk > qq ? pk : qq;
        qq = __shfl_xor(pk, 2); pk = pk > qq ? pk : qq;
        qq = __shfl_xor(pk, 4); pk = pk > qq ? pk : qq;
        qq = __shfl_xor(pk, 8); pk = pk > qq ? pk : qq;
        if (cg == 0 && valid) atomicMax(&fin[(size_t)b * NN + n], pk);
    }
}

// ---- Kernel B: bf16 MFMA MLP, 512 threads / 8 waves, 64ch-slice per wave,
//      per-wave kb STAGGER (anti-convoy) + setprio + 3-buffer prefetch ----

// One step: MFMA cluster for staggered index KB2, then prefetch KB2+3's weights
#define MLP_STEP(BUF, KB)                                                      \
    {                                                                          \
        const int kb2 = ((KB) + woff) & (NKB - 1);                             \
        __builtin_amdgcn_s_setprio(1);                                         \
        _Pragma("unroll")                                                      \
        for (int jb = 0; jb < 4; ++jb) {                                       \
            int pt = jb * 16 + l15;                                            \
            int chk = (kb2 * 4 + l4) ^ (pt & 7);                               \
            short8_t bfr = *reinterpret_cast<const short8_t*>(                 \
                act + (pt * 64 + chk) * 8);                                    \
            _Pragma("unroll")                                                  \
            for (int ia = 0; ia < 4; ++ia)                                     \
                acc[ia][jb] = __builtin_amdgcn_mfma_f32_16x16x32_bf16(         \
                    BUF[ia], bfr, acc[ia][jb], 0, 0, 0);                       \
        }                                                                      \
        __builtin_amdgcn_s_setprio(0);                                         \
        if ((KB) + 3 < NKB) {                                                  \
            const int kbp = ((KB) + 3 + woff) & (NKB - 1);                     \
            _Pragma("unroll")                                                  \
            for (int ia = 0; ia < 4; ++ia)                                     \
                BUF[ia] = *reinterpret_cast<const short8_t*>(                  \
                    wt + (((chBlk0 + ia) * NKB + kbp) * 64 + lane) * 8);       \
        }                                                                      \
    }

template<int K>
__device__ __forceinline__ void mlp_layer8(
    u16* act, const u16* __restrict__ wt,
    const float* __restrict__ bias, int lane, int wid)
{
    constexpr int NKB = K / 32;
    floatx4 acc[4][4];
    #pragma unroll
    for (int ia = 0; ia < 4; ++ia)
        #pragma unroll
        for (int jb = 0; jb < 4; ++jb)
            acc[ia][jb] = (floatx4)(0.0f);

    const int l15 = lane & 15, l4 = lane >> 4;
    const int chBlk0 = wid * 4;       // (wid*64)/16
    const int woff = (wid * 2) & (NKB - 1);   // per-wave kb stagger

    short8_t a0[4], a1[4], a2[4];
    #pragma unroll
    for (int ia = 0; ia < 4; ++ia)
        a0[ia] = *reinterpret_cast<const short8_t*>(
            wt + (((chBlk0 + ia) * NKB + ((0 + woff) & (NKB - 1))) * 64 + lane) * 8);
    #pragma unroll
    for (int ia = 0; ia < 4; ++ia)
        a1[ia] = *reinterpret_cast<const short8_t*>(
            wt + (((chBlk0 + ia) * NKB + ((1 + woff) & (NKB - 1))) * 64 + lane) * 8);
    #pragma unroll
    for (int ia = 0; ia < 4; ++ia)
        a2[ia] = *reinterpret_cast<const short8_t*>(
            wt + (((chBlk0 + ia) * NKB + ((2 + woff) & (NKB - 1))) * 64 + lane) * 8);

    #pragma unroll
    for (int kb = 0; kb < NKB; ++kb) {
        if ((kb % 3) == 0)      MLP_STEP(a0, kb)
        else if ((kb % 3) == 1) MLP_STEP(a1, kb)
        else                    MLP_STEP(a2, kb)
    }
    __syncthreads();   // all reads done before in-place overwrite

    const int ch0 = wid * 64;
    #pragma unroll
    for (int ia = 0; ia < 4; ++ia) {
        int cb = ia * 16 + l4 * 4;
        float4 bv = *reinterpret_cast<const float4*>(bias + ch0 + cb);
        #pragma unroll
        for (int jb = 0; jb < 4; ++jb) {
            int pt = jb * 16 + l15;
            ushort4_t h;
            h[0] = f2bf(fmaxf(acc[ia][jb][0] + bv.x, 0.0f));
            h[1] = f2bf(fmaxf(acc[ia][jb][1] + bv.y, 0.0f));
            h[2] = f2bf(fmaxf(acc[ia][jb][2] + bv.z, 0.0f));
            h[3] = f2bf(fmaxf(acc[ia][jb][3] + bv.w, 0.0f));
            int chk = ((ch0 + cb) >> 3) ^ (pt & 7);
            *reinterpret_cast<ushort4_t*>(act + (pt * 64 + chk) * 8 + (cb & 7)) = h;
        }
    }
    __syncthreads();
}

__global__ __launch_bounds__(512, 2) void mlp_mfma_kernel(
    const float* __restrict__ f1, const float* __restrict__ f2,
    const float* __restrict__ kps1, const float* __restrict__ kps2,
    const float* __restrict__ scales1,
    const float* __restrict__ b1, const float* __restrict__ b2,
    const float* __restrict__ b3, const float* __restrict__ b4,
    const float* __restrict__ b5,
    const u16* __restrict__ wt,
    const ull* __restrict__ rowfin, const ull* __restrict__ colfin,
    float* __restrict__ out)
{
    __shared__ __align__(16) unsigned char lds_raw[65536];
    u16* act = reinterpret_cast<u16*>(lds_raw);
    float* logf = reinterpret_cast<float*>(lds_raw);

    const int t = threadIdx.x;
    const int lane = t & 63, wid = t >> 6;
    const int base = blockIdx.x * 64;
    const int b = base / NN;
    const int n0 = base % NN;

    // stage concat(f1[n], f2[match12[n]]) as bf16, swizzled; 512 threads
    {
        const int pt = t & 63, seg = t >> 6;   // 8 segs * 16 floats
        const int n = n0 + pt;
        ull rm = rowfin[(size_t)b * NN + n];
        const int m = (int)(~(unsigned int)(rm & 0xffffffffULL));
        const float* src = (seg < 4)
            ? (f1 + ((size_t)b * NN + n) * DD + seg * 16)
            : (f2 + ((size_t)b * NN + m) * DD + (seg - 4) * 16);
        #pragma unroll
        for (int q = 0; q < 2; ++q) {
            float4 v0 = *reinterpret_cast<const float4*>(src + q * 8);
            float4 v1 = *reinterpret_cast<const float4*>(src + q * 8 + 4);
            short8_t h;
            h[0] = (short)f2bf(v0.x); h[1] = (short)f2bf(v0.y);
            h[2] = (short)f2bf(v0.z); h[3] = (short)f2bf(v0.w);
            h[4] = (short)f2bf(v1.x); h[5] = (short)f2bf(v1.y);
            h[6] = (short)f2bf(v1.z); h[7] = (short)f2bf(v1.w);
            int chk = (seg * 2 + q) ^ (pt & 7);
            *reinterpret_cast<short8_t*>(act + (pt * 64 + chk) * 8) = h;
        }
    }
    __syncthreads();

    mlp_layer8<128>(act, wt + WT1_OFF, b1, lane, wid);
    mlp_layer8<512>(act, wt + WT2_OFF, b2, lane, wid);
    mlp_layer8<512>(act, wt + WT3_OFF, b3, lane, wid);
    mlp_layer8<512>(act, wt + WT4_OFF, b4, lane, wid);

    // layer 5: 512 -> 64, no relu; waves 0-3 handle 16 out-ch each (staggered kb)
    {
        const int l15 = lane & 15, l4 = lane >> 4;
        floatx4 acc5[4];
        #pragma unroll
        for (int jb = 0; jb < 4; ++jb) acc5[jb] = (floatx4)(0.0f);
        if (wid < 4) {
            const int woff5 = (wid * 4) & 15;
            short8_t a_cur = *reinterpret_cast<const short8_t*>(
                wt + WT5_OFF + ((wid * 16 + woff5) * 64 + lane) * 8);
            short8_t a_nxt;
            #pragma unroll
            for (int kb = 0; kb < 16; ++kb) {
                const int kb2 = (kb + woff5) & 15;
                if (kb + 1 < 16) {
                    const int kbn = (kb + 1 + woff5) & 15;
                    a_nxt = *reinterpret_cast<const short8_t*>(
                        wt + WT5_OFF + ((wid * 16 + kbn) * 64 + lane) * 8);
                }
                __builtin_amdgcn_s_setprio(1);
                #pragma unroll
                for (int jb = 0; jb < 4; ++jb) {
                    int pt = jb * 16 + l15;
                    int chk = (kb2 * 4 + l4) ^ (pt & 7);
                    short8_t bfr = *reinterpret_cast<const short8_t*>(act + (pt * 64 + chk) * 8);
                    acc5[jb] = __builtin_amdgcn_mfma_f32_16x16x32_bf16(
                        a_cur, bfr, acc5[jb], 0, 0, 0);
                }
                __builtin_amdgcn_s_setprio(0);
                if (kb + 1 < 16) a_cur = a_nxt;
            }
        }
        __syncthreads();   // all act reads done; lds_raw becomes logits f32
        if (wid < 4) {
            int cb = wid * 16 + l4 * 4;
            float4 bv = *reinterpret_cast<const float4*>(b5 + cb);
            #pragma unroll
            for (int jb = 0; jb < 4; ++jb) {
                int pt = jb * 16 + l15;
                float4 o;
                o.x = acc5[jb][0] + bv.x;
                o.y = acc5[jb][1] + bv.y;
                o.z = acc5[jb][2] + bv.z;
                o.w = acc5[jb][3] + bv.w;
                *reinterpret_cast<float4*>(&logf[pt * 68 + cb]) = o;
            }
        }
        __syncthreads();
    }

    if (t < 64) {
        const int pt = t;
        const int n = n0 + pt;
        const float* lrow = &logf[pt * 68];
        float mx = -1e30f;
        #pragma unroll 8
        for (int j = 0; j < OUTD; ++j) mx = fmaxf(mx, 3.0f * lrow[j]);
        float s = 0.0f, cx = 0.0f, cy = 0.0f;
        #pragma unroll 8
        for (int j = 0; j < OUTD; ++j) {
            float e = __expf(3.0f * lrow[j] - mx);
            s  += e;
            cx += e * (float)((j & 7) - 4);
            cy += e * (float)((j >> 3) - 4);
        }
        float conf = 1.0f / s;
        cx /= s; cy /= s;
        ull rm = rowfin[(size_t)b * NN + n];
        int m = (int)(~(unsigned int)(rm & 0xffffffffULL));
        ull cm = colfin[(size_t)b * NN + m];
        int back = (int)(~(unsigned int)(cm & 0xffffffffULL));
        bool mutual = (back == n);
        float sc = scales1[(size_t)b * NN + n];
        float x0 = kps1[((size_t)b * NN + n) * 2 + 0] + cx * sc;
        float y0 = kps1[((size_t)b * NN + n) * 2 + 1] + cy * sc;
        float x1 = kps2[((size_t)b * NN + m) * 2 + 0];
        float y1 = kps2[((size_t)b * NN + m) * 2 + 1];
        float* mt = out + ((size_t)b * NN + n) * 4;
        mt[0] = x0; mt[1] = y0; mt[2] = x1; mt[3] = y1;
        out[(size_t)BB * NN * 4 + (size_t)b * NN + n] =
            (mutual && conf > 0.25f) ? 1.0f : 0.0f;
    }
}

extern "C" void kernel_launch(void* const* d_in, const int* in_sizes, int n_in,
                              void* d_out, int out_size, void* d_ws, size_t ws_size,
                              hipStream_t stream)
{
    const float* f1  = (const float*)d_in[0];
    const float* f2  = (const float*)d_in[1];
    const float* kp1 = (const float*)d_in[2];
    const float* kp2 = (const float*)d_in[3];
    const float* sc1 = (const float*)d_in[4];
    const float* w1  = (const float*)d_in[5];
    const float* b1  = (const float*)d_in[6];
    const float* w2  = (const float*)d_in[7];
    const float* b2  = (const float*)d_in[8];
    const float* w3  = (const float*)d_in[9];
    const float* b3  = (const float*)d_in[10];
    const float* w4  = (const float*)d_in[11];
    const float* b4  = (const float*)d_in[12];
    const float* w5  = (const float*)d_in[13];
    const float* b5  = (const float*)d_in[14];

    char* ws = (char*)d_ws;
    ull* rowfin = (ull*)(ws + OFF_ROWFIN);
    ull* colfin = (ull*)(ws + OFF_COLFIN);
    u16* wt     = (u16*)(ws + OFF_WT);
    u16* f1t    = (u16*)(ws + OFF_F1T);
    u16* f2t    = (u16*)(ws + OFF_F2T);
    u16* rbm    = (u16*)(ws + OFF_RBM);
    u16* cbm    = (u16*)(ws + OFF_CBM);
    int* cntR   = (int*)(ws + OFF_CNTR);
    int* cntC   = (int*)(ws + OFF_CNTC);
    int* listR  = (int*)(ws + OFF_LISTR);
    int* listC  = (int*)(ws + OFF_LISTC);
    float* out  = (float*)d_out;

    prep_kernel<<<(2 * BB * NN * DD) / 256, 256, 0, stream>>>(
        w1, w2, w3, w4, w5, f1, f2, wt, f1t, f2t, rowfin, cntR);

    dim3 gS(48, 24, BB);
    simb_kernel<<<gS, 256, 0, stream>>>(f1t, f2t, rbm, cbm);

    dim3 gScan((BB * NN) / 256, 2);
    scan_kernel<<<gScan, 256, 0, stream>>>(rbm, cbm, cntR, cntC, listR, listC);

    dim3 gR(BB * 48, RSPLIT, 2);
    refine_kernel<<<gR, 256, 0, stream>>>(f1, f2, cntR, cntC, listR, listC,
                                          rowfin, colfin);

    mlp_mfma_kernel<<<(BB * NN) / 64, 512, 0, stream>>>(
        f1, f2, kp1, kp2, sc1, b1, b2, b3, b4, b5, wt, rowfin, colfin, out);
}

// Round 11
// 175.553 us; speedup vs baseline: 3.7855x; 1.1388x over previous
//
#include <hip/hip_runtime.h>
#include <cstddef>
#include <cstdint>

#define BB 4
#define NN 6144
#define DD 64
#define HID 512
#define OUTD 64
#define CAP 512
#define RSPLIT 8

typedef unsigned long long ull;
typedef unsigned int u32;
typedef unsigned short u16;
typedef unsigned char u8;
typedef __attribute__((ext_vector_type(8))) short short8_t;
typedef __attribute__((ext_vector_type(4))) float floatx4;

// ---- ws layout (byte offsets) ----
#define OFF_ROWFIN 0
#define OFF_COLFIN 196608
#define OFF_WT     393216
#define OFF_F1T    2162688
#define OFF_F2T    5308416
#define OFF_RBM    8454144
#define OFF_CBM    10813440
#define OFF_CNTR   13172736
#define OFF_CNTC   13173504
#define OFF_LISTR  13174272
#define OFF_LISTC  13567488

#define WT1_OFF 0
#define WT2_OFF 65536
#define WT3_OFF 327680
#define WT4_OFF 589824
#define WT5_OFF 851968
#define WT_TOTAL 884736

__device__ __forceinline__ unsigned int fkey(float v) {
    unsigned int u = __float_as_uint(v);
    return (u & 0x80000000u) ? ~u : (u | 0x80000000u);
}

__device__ __forceinline__ float inv16(u32 k16) {
    u32 u = k16 << 16;
    return (u & 0x80000000u) ? __uint_as_float(u & 0x7fffffffu)
                             : __uint_as_float(~u);
}

__device__ __forceinline__ u16 f2bf(float f) {
    unsigned int u = __float_as_uint(f);
    u += 0x7FFFu + ((u >> 16) & 1u);
    return (u16)(u >> 16);
}

// two floats -> two fp8 (chip-native fp8; self-consistent with fp8 MFMA)
__device__ __forceinline__ u32 f2fp8x2(float a, float b) {
    return (u32)__builtin_amdgcn_cvt_pk_fp8_f32(a, b, 0, false) & 0xffffu;
}

// ---- prep: ws init + weights->fp8 tiled + feats->bf16 tiled ----
__global__ __launch_bounds__(256) void prep_kernel(
    const float* __restrict__ w1, const float* __restrict__ w2,
    const float* __restrict__ w3, const float* __restrict__ w4,
    const float* __restrict__ w5,
    const float* __restrict__ f1, const float* __restrict__ f2,
    u8* __restrict__ wt8, u16* __restrict__ f1t, u16* __restrict__ f2t,
    ull* __restrict__ finals, int* __restrict__ cnts)
{
    int idx = blockIdx.x * 256 + threadIdx.x;

    if (idx < 2 * BB * NN) finals[idx] = 0ULL;
    if (idx < 384) cnts[idx] = 0;

    if (idx < WT_TOTAL) {
        const float* w; u8* o; int K, nsh, li;
        if (idx < 65536)        { w = w1; o = wt8 + WT1_OFF; K = 128; nsh = 9; li = idx; }
        else if (idx < 327680)  { w = w2; o = wt8 + WT2_OFF; K = 512; nsh = 9; li = idx - 65536; }
        else if (idx < 589824)  { w = w3; o = wt8 + WT3_OFF; K = 512; nsh = 9; li = idx - 327680; }
        else if (idx < 851968)  { w = w4; o = wt8 + WT4_OFF; K = 512; nsh = 9; li = idx - 589824; }
        else                    { w = w5; o = wt8 + WT5_OFF; K = 512; nsh = 6; li = idx - 851968; }
        int k = li >> nsh;
        int n = li & ((1 << nsh) - 1);
        u8 v = (u8)(f2fp8x2(w[li], 0.0f) & 0xff);
        int lane = (n & 15) | (((k >> 3) & 3) << 4);
        o[(((size_t)(n >> 4) * (K >> 5) + (k >> 5)) * 64 + lane) * 8 + (k & 7)] = v;
    }

    {
        const int TE = BB * NN * DD;
        const float* src; u16* dst; int e;
        if (idx < TE) { src = f1; dst = f1t; e = idx; }
        else          { src = f2; dst = f2t; e = idx - TE; }
        int k  = e & 63;
        int rn = e >> 6;
        int b  = rn / NN;
        int r  = rn - b * NN;
        int R  = r >> 7, rb = (r >> 4) & 7;
        int kb = k >> 5, lane = (r & 15) | (((k >> 3) & 3) << 4), j = k & 7;
        dst[(size_t)(b * 48 + R) * 8192 + ((rb * 2 + kb) * 64 + lane) * 8 + j] = f2bf(src[e]);
    }
}

// ---- Kernel A: bf16 MFMA sim, 128x256 tile, block maxima -> rbm/cbm ----
__global__ __launch_bounds__(256, 2) void simb_kernel(
    const u16* __restrict__ f1t, const u16* __restrict__ f2t,
    u16* __restrict__ rbm, u16* __restrict__ cbm)
{
    __shared__ __align__(16) u16 sA[8192];
    __shared__ __align__(16) u16 sB[16384];
    __shared__ float cv[2][2][128];
    const int R = blockIdx.x, C2 = blockIdx.y, b = blockIdx.z;
    const int t = threadIdx.x, lane = t & 63, w = t >> 6;
    const int wr = w >> 1, wc = w & 1;
    const int l15 = lane & 15, l4 = lane >> 4;

    const u16* Ag = f1t + (size_t)(b * 48 + R) * 8192;
    const u16* Bg = f2t + (size_t)(b * 48 + C2 * 2) * 8192;

    #pragma unroll
    for (int rnd = 0; rnd < 4; ++rnd) {
        int c = rnd * 256 + t;
        *reinterpret_cast<uint4*>(&sA[c * 8]) = *reinterpret_cast<const uint4*>(Ag + c * 8);
    }
    #pragma unroll
    for (int rnd = 0; rnd < 8; ++rnd) {
        int c = rnd * 256 + t;
        *reinterpret_cast<uint4*>(&sB[c * 8]) = *reinterpret_cast<const uint4*>(Bg + c * 8);
    }
    __syncthreads();

    floatx4 acc[4][8];
    #pragma unroll
    for (int i = 0; i < 4; ++i)
        #pragma unroll
        for (int j = 0; j < 8; ++j) acc[i][j] = (floatx4)(0.0f);

    #pragma unroll
    for (int kb = 0; kb < 2; ++kb) {
        short8_t afr[4], bfr[8];
        #pragma unroll
        for (int i = 0; i < 4; ++i)
            afr[i] = *reinterpret_cast<const short8_t*>(
                &sA[(((wr * 4 + i) * 2 + kb) * 64 + lane) * 8]);
        #pragma unroll
        for (int j = 0; j < 8; ++j) {
            int cb = wc * 8 + j;
            bfr[j] = *reinterpret_cast<const short8_t*>(
                &sB[(cb >> 3) * 8192 + (((cb & 7) * 2 + kb) * 64 + lane) * 8]);
        }
        #pragma unroll
        for (int i = 0; i < 4; ++i)
            #pragma unroll
            for (int j = 0; j < 8; ++j)
                acc[i][j] = __builtin_amdgcn_mfma_f32_16x16x32_bf16(
                    afr[i], bfr[j], acc[i][j], 0, 0, 0);
    }

    const int Cme = C2 * 2 + wc;
    #pragma unroll
    for (int i = 0; i < 4; ++i) {
        #pragma unroll
        for (int reg = 0; reg < 4; ++reg) {
            float v = acc[i][0][reg];
            #pragma unroll
            for (int j = 1; j < 8; ++j) v = fmaxf(v, acc[i][j][reg]);
            v = fmaxf(v, __shfl_xor(v, 1));
            v = fmaxf(v, __shfl_xor(v, 2));
            v = fmaxf(v, __shfl_xor(v, 4));
            v = fmaxf(v, __shfl_xor(v, 8));
            if (l15 == 0) {
                int row = R * 128 + wr * 64 + i * 16 + l4 * 4 + reg;
                rbm[((size_t)b * NN + row) * 48 + Cme] = (u16)(fkey(v) >> 16);
            }
        }
    }

    #pragma unroll
    for (int j = 0; j < 8; ++j) {
        float v = acc[0][j][0];
        #pragma unroll
        for (int i = 0; i < 4; ++i)
            #pragma unroll
            for (int reg = 0; reg < 4; ++reg) v = fmaxf(v, acc[i][j][reg]);
        v = fmaxf(v, __shfl_xor(v, 16));
        v = fmaxf(v, __shfl_xor(v, 32));
        if (l4 == 0) cv[wc][wr][j * 16 + l15] = v;
    }
    __syncthreads();
    {
        int wcc = t >> 7, col0 = t & 127;
        float v = fmaxf(cv[wcc][0][col0], cv[wcc][1][col0]);
        int col = C2 * 256 + wcc * 128 + col0;
        cbm[((size_t)b * NN + col) * 48 + R] = (u16)(fkey(v) >> 16);
    }
}

// ---- scan (merged row/col via blockIdx.y): block-aggregated candidate append ----
__global__ __launch_bounds__(256) void scan_kernel(
    const u16* __restrict__ rbm, const u16* __restrict__ cbm,
    int* __restrict__ cntR, int* __restrict__ cntC,
    int* __restrict__ listR, int* __restrict__ listC)
{
    const u16* bm = blockIdx.y ? cbm : rbm;
    int* cnt  = blockIdx.y ? cntC : cntR;
    int* list = blockIdx.y ? listC : listR;

    __shared__ int lcnt[48];
    __shared__ int lbase[48];
    const int t = threadIdx.x;
    if (t < 48) lcnt[t] = 0;
    const int idx = blockIdx.x * 256 + t;
    const int b = (blockIdx.x * 256) / NN;
    const int n = idx - b * NN;

    u16 ks[48];
    const uint4* p4 = reinterpret_cast<const uint4*>(bm + (size_t)idx * 48);
    #pragma unroll
    for (int q = 0; q < 6; ++q) {
        uint4 u = p4[q];
        ks[q * 8 + 0] = (u16)(u.x & 0xffff); ks[q * 8 + 1] = (u16)(u.x >> 16);
        ks[q * 8 + 2] = (u16)(u.y & 0xffff); ks[q * 8 + 3] = (u16)(u.y >> 16);
        ks[q * 8 + 4] = (u16)(u.z & 0xffff); ks[q * 8 + 5] = (u16)(u.z >> 16);
        ks[q * 8 + 6] = (u16)(u.w & 0xffff); ks[q * 8 + 7] = (u16)(u.w >> 16);
    }
    u16 mx = 0;
    #pragma unroll
    for (int c = 0; c < 48; ++c) mx = ks[c] > mx ? ks[c] : mx;
    float thr = inv16(mx) - 0.024f;   // >= 1.5x worst-case bf16 error bound
    u32 m0 = 0, m1 = 0;
    #pragma unroll
    for (int c = 0; c < 48; ++c) {
        if (inv16((u32)ks[c] + 1) >= thr) {
            if (c < 32) m0 |= 1u << c; else m1 |= 1u << (c - 32);
        }
    }
    __syncthreads();
    {
        u32 a = m0;
        while (a) { int c = __builtin_ctz(a); a &= a - 1; atomicAdd(&lcnt[c], 1); }
        a = m1;
        while (a) { int c = 32 + __builtin_ctz(a); a &= a - 1; atomicAdd(&lcnt[c], 1); }
    }
    __syncthreads();
    if (t < 48) { lbase[t] = atomicAdd(&cnt[b * 48 + t], lcnt[t]); lcnt[t] = 0; }
    __syncthreads();
    {
        u32 a = m0;
        while (a) {
            int c = __builtin_ctz(a); a &= a - 1;
            int pos = lbase[c] + atomicAdd(&lcnt[c], 1);
            if (pos < CAP) list[(b * 48 + c) * CAP + pos] = n;
        }
        a = m1;
        while (a) {
            int c = 32 + __builtin_ctz(a); a &= a - 1;
            int pos = lbase[c] + atomicAdd(&lcnt[c], 1);
            if (pos < CAP) list[(b * 48 + c) * CAP + pos] = n;
        }
    }
}

// ---- exact fp32 refine (merged row/col via blockIdx.z), LDS-staged queries ----
__global__ __launch_bounds__(256, 2) void refine_kernel(
    const float* __restrict__ f1, const float* __restrict__ f2,
    const int* __restrict__ cntR, const int* __restrict__ cntC,
    const int* __restrict__ listR, const int* __restrict__ listC,
    ull* __restrict__ rowfin, ull* __restrict__ colfin)
{
    const float* qfeat = blockIdx.z ? f2 : f1;
    const float* tfeat = blockIdx.z ? f1 : f2;
    const int* cnt  = blockIdx.z ? cntC : cntR;
    const int* list = blockIdx.z ? listC : listR;
    ull* fin = blockIdx.z ? colfin : rowfin;

    const int b = blockIdx.x / 48;
    const int C = blockIdx.x - b * 48;
    const int sub = blockIdx.y;
    int n_items = cnt[b * 48 + C];
    if (n_items > CAP) n_items = CAP;
    int chunk = (n_items + RSPLIT - 1) / RSPLIT;
    int lo = sub * chunk;
    int hi = lo + chunk; if (hi > n_items) hi = n_items;
    if (lo >= hi) return;

    __shared__ float s2f[128 * 68];
    __shared__ float sq[16 * 68];
    const int t = threadIdx.x;
    const float* tb = tfeat + ((size_t)b * NN + C * 128) * 64;
    #pragma unroll
    for (int p = 0; p < 8; ++p) {
        int idx = p * 256 + t;
        int row = idx >> 4, c4 = idx & 15;
        *reinterpret_cast<float4*>(&s2f[row * 68 + c4 * 4]) =
            *reinterpret_cast<const float4*>(tb + row * 64 + c4 * 4);
    }
    __syncthreads();
    const int rs = t >> 4, cg = t & 15;
    const int* mylist = list + (b * 48 + C) * CAP;
    for (int base = lo; base < hi; base += 16) {
        // stage 16 query rows (coalesced; one float4 per thread)
        {
            int lq = base + rs;
            int nn = (lq < hi) ? mylist[lq] : mylist[lo];
            *reinterpret_cast<float4*>(&sq[rs * 68 + cg * 4]) =
                *reinterpret_cast<const float4*>(qfeat + ((size_t)b * NN + nn) * 64 + cg * 4);
        }
        __syncthreads();

        int li = base + rs;
        bool valid = li < hi;
        int n = valid ? mylist[li] : mylist[lo];
        float dot[8];
        #pragma unroll
        for (int c8 = 0; c8 < 8; ++c8) dot[c8] = 0.0f;
        #pragma unroll 4
        for (int kq = 0; kq < 16; ++kq) {
            float4 a4 = *reinterpret_cast<const float4*>(&sq[rs * 68 + kq * 4]);
            #pragma unroll
            for (int c8 = 0; c8 < 8; ++c8) {
                float4 s4 = *reinterpret_cast<const float4*>(&s2f[(cg + 16 * c8) * 68 + kq * 4]);
                dot[c8] = fmaf(a4.x, s4.x, dot[c8]);
                dot[c8] = fmaf(a4.y, s4.y, dot[c8]);
                dot[c8] = fmaf(a4.z, s4.z, dot[c8]);
                dot[c8] = fmaf(a4.w, s4.w, dot[c8]);
            }
        }
        float bv = dot[0]; int bc = cg;
        #pragma unroll
        for (int c8 = 1; c8 < 8; ++c8) {
            if (dot[c8] > bv) { bv = dot[c8]; bc = cg + 16 * c8; }
        }
        ull pk = ((ull)fkey(bv) << 32) | (u32)(~(u32)(C * 128 + bc));
        ull qq;
        qq = __shfl_xor(pk, 1); pk = pk > qq ? pk : qq;
        qq = __shfl_xor(pk, 2); pk = pk > qq ? pk : qq;
        qq = __shfl_xor(pk, 4); pk = pk > qq ? pk : qq;
        qq = __shfl_xor(pk, 8); pk = pk > qq ? pk : qq;
        if (cg == 0 && valid) atomicMax(&fin[(size_t)b * NN + n], pk);
        __syncthreads();   // protect sq before next stage
    }
}

// ---- Kernel B: fp8 MFMA MLP, 96 pts/block, grid=256 (1 block/CU),
//      512 thr / 8 waves, 64ch/wave, stagger + setprio + 3-buf prefetch ----

#define MLP_STEP(BUF, KB)                                                        \
    {                                                                            \
        const int kb2 = ((KB) + woff) & (NKB - 1);                               \
        __builtin_amdgcn_s_setprio(1);                                           \
        _Pragma("unroll")                                                        \
        for (int jb = 0; jb < 6; ++jb) {                                         \
            const int pt = jb * 16 + l15;                                        \
            const int sp = (kb2 * 4 + l4) ^ (pt & 7);                            \
            long bfr = *reinterpret_cast<const long*>(act + pt * 512 + sp * 8);  \
            _Pragma("unroll")                                                    \
            for (int ia = 0; ia < 4; ++ia)                                       \
                acc[ia][jb] = __builtin_amdgcn_mfma_f32_16x16x32_fp8_fp8(        \
                    BUF[ia], bfr, acc[ia][jb], 0, 0, 0);                         \
        }                                                                        \
        __builtin_amdgcn_s_setprio(0);                                           \
        if ((KB) + 3 < NKB) {                                                    \
            const int kbp = ((KB) + 3 + woff) & (NKB - 1);                       \
            _Pragma("unroll")                                                    \
            for (int ia = 0; ia < 4; ++ia)                                       \
                BUF[ia] = *reinterpret_cast<const long*>(                        \
                    wt8 + (((size_t)(chBlk0 + ia) * NKB + kbp) * 64 + lane) * 8);\
        }                                                                        \
    }

template<int K>
__device__ __forceinline__ void mlp_layer8(
    u8* act, const u8* __restrict__ wt8,
    const float* __restrict__ bias, int lane, int wid)
{
    constexpr int NKB = K / 32;
    floatx4 acc[4][6];
    #pragma unroll
    for (int ia = 0; ia < 4; ++ia)
        #pragma unroll
        for (int jb = 0; jb < 6; ++jb)
            acc[ia][jb] = (floatx4)(0.0f);

    const int l15 = lane & 15, l4 = lane >> 4;
    const int chBlk0 = wid * 4;               // (wid*64)/16
    const int woff = (wid * 2) & (NKB - 1);   // per-wave kb stagger

    long a0[4], a1[4], a2[4];
    #pragma unroll
    for (int ia = 0; ia < 4; ++ia)
        a0[ia] = *reinterpret_cast<const long*>(
            wt8 + (((size_t)(chBlk0 + ia) * NKB + ((0 + woff) & (NKB - 1))) * 64 + lane) * 8);
    #pragma unroll
    for (int ia = 0; ia < 4; ++ia)
        a1[ia] = *reinterpret_cast<const long*>(
            wt8 + (((size_t)(chBlk0 + ia) * NKB + ((1 + woff) & (NKB - 1))) * 64 + lane) * 8);
    #pragma unroll
    for (int ia = 0; ia < 4; ++ia)
        a2[ia] = *reinterpret_cast<const long*>(
            wt8 + (((size_t)(chBlk0 + ia) * NKB + ((2 + woff) & (NKB - 1))) * 64 + lane) * 8);

    #pragma unroll
    for (int kb = 0; kb < NKB; ++kb) {
        if ((kb % 3) == 0)      MLP_STEP(a0, kb)
        else if ((kb % 3) == 1) MLP_STEP(a1, kb)
        else                    MLP_STEP(a2, kb)
    }
    __syncthreads();   // all reads done before in-place overwrite

    const int ch0 = wid * 64;
    #pragma unroll
    for (int ia = 0; ia < 4; ++ia) {
        int cb = ia * 16 + l4 * 4;
        float4 bv = *reinterpret_cast<const float4*>(bias + ch0 + cb);
        #pragma unroll
        for (int jb = 0; jb < 6; ++jb) {
            int pt = jb * 16 + l15;
            u32 pk0 = f2fp8x2(fmaxf(acc[ia][jb][0] + bv.x, 0.0f),
                              fmaxf(acc[ia][jb][1] + bv.y, 0.0f));
            u32 pk1 = f2fp8x2(fmaxf(acc[ia][jb][2] + bv.z, 0.0f),
                              fmaxf(acc[ia][jb][3] + bv.w, 0.0f));
            u32 word = pk0 | (pk1 << 16);
            int s = (ch0 + cb) >> 3;
            int sp = s ^ (pt & 7);
            *reinterpret_cast<u32*>(act + pt * 512 + sp * 8 + (cb & 4)) = word;
        }
    }
    __syncthreads();
}

__global__ __launch_bounds__(512, 2) void mlp_mfma_kernel(
    const float* __restrict__ f1, const float* __restrict__ f2,
    const float* __restrict__ kps1, const float* __restrict__ kps2,
    const float* __restrict__ scales1,
    const float* __restrict__ b1, const float* __restrict__ b2,
    const float* __restrict__ b3, const float* __restrict__ b4,
    const float* __restrict__ b5,
    const u8* __restrict__ wt8,
    const ull* __restrict__ rowfin, const ull* __restrict__ colfin,
    float* __restrict__ out)
{
    __shared__ __align__(16) unsigned char lds_raw[49152];   // 96 pts x 512 ch fp8
    u8* act = lds_raw;
    float* logf = reinterpret_cast<float*>(lds_raw);

    const int t = threadIdx.x;
    const int lane = t & 63, wid = t >> 6;
    const int base = blockIdx.x * 96;
    const int b = base / NN;
    const int n0 = base % NN;

    // stage concat(f1[n], f2[match12[n]]) as fp8, swizzled; 384 active threads
    if (t < 384) {
        const int pt = t >> 2, seg = t & 3;   // 4 segs * 32 dims
        const int n = n0 + pt;
        ull rm = rowfin[(size_t)b * NN + n];
        const int m = (int)(~(u32)(rm & 0xffffffffULL));
        const float* src = (seg < 2)
            ? (f1 + ((size_t)b * NN + n) * DD + seg * 32)
            : (f2 + ((size_t)b * NN + m) * DD + (seg - 2) * 32);
        #pragma unroll
        for (int q8 = 0; q8 < 4; ++q8) {
            float4 v0 = *reinterpret_cast<const float4*>(src + q8 * 8);
            float4 v1 = *reinterpret_cast<const float4*>(src + q8 * 8 + 4);
            ull w64 = (ull)f2fp8x2(v0.x, v0.y)
                    | ((ull)f2fp8x2(v0.z, v0.w) << 16)
                    | ((ull)f2fp8x2(v1.x, v1.y) << 32)
                    | ((ull)f2fp8x2(v1.z, v1.w) << 48);
            int s = seg * 4 + q8;
            int sp = s ^ (pt & 7);
            *reinterpret_cast<ull*>(act + pt * 512 + sp * 8) = w64;
        }
    }
    __syncthreads();

    mlp_layer8<128>(act, wt8 + WT1_OFF, b1, lane, wid);
    mlp_layer8<512>(act, wt8 + WT2_OFF, b2, lane, wid);
    mlp_layer8<512>(act, wt8 + WT3_OFF, b3, lane, wid);
    mlp_layer8<512>(act, wt8 + WT4_OFF, b4, lane, wid);

    // layer 5: 512 -> 64, no relu; waves 0-3 handle 16 out-ch each (staggered)
    {
        const int l15 = lane & 15, l4 = lane >> 4;
        floatx4 acc5[6];
        #pragma unroll
        for (int jb = 0; jb < 6; ++jb) acc5[jb] = (floatx4)(0.0f);
        if (wid < 4) {
            const int woff5 = (wid * 4) & 15;
            long a_cur = *reinterpret_cast<const long*>(
                wt8 + WT5_OFF + (((size_t)wid * 16 + woff5) * 64 + lane) * 8);
            long a_nxt;
            #pragma unroll
            for (int kb = 0; kb < 16; ++kb) {
                const int kb2 = (kb + woff5) & 15;
                if (kb + 1 < 16) {
                    const int kbn = (kb + 1 + woff5) & 15;
                    a_nxt = *reinterpret_cast<const long*>(
                        wt8 + WT5_OFF + (((size_t)wid * 16 + kbn) * 64 + lane) * 8);
                }
                __builtin_amdgcn_s_setprio(1);
                #pragma unroll
                for (int jb = 0; jb < 6; ++jb) {
                    const int pt = jb * 16 + l15;
                    const int sp = (kb2 * 4 + l4) ^ (pt & 7);
                    long bfr = *reinterpret_cast<const long*>(act + pt * 512 + sp * 8);
                    acc5[jb] = __builtin_amdgcn_mfma_f32_16x16x32_fp8_fp8(
                        a_cur, bfr, acc5[jb], 0, 0, 0);
                }
                __builtin_amdgcn_s_setprio(0);
                if (kb + 1 < 16) a_cur = a_nxt;
            }
        }
        __syncthreads();   // all act reads done; lds_raw becomes logits f32
        if (wid < 4) {
            int cb = wid * 16 + l4 * 4;
            float4 bv = *reinterpret_cast<const float4*>(b5 + cb);
            #pragma unroll
            for (int jb = 0; jb < 6; ++jb) {
                int pt = jb * 16 + l15;
                float4 o;
                o.x = acc5[jb][0] + bv.x;
                o.y = acc5[jb][1] + bv.y;
                o.z = acc5[jb][2] + bv.z;
                o.w = acc5[jb][3] + bv.w;
                *reinterpret_cast<float4*>(&logf[pt * 68 + cb]) = o;
            }
        }
        __syncthreads();
    }

    if (t < 96) {
        const int pt = t;
        const int n = n0 + pt;
        const float* lrow = &logf[pt * 68];
        float mx = -1e30f;
        #pragma unroll 8
        for (int j = 0; j < OUTD; ++j) mx = fmaxf(mx, 3.0f * lrow[j]);
        float s = 0.0f, cx = 0.0f, cy = 0.0f;
        #pragma unroll 8
        for (int j = 0; j < OUTD; ++j) {
            float e = __expf(3.0f * lrow[j] - mx);
            s  += e;
            cx += e * (float)((j & 7) - 4);
            cy += e * (float)((j >> 3) - 4);
        }
        float conf = 1.0f / s;
        cx /= s; cy /= s;
        ull rm = rowfin[(size_t)b * NN + n];
        int m = (int)(~(u32)(rm & 0xffffffffULL));
        ull cm = colfin[(size_t)b * NN + m];
        int back = (int)(~(u32)(cm & 0xffffffffULL));
        bool mutual = (back == n);
        float sc = scales1[(size_t)b * NN + n];
        float x0 = kps1[((size_t)b * NN + n) * 2 + 0] + cx * sc;
        float y0 = kps1[((size_t)b * NN + n) * 2 + 1] + cy * sc;
        float x1 = kps2[((size_t)b * NN + m) * 2 + 0];
        float y1 = kps2[((size_t)b * NN + m) * 2 + 1];
        float* mt = out + ((size_t)b * NN + n) * 4;
        mt[0] = x0; mt[1] = y0; mt[2] = x1; mt[3] = y1;
        out[(size_t)BB * NN * 4 + (size_t)b * NN + n] =
            (mutual && conf > 0.25f) ? 1.0f : 0.0f;
    }
}

extern "C" void kernel_launch(void* const* d_in, const int* in_sizes, int n_in,
                              void* d_out, int out_size, void* d_ws, size_t ws_size,
                              hipStream_t stream)
{
    const float* f1  = (const float*)d_in[0];
    const float* f2  = (const float*)d_in[1];
    const float* kp1 = (const float*)d_in[2];
    const float* kp2 = (const float*)d_in[3];
    const float* sc1 = (const float*)d_in[4];
    const float* w1  = (const float*)d_in[5];
    const float* b1  = (const float*)d_in[6];
    const float* w2  = (const float*)d_in[7];
    const float* b2  = (const float*)d_in[8];
    const float* w3  = (const float*)d_in[9];
    const float* b3  = (const float*)d_in[10];
    const float* w4  = (const float*)d_in[11];
    const float* b4  = (const float*)d_in[12];
    const float* w5  = (const float*)d_in[13];
    const float* b5  = (const float*)d_in[14];

    char* ws = (char*)d_ws;
    ull* rowfin = (ull*)(ws + OFF_ROWFIN);
    ull* colfin = (ull*)(ws + OFF_COLFIN);
    u8*  wt8    = (u8*)(ws + OFF_WT);
    u16* f1t    = (u16*)(ws + OFF_F1T);
    u16* f2t    = (u16*)(ws + OFF_F2T);
    u16* rbm    = (u16*)(ws + OFF_RBM);
    u16* cbm    = (u16*)(ws + OFF_CBM);
    int* cntR   = (int*)(ws + OFF_CNTR);
    int* cntC   = (int*)(ws + OFF_CNTC);
    int* listR  = (int*)(ws + OFF_LISTR);
    int* listC  = (int*)(ws + OFF_LISTC);
    float* out  = (float*)d_out;

    prep_kernel<<<(2 * BB * NN * DD) / 256, 256, 0, stream>>>(
        w1, w2, w3, w4, w5, f1, f2, wt8, f1t, f2t, rowfin, cntR);

    dim3 gS(48, 24, BB);
    simb_kernel<<<gS, 256, 0, stream>>>(f1t, f2t, rbm, cbm);

    dim3 gScan((BB * NN) / 256, 2);
    scan_kernel<<<gScan, 256, 0, stream>>>(rbm, cbm, cntR, cntC, listR, listC);

    dim3 gR(BB * 48, RSPLIT, 2);
    refine_kernel<<<gR, 256, 0, stream>>>(f1, f2, cntR, cntC, listR, listC,
                                          rowfin, colfin);

    mlp_mfma_kernel<<<(BB * NN) / 96, 512, 0, stream>>>(
        f1, f2, kp1, kp2, sc1, b1, b2, b3, b4, b5, wt8, rowfin, colfin, out);
}

// Round 13
// 157.071 us; speedup vs baseline: 4.2310x; 1.1177x over previous
//
#include <hip/hip_runtime.h>
#include <cstddef>
#include <cstdint>

#define BB 4
#define NN 6144
#define DD 64
#define HID 512
#define OUTD 64
#define CAP 512
#define RSPLIT 8

typedef unsigned long long ull;
typedef unsigned int u32;
typedef unsigned short u16;
typedef unsigned char u8;
typedef __attribute__((ext_vector_type(8))) short short8_t;
typedef __attribute__((ext_vector_type(4))) float floatx4;

// ---- ws layout (byte offsets) ----
#define OFF_ROWFIN 0
#define OFF_COLFIN 196608
#define OFF_WT     393216
#define OFF_F1T    2162688
#define OFF_F2T    5308416
#define OFF_RBM    8454144
#define OFF_CBM    10813440
#define OFF_CNTR   13172736
#define OFF_CNTC   13173504
#define OFF_LISTR  13174272
#define OFF_LISTC  13567488

#define WT1_OFF 0
#define WT2_OFF 65536
#define WT3_OFF 327680
#define WT4_OFF 589824
#define WT5_OFF 851968
#define WT_TOTAL 884736

__device__ __forceinline__ unsigned int fkey(float v) {
    unsigned int u = __float_as_uint(v);
    return (u & 0x80000000u) ? ~u : (u | 0x80000000u);
}

__device__ __forceinline__ float inv16(u32 k16) {
    u32 u = k16 << 16;
    return (u & 0x80000000u) ? __uint_as_float(u & 0x7fffffffu)
                             : __uint_as_float(~u);
}

__device__ __forceinline__ u16 f2bf(float f) {
    unsigned int u = __float_as_uint(f);
    u += 0x7FFFu + ((u >> 16) & 1u);
    return (u16)(u >> 16);
}

// two floats -> two fp8 (chip-native fp8; self-consistent with fp8 MFMA)
__device__ __forceinline__ u32 f2fp8x2(float a, float b) {
    return (u32)__builtin_amdgcn_cvt_pk_fp8_f32(a, b, 0, false) & 0xffffu;
}

// ---- prep: ws init + weights->fp8 tiled + feats->bf16 tiled ----
__global__ __launch_bounds__(256) void prep_kernel(
    const float* __restrict__ w1, const float* __restrict__ w2,
    const float* __restrict__ w3, const float* __restrict__ w4,
    const float* __restrict__ w5,
    const float* __restrict__ f1, const float* __restrict__ f2,
    u8* __restrict__ wt8, u16* __restrict__ f1t, u16* __restrict__ f2t,
    ull* __restrict__ finals, int* __restrict__ cnts)
{
    int idx = blockIdx.x * 256 + threadIdx.x;

    if (idx < 2 * BB * NN) finals[idx] = 0ULL;
    if (idx < 384) cnts[idx] = 0;

    if (idx < WT_TOTAL) {
        const float* w; u8* o; int K, nsh, li;
        if (idx < 65536)        { w = w1; o = wt8 + WT1_OFF; K = 128; nsh = 9; li = idx; }
        else if (idx < 327680)  { w = w2; o = wt8 + WT2_OFF; K = 512; nsh = 9; li = idx - 65536; }
        else if (idx < 589824)  { w = w3; o = wt8 + WT3_OFF; K = 512; nsh = 9; li = idx - 327680; }
        else if (idx < 851968)  { w = w4; o = wt8 + WT4_OFF; K = 512; nsh = 9; li = idx - 589824; }
        else                    { w = w5; o = wt8 + WT5_OFF; K = 512; nsh = 6; li = idx - 851968; }
        int k = li >> nsh;
        int n = li & ((1 << nsh) - 1);
        u8 v = (u8)(f2fp8x2(w[li], 0.0f) & 0xff);
        int lane = (n & 15) | (((k >> 3) & 3) << 4);
        o[(((size_t)(n >> 4) * (K >> 5) + (k >> 5)) * 64 + lane) * 8 + (k & 7)] = v;
    }

    {
        const int TE = BB * NN * DD;
        const float* src; u16* dst; int e;
        if (idx < TE) { src = f1; dst = f1t; e = idx; }
        else          { src = f2; dst = f2t; e = idx - TE; }
        int k  = e & 63;
        int rn = e >> 6;
        int b  = rn / NN;
        int r  = rn - b * NN;
        int R  = r >> 7, rb = (r >> 4) & 7;
        int kb = k >> 5, lane = (r & 15) | (((k >> 3) & 3) << 4), j = k & 7;
        dst[(size_t)(b * 48 + R) * 8192 + ((rb * 2 + kb) * 64 + lane) * 8 + j] = f2bf(src[e]);
    }
}

// ---- Kernel A: bf16 MFMA sim, 128x256 tile, block maxima -> rbm/cbm ----
__global__ __launch_bounds__(256, 2) void simb_kernel(
    const u16* __restrict__ f1t, const u16* __restrict__ f2t,
    u16* __restrict__ rbm, u16* __restrict__ cbm)
{
    __shared__ __align__(16) u16 sA[8192];
    __shared__ __align__(16) u16 sB[16384];
    __shared__ float cv[2][2][128];
    const int R = blockIdx.x, C2 = blockIdx.y, b = blockIdx.z;
    const int t = threadIdx.x, lane = t & 63, w = t >> 6;
    const int wr = w >> 1, wc = w & 1;
    const int l15 = lane & 15, l4 = lane >> 4;

    const u16* Ag = f1t + (size_t)(b * 48 + R) * 8192;
    const u16* Bg = f2t + (size_t)(b * 48 + C2 * 2) * 8192;

    #pragma unroll
    for (int rnd = 0; rnd < 4; ++rnd) {
        int c = rnd * 256 + t;
        *reinterpret_cast<uint4*>(&sA[c * 8]) = *reinterpret_cast<const uint4*>(Ag + c * 8);
    }
    #pragma unroll
    for (int rnd = 0; rnd < 8; ++rnd) {
        int c = rnd * 256 + t;
        *reinterpret_cast<uint4*>(&sB[c * 8]) = *reinterpret_cast<const uint4*>(Bg + c * 8);
    }
    __syncthreads();

    floatx4 acc[4][8];
    #pragma unroll
    for (int i = 0; i < 4; ++i)
        #pragma unroll
        for (int j = 0; j < 8; ++j) acc[i][j] = (floatx4)(0.0f);

    #pragma unroll
    for (int kb = 0; kb < 2; ++kb) {
        short8_t afr[4], bfr[8];
        #pragma unroll
        for (int i = 0; i < 4; ++i)
            afr[i] = *reinterpret_cast<const short8_t*>(
                &sA[(((wr * 4 + i) * 2 + kb) * 64 + lane) * 8]);
        #pragma unroll
        for (int j = 0; j < 8; ++j) {
            int cb = wc * 8 + j;
            bfr[j] = *reinterpret_cast<const short8_t*>(
                &sB[(cb >> 3) * 8192 + (((cb & 7) * 2 + kb) * 64 + lane) * 8]);
        }
        #pragma unroll
        for (int i = 0; i < 4; ++i)
            #pragma unroll
            for (int j = 0; j < 8; ++j)
                acc[i][j] = __builtin_amdgcn_mfma_f32_16x16x32_bf16(
                    afr[i], bfr[j], acc[i][j], 0, 0, 0);
    }

    const int Cme = C2 * 2 + wc;
    #pragma unroll
    for (int i = 0; i < 4; ++i) {
        #pragma unroll
        for (int reg = 0; reg < 4; ++reg) {
            float v = acc[i][0][reg];
            #pragma unroll
            for (int j = 1; j < 8; ++j) v = fmaxf(v, acc[i][j][reg]);
            v = fmaxf(v, __shfl_xor(v, 1));
            v = fmaxf(v, __shfl_xor(v, 2));
            v = fmaxf(v, __shfl_xor(v, 4));
            v = fmaxf(v, __shfl_xor(v, 8));
            if (l15 == 0) {
                int row = R * 128 + wr * 64 + i * 16 + l4 * 4 + reg;
                rbm[((size_t)b * NN + row) * 48 + Cme] = (u16)(fkey(v) >> 16);
            }
        }
    }

    #pragma unroll
    for (int j = 0; j < 8; ++j) {
        float v = acc[0][j][0];
        #pragma unroll
        for (int i = 0; i < 4; ++i)
            #pragma unroll
            for (int reg = 0; reg < 4; ++reg) v = fmaxf(v, acc[i][j][reg]);
        v = fmaxf(v, __shfl_xor(v, 16));
        v = fmaxf(v, __shfl_xor(v, 32));
        if (l4 == 0) cv[wc][wr][j * 16 + l15] = v;
    }
    __syncthreads();
    {
        int wcc = t >> 7, col0 = t & 127;
        float v = fmaxf(cv[wcc][0][col0], cv[wcc][1][col0]);
        int col = C2 * 256 + wcc * 128 + col0;
        cbm[((size_t)b * NN + col) * 48 + R] = (u16)(fkey(v) >> 16);
    }
}

// ---- scan (merged row/col via blockIdx.y): block-aggregated candidate append ----
__global__ __launch_bounds__(256) void scan_kernel(
    const u16* __restrict__ rbm, const u16* __restrict__ cbm,
    int* __restrict__ cntR, int* __restrict__ cntC,
    int* __restrict__ listR, int* __restrict__ listC)
{
    const u16* bm = blockIdx.y ? cbm : rbm;
    int* cnt  = blockIdx.y ? cntC : cntR;
    int* list = blockIdx.y ? listC : listR;

    __shared__ int lcnt[48];
    __shared__ int lbase[48];
    const int t = threadIdx.x;
    if (t < 48) lcnt[t] = 0;
    const int idx = blockIdx.x * 256 + t;
    const int b = (blockIdx.x * 256) / NN;
    const int n = idx - b * NN;

    u16 ks[48];
    const uint4* p4 = reinterpret_cast<const uint4*>(bm + (size_t)idx * 48);
    #pragma unroll
    for (int q = 0; q < 6; ++q) {
        uint4 u = p4[q];
        ks[q * 8 + 0] = (u16)(u.x & 0xffff); ks[q * 8 + 1] = (u16)(u.x >> 16);
        ks[q * 8 + 2] = (u16)(u.y & 0xffff); ks[q * 8 + 3] = (u16)(u.y >> 16);
        ks[q * 8 + 4] = (u16)(u.z & 0xffff); ks[q * 8 + 5] = (u16)(u.z >> 16);
        ks[q * 8 + 6] = (u16)(u.w & 0xffff); ks[q * 8 + 7] = (u16)(u.w >> 16);
    }
    u16 mx = 0;
    #pragma unroll
    for (int c = 0; c < 48; ++c) mx = ks[c] > mx ? ks[c] : mx;
    // margin: worst-case bf16 sim error |S~-S| <= 2^-8 * sum|a_k b_k| <= 0.0039
    // (round-to-nearest f2bf, unit vectors); listing the true block needs
    // margin >= 2*0.0039 = 0.0078; 0.010 gives 28% cushion.
    float thr = inv16(mx) - 0.010f;
    u32 m0 = 0, m1 = 0;
    #pragma unroll
    for (int c = 0; c < 48; ++c) {
        if (inv16((u32)ks[c] + 1) >= thr) {
            if (c < 32) m0 |= 1u << c; else m1 |= 1u << (c - 32);
        }
    }
    __syncthreads();
    {
        u32 a = m0;
        while (a) { int c = __builtin_ctz(a); a &= a - 1; atomicAdd(&lcnt[c], 1); }
        a = m1;
        while (a) { int c = 32 + __builtin_ctz(a); a &= a - 1; atomicAdd(&lcnt[c], 1); }
    }
    __syncthreads();
    if (t < 48) { lbase[t] = atomicAdd(&cnt[b * 48 + t], lcnt[t]); lcnt[t] = 0; }
    __syncthreads();
    {
        u32 a = m0;
        while (a) {
            int c = __builtin_ctz(a); a &= a - 1;
            int pos = lbase[c] + atomicAdd(&lcnt[c], 1);
            if (pos < CAP) list[(b * 48 + c) * CAP + pos] = n;
        }
        a = m1;
        while (a) {
            int c = 32 + __builtin_ctz(a); a &= a - 1;
            int pos = lbase[c] + atomicAdd(&lcnt[c], 1);
            if (pos < CAP) list[(b * 48 + c) * CAP + pos] = n;
        }
    }
}

// ---- exact fp32 refine (merged row/col via blockIdx.z), LDS-staged queries ----
__global__ __launch_bounds__(256, 2) void refine_kernel(
    const float* __restrict__ f1, const float* __restrict__ f2,
    const int* __restrict__ cntR, const int* __restrict__ cntC,
    const int* __restrict__ listR, const int* __restrict__ listC,
    ull* __restrict__ rowfin, ull* __restrict__ colfin)
{
    const float* qfeat = blockIdx.z ? f2 : f1;
    const float* tfeat = blockIdx.z ? f1 : f2;
    const int* cnt  = blockIdx.z ? cntC : cntR;
    const int* list = blockIdx.z ? listC : listR;
    ull* fin = blockIdx.z ? colfin : rowfin;

    const int b = blockIdx.x / 48;
    const int C = blockIdx.x - b * 48;
    const int sub = blockIdx.y;
    int n_items = cnt[b * 48 + C];
    if (n_items > CAP) n_items = CAP;
    int chunk = (n_items + RSPLIT - 1) / RSPLIT;
    int lo = sub * chunk;
    int hi = lo + chunk; if (hi > n_items) hi = n_items;
    if (lo >= hi) return;

    __shared__ float s2f[128 * 68];
    __shared__ float sq[16 * 68];
    const int t = threadIdx.x;
    const float* tb = tfeat + ((size_t)b * NN + C * 128) * 64;
    #pragma unroll
    for (int p = 0; p < 8; ++p) {
        int idx = p * 256 + t;
        int row = idx >> 4, c4 = idx & 15;
        *reinterpret_cast<float4*>(&s2f[row * 68 + c4 * 4]) =
            *reinterpret_cast<const float4*>(tb + row * 64 + c4 * 4);
    }
    __syncthreads();
    const int rs = t >> 4, cg = t & 15;
    const int* mylist = list + (b * 48 + C) * CAP;
    for (int base = lo; base < hi; base += 16) {
        // stage 16 query rows (coalesced; one float4 per thread)
        {
            int lq = base + rs;
            int nn = (lq < hi) ? mylist[lq] : mylist[lo];
            *reinterpret_cast<float4*>(&sq[rs * 68 + cg * 4]) =
                *reinterpret_cast<const float4*>(qfeat + ((size_t)b * NN + nn) * 64 + cg * 4);
        }
        __syncthreads();

        int li = base + rs;
        bool valid = li < hi;
        int n = valid ? mylist[li] : mylist[lo];
        float dot[8];
        #pragma unroll
        for (int c8 = 0; c8 < 8; ++c8) dot[c8] = 0.0f;
        #pragma unroll 4
        for (int kq = 0; kq < 16; ++kq) {
            float4 a4 = *reinterpret_cast<const float4*>(&sq[rs * 68 + kq * 4]);
            #pragma unroll
            for (int c8 = 0; c8 < 8; ++c8) {
                float4 s4 = *reinterpret_cast<const float4*>(&s2f[(cg + 16 * c8) * 68 + kq * 4]);
                dot[c8] = fmaf(a4.x, s4.x, dot[c8]);
                dot[c8] = fmaf(a4.y, s4.y, dot[c8]);
                dot[c8] = fmaf(a4.z, s4.z, dot[c8]);
                dot[c8] = fmaf(a4.w, s4.w, dot[c8]);
            }
        }
        float bv = dot[0]; int bc = cg;
        #pragma unroll
        for (int c8 = 1; c8 < 8; ++c8) {
            if (dot[c8] > bv) { bv = dot[c8]; bc = cg + 16 * c8; }
        }
        ull pk = ((ull)fkey(bv) << 32) | (u32)(~(u32)(C * 128 + bc));
        ull qq;
        qq = __shfl_xor(pk, 1); pk = pk > qq ? pk : qq;
        qq = __shfl_xor(pk, 2); pk = pk > qq ? pk : qq;
        qq = __shfl_xor(pk, 4); pk = pk > qq ? pk : qq;
        qq = __shfl_xor(pk, 8); pk = pk > qq ? pk : qq;
        if (cg == 0 && valid) atomicMax(&fin[(size_t)b * NN + n], pk);
        __syncthreads();   // protect sq before next stage
    }
}

// ---- Kernel B: fp8 MFMA MLP, 96 pts/block, grid=256 (1 block/CU),
//      512 thr / 8 waves, 64ch/wave, stagger + setprio + 3-buf prefetch ----

#define MLP_STEP(BUF, KB)                                                        \
    {                                                                            \
        const int kb2 = ((KB) + woff) & (NKB - 1);                               \
        __builtin_amdgcn_s_setprio(1);                                           \
        _Pragma("unroll")                                                        \
        for (int jb = 0; jb < 6; ++jb) {                                         \
            const int pt = jb * 16 + l15;                                        \
            const int sp = (kb2 * 4 + l4) ^ (pt & 7);                            \
            long bfr = *reinterpret_cast<const long*>(act + pt * 512 + sp * 8);  \
            _Pragma("unroll")                                                    \
            for (int ia = 0; ia < 4; ++ia)                                       \
                acc[ia][jb] = __builtin_amdgcn_mfma_f32_16x16x32_fp8_fp8(        \
                    BUF[ia], bfr, acc[ia][jb], 0, 0, 0);                         \
        }                                                                        \
        __builtin_amdgcn_s_setprio(0);                                           \
        if ((KB) + 3 < NKB) {                                                    \
            const int kbp = ((KB) + 3 + woff) & (NKB - 1);                       \
            _Pragma("unroll")                                                    \
            for (int ia = 0; ia < 4; ++ia)                                       \
                BUF[ia] = *reinterpret_cast<const long*>(                        \
                    wt8 + (((size_t)(chBlk0 + ia) * NKB + kbp) * 64 + lane) * 8);\
        }                                                                        \
    }

template<int K>
__device__ __forceinline__ void mlp_layer8(
    u8* act, const u8* __restrict__ wt8,
    const float* __restrict__ bias, int lane, int wid)
{
    constexpr int NKB = K / 32;
    floatx4 acc[4][6];
    #pragma unroll
    for (int ia = 0; ia < 4; ++ia)
        #pragma unroll
        for (int jb = 0; jb < 6; ++jb)
            acc[ia][jb] = (floatx4)(0.0f);

    const int l15 = lane & 15, l4 = lane >> 4;
    const int chBlk0 = wid * 4;               // (wid*64)/16
    const int woff = (wid * 2) & (NKB - 1);   // per-wave kb stagger

    long a0[4], a1[4], a2[4];
    #pragma unroll
    for (int ia = 0; ia < 4; ++ia)
        a0[ia] = *reinterpret_cast<const long*>(
            wt8 + (((size_t)(chBlk0 + ia) * NKB + ((0 + woff) & (NKB - 1))) * 64 + lane) * 8);
    #pragma unroll
    for (int ia = 0; ia < 4; ++ia)
        a1[ia] = *reinterpret_cast<const long*>(
            wt8 + (((size_t)(chBlk0 + ia) * NKB + ((1 + woff) & (NKB - 1))) * 64 + lane) * 8);
    #pragma unroll
    for (int ia = 0; ia < 4; ++ia)
        a2[ia] = *reinterpret_cast<const long*>(
            wt8 + (((size_t)(chBlk0 + ia) * NKB + ((2 + woff) & (NKB - 1))) * 64 + lane) * 8);

    #pragma unroll
    for (int kb = 0; kb < NKB; ++kb) {
        if ((kb % 3) == 0)      MLP_STEP(a0, kb)
        else if ((kb % 3) == 1) MLP_STEP(a1, kb)
        else                    MLP_STEP(a2, kb)
    }
    __syncthreads();   // all reads done before in-place overwrite

    const int ch0 = wid * 64;
    #pragma unroll
    for (int ia = 0; ia < 4; ++ia) {
        int cb = ia * 16 + l4 * 4;
        float4 bv = *reinterpret_cast<const float4*>(bias + ch0 + cb);
        #pragma unroll
        for (int jb = 0; jb < 6; ++jb) {
            int pt = jb * 16 + l15;
            u32 pk0 = f2fp8x2(fmaxf(acc[ia][jb][0] + bv.x, 0.0f),
                              fmaxf(acc[ia][jb][1] + bv.y, 0.0f));
            u32 pk1 = f2fp8x2(fmaxf(acc[ia][jb][2] + bv.z, 0.0f),
                              fmaxf(acc[ia][jb][3] + bv.w, 0.0f));
            u32 word = pk0 | (pk1 << 16);
            int s = (ch0 + cb) >> 3;
            int sp = s ^ (pt & 7);
            *reinterpret_cast<u32*>(act + pt * 512 + sp * 8 + (cb & 4)) = word;
        }
    }
    __syncthreads();
}

__global__ __launch_bounds__(512, 2) void mlp_mfma_kernel(
    const float* __restrict__ f1, const float* __restrict__ f2,
    const float* __restrict__ kps1, const float* __restrict__ kps2,
    const float* __restrict__ scales1,
    const float* __restrict__ b1, const float* __restrict__ b2,
    const float* __restrict__ b3, const float* __restrict__ b4,
    const float* __restrict__ b5,
    const u8* __restrict__ wt8,
    const ull* __restrict__ rowfin, const ull* __restrict__ colfin,
    float* __restrict__ out)
{
    __shared__ __align__(16) unsigned char lds_raw[49152];   // 96 pts x 512 ch fp8
    u8* act = lds_raw;
    float* logf = reinterpret_cast<float*>(lds_raw);

    const int t = threadIdx.x;
    const int lane = t & 63, wid = t >> 6;
    const int base = blockIdx.x * 96;
    const int b = base / NN;
    const int n0 = base % NN;

    // stage concat(f1[n], f2[match12[n]]) as fp8, swizzled; 384 active threads
    if (t < 384) {
        const int pt = t >> 2, seg = t & 3;   // 4 segs * 32 dims
        const int n = n0 + pt;
        ull rm = rowfin[(size_t)b * NN + n];
        const int m = (int)(~(u32)(rm & 0xffffffffULL));
        const float* src = (seg < 2)
            ? (f1 + ((size_t)b * NN + n) * DD + seg * 32)
            : (f2 + ((size_t)b * NN + m) * DD + (seg - 2) * 32);
        #pragma unroll
        for (int q8 = 0; q8 < 4; ++q8) {
            float4 v0 = *reinterpret_cast<const float4*>(src + q8 * 8);
            float4 v1 = *reinterpret_cast<const float4*>(src + q8 * 8 + 4);
            ull w64 = (ull)f2fp8x2(v0.x, v0.y)
                    | ((ull)f2fp8x2(v0.z, v0.w) << 16)
                    | ((ull)f2fp8x2(v1.x, v1.y) << 32)
                    | ((ull)f2fp8x2(v1.z, v1.w) << 48);
            int s = seg * 4 + q8;
            int sp = s ^ (pt & 7);
            *reinterpret_cast<ull*>(act + pt * 512 + sp * 8) = w64;
        }
    }
    __syncthreads();

    mlp_layer8<128>(act, wt8 + WT1_OFF, b1, lane, wid);
    mlp_layer8<512>(act, wt8 + WT2_OFF, b2, lane, wid);
    mlp_layer8<512>(act, wt8 + WT3_OFF, b3, lane, wid);
    mlp_layer8<512>(act, wt8 + WT4_OFF, b4, lane, wid);

    // layer 5: 512 -> 64, no relu; waves 0-3 handle 16 out-ch each (staggered)
    {
        const int l15 = lane & 15, l4 = lane >> 4;
        floatx4 acc5[6];
        #pragma unroll
        for (int jb = 0; jb < 6; ++jb) acc5[jb] = (floatx4)(0.0f);
        if (wid < 4) {
            const int woff5 = (wid * 4) & 15;
            long a_cur = *reinterpret_cast<const long*>(
                wt8 + WT5_OFF + (((size_t)wid * 16 + woff5) * 64 + lane) * 8);
            long a_nxt;
            #pragma unroll
            for (int kb = 0; kb < 16; ++kb) {
                const int kb2 = (kb + woff5) & 15;
                if (kb + 1 < 16) {
                    const int kbn = (kb + 1 + woff5) & 15;
                    a_nxt = *reinterpret_cast<const long*>(
                        wt8 + WT5_OFF + (((size_t)wid * 16 + kbn) * 64 + lane) * 8);
                }
                __builtin_amdgcn_s_setprio(1);
                #pragma unroll
                for (int jb = 0; jb < 6; ++jb) {
                    const int pt = jb * 16 + l15;
                    const int sp = (kb2 * 4 + l4) ^ (pt & 7);
                    long bfr = *reinterpret_cast<const long*>(act + pt * 512 + sp * 8);
                    acc5[jb] = __builtin_amdgcn_mfma_f32_16x16x32_fp8_fp8(
                        a_cur, bfr, acc5[jb], 0, 0, 0);
                }
                __builtin_amdgcn_s_setprio(0);
                if (kb + 1 < 16) a_cur = a_nxt;
            }
        }
        __syncthreads();   // all act reads done; lds_raw becomes logits f32
        if (wid < 4) {
            int cb = wid * 16 + l4 * 4;
            float4 bv = *reinterpret_cast<const float4*>(b5 + cb);
            #pragma unroll
            for (int jb = 0; jb < 6; ++jb) {
                int pt = jb * 16 + l15;
                float4 o;
                o.x = acc5[jb][0] + bv.x;
                o.y = acc5[jb][1] + bv.y;
                o.z = acc5[jb][2] + bv.z;
                o.w = acc5[jb][3] + bv.w;
                *reinterpret_cast<float4*>(&logf[pt * 68 + cb]) = o;
            }
        }
        __syncthreads();
    }

    if (t < 96) {
        const int pt = t;
        const int n = n0 + pt;
        const float* lrow = &logf[pt * 68];
        float mx = -1e30f;
        #pragma unroll 8
        for (int j = 0; j < OUTD; ++j) mx = fmaxf(mx, 3.0f * lrow[j]);
        float s = 0.0f, cx = 0.0f, cy = 0.0f;
        #pragma unroll 8
        for (int j = 0; j < OUTD; ++j) {
            float e = __expf(3.0f * lrow[j] - mx);
            s  += e;
            cx += e * (float)((j & 7) - 4);
            cy += e * (float)((j >> 3) - 4);
        }
        float conf = 1.0f / s;
        cx /= s; cy /= s;
        ull rm = rowfin[(size_t)b * NN + n];
        int m = (int)(~(u32)(rm & 0xffffffffULL));
        ull cm = colfin[(size_t)b * NN + m];
        int back = (int)(~(u32)(cm & 0xffffffffULL));
        bool mutual = (back == n);
        float sc = scales1[(size_t)b * NN + n];
        float x0 = kps1[((size_t)b * NN + n) * 2 + 0] + cx * sc;
        float y0 = kps1[((size_t)b * NN + n) * 2 + 1] + cy * sc;
        float x1 = kps2[((size_t)b * NN + m) * 2 + 0];
        float y1 = kps2[((size_t)b * NN + m) * 2 + 1];
        float* mt = out + ((size_t)b * NN + n) * 4;
        mt[0] = x0; mt[1] = y0; mt[2] = x1; mt[3] = y1;
        out[(size_t)BB * NN * 4 + (size_t)b * NN + n] =
            (mutual && conf > 0.25f) ? 1.0f : 0.0f;
    }
}

extern "C" void kernel_launch(void* const* d_in, const int* in_sizes, int n_in,
                              void* d_out, int out_size, void* d_ws, size_t ws_size,
                              hipStream_t stream)
{
    const float* f1  = (const float*)d_in[0];
    const float* f2  = (const float*)d_in[1];
    const float* kp1 = (const float*)d_in[2];
    const float* kp2 = (const float*)d_in[3];
    const float* sc1 = (const float*)d_in[4];
    const float* w1  = (const float*)d_in[5];
    const float* b1  = (const float*)d_in[6];
    const float* w2  = (const float*)d_in[7];
    const float* b2  = (const float*)d_in[8];
    const float* w3  = (const float*)d_in[9];
    const float* b3  = (const float*)d_in[10];
    const float* w4  = (const float*)d_in[11];
    const float* b4  = (const float*)d_in[12];
    const float* w5  = (const float*)d_in[13];
    const float* b5  = (const float*)d_in[14];

    char* ws = (char*)d_ws;
    ull* rowfin = (ull*)(ws + OFF_ROWFIN);
    ull* colfin = (ull*)(ws + OFF_COLFIN);
    u8*  wt8    = (u8*)(ws + OFF_WT);
    u16* f1t    = (u16*)(ws + OFF_F1T);
    u16* f2t    = (u16*)(ws + OFF_F2T);
    u16* rbm    = (u16*)(ws + OFF_RBM);
    u16* cbm    = (u16*)(ws + OFF_CBM);
    int* cntR   = (int*)(ws + OFF_CNTR);
    int* cntC   = (int*)(ws + OFF_CNTC);
    int* listR  = (int*)(ws + OFF_LISTR);
    int* listC  = (int*)(ws + OFF_LISTC);
    float* out  = (float*)d_out;

    prep_kernel<<<(2 * BB * NN * DD) / 256, 256, 0, stream>>>(
        w1, w2, w3, w4, w5, f1, f2, wt8, f1t, f2t, rowfin, cntR);

    dim3 gS(48, 24, BB);
    simb_kernel<<<gS, 256, 0, stream>>>(f1t, f2t, rbm, cbm);

    dim3 gScan((BB * NN) / 256, 2);
    scan_kernel<<<gScan, 256, 0, stream>>>(rbm, cbm, cntR, cntC, listR, listC);

    dim3 gR(BB * 48, RSPLIT, 2);
    refine_kernel<<<gR, 256, 0, stream>>>(f1, f2, cntR, cntC, listR, listC,
                                          rowfin, colfin);

    mlp_mfma_kernel<<<(BB * NN) / 96, 512, 0, stream>>>(
        f1, f2, kp1, kp2, sc1, b1, b2, b3, b4, b5, wt8, rowfin, colfin, out);
}

// Round 14
// 139.851 us; speedup vs baseline: 4.7519x; 1.1231x over previous
//
#include <hip/hip_runtime.h>
#include <cstddef>
#include <cstdint>

#define BB 4
#define NN 6144
#define DD 64
#define HID 512
#define OUTD 64
#define CAP 512
#define RSPLIT 8

typedef unsigned long long ull;
typedef unsigned int u32;
typedef unsigned short u16;
typedef unsigned char u8;
typedef __attribute__((ext_vector_type(8))) short short8_t;
typedef __attribute__((ext_vector_type(4))) float floatx4;

// ---- ws layout (byte offsets) ----
#define OFF_ROWFIN 0
#define OFF_COLFIN 196608
#define OFF_WT     393216
#define OFF_F1T    2162688
#define OFF_F2T    5308416
#define OFF_RBM    8454144
#define OFF_CBM    10813440
#define OFF_CNTR   13172736
#define OFF_CNTC   13173504
#define OFF_LISTR  13174272
#define OFF_LISTC  13567488

#define WT1_OFF 0
#define WT2_OFF 65536
#define WT3_OFF 327680
#define WT4_OFF 589824
#define WT5_OFF 851968
#define WT_TOTAL 884736

__device__ __forceinline__ unsigned int fkey(float v) {
    unsigned int u = __float_as_uint(v);
    return (u & 0x80000000u) ? ~u : (u | 0x80000000u);
}

__device__ __forceinline__ float inv16(u32 k16) {
    u32 u = k16 << 16;
    return (u & 0x80000000u) ? __uint_as_float(u & 0x7fffffffu)
                             : __uint_as_float(~u);
}

__device__ __forceinline__ u16 f2bf(float f) {
    unsigned int u = __float_as_uint(f);
    u += 0x7FFFu + ((u >> 16) & 1u);
    return (u16)(u >> 16);
}

// two floats -> two fp8 (chip-native fp8; self-consistent with fp8 MFMA)
__device__ __forceinline__ u32 f2fp8x2(float a, float b) {
    return (u32)__builtin_amdgcn_cvt_pk_fp8_f32(a, b, 0, false) & 0xffffu;
}

// ---- prep: ws init + weights->fp8 tiled + feats->bf16 tiled ----
__global__ __launch_bounds__(256) void prep_kernel(
    const float* __restrict__ w1, const float* __restrict__ w2,
    const float* __restrict__ w3, const float* __restrict__ w4,
    const float* __restrict__ w5,
    const float* __restrict__ f1, const float* __restrict__ f2,
    u8* __restrict__ wt8, u16* __restrict__ f1t, u16* __restrict__ f2t,
    ull* __restrict__ finals, int* __restrict__ cnts)
{
    int idx = blockIdx.x * 256 + threadIdx.x;

    if (idx < 2 * BB * NN) finals[idx] = 0ULL;
    if (idx < 384) cnts[idx] = 0;

    if (idx < WT_TOTAL) {
        const float* w; u8* o; int K, nsh, li;
        if (idx < 65536)        { w = w1; o = wt8 + WT1_OFF; K = 128; nsh = 9; li = idx; }
        else if (idx < 327680)  { w = w2; o = wt8 + WT2_OFF; K = 512; nsh = 9; li = idx - 65536; }
        else if (idx < 589824)  { w = w3; o = wt8 + WT3_OFF; K = 512; nsh = 9; li = idx - 327680; }
        else if (idx < 851968)  { w = w4; o = wt8 + WT4_OFF; K = 512; nsh = 9; li = idx - 589824; }
        else                    { w = w5; o = wt8 + WT5_OFF; K = 512; nsh = 6; li = idx - 851968; }
        int k = li >> nsh;
        int n = li & ((1 << nsh) - 1);
        u8 v = (u8)(f2fp8x2(w[li], 0.0f) & 0xff);
        int lane = (n & 15) | (((k >> 3) & 3) << 4);
        o[(((size_t)(n >> 4) * (K >> 5) + (k >> 5)) * 64 + lane) * 8 + (k & 7)] = v;
    }

    {
        const int TE = BB * NN * DD;
        const float* src; u16* dst; int e;
        if (idx < TE) { src = f1; dst = f1t; e = idx; }
        else          { src = f2; dst = f2t; e = idx - TE; }
        int k  = e & 63;
        int rn = e >> 6;
        int b  = rn / NN;
        int r  = rn - b * NN;
        int R  = r >> 7, rb = (r >> 4) & 7;
        int kb = k >> 5, lane = (r & 15) | (((k >> 3) & 3) << 4), j = k & 7;
        dst[(size_t)(b * 48 + R) * 8192 + ((rb * 2 + kb) * 64 + lane) * 8 + j] = f2bf(src[e]);
    }
}

// ---- Kernel A: bf16 MFMA sim, 128x128 tile, 4 waves x (32 rows x 128 cols),
//      wave-local row-max, LDS col-merge; TRANSPOSED maxima [b][C][n] ----
__global__ __launch_bounds__(256, 4) void simb_kernel(
    const u16* __restrict__ f1t, const u16* __restrict__ f2t,
    u16* __restrict__ rbm, u16* __restrict__ cbm)
{
    __shared__ __align__(16) u16 sA[8192];
    __shared__ __align__(16) u16 sB[8192];
    __shared__ float cv[4][128];
    const int R = blockIdx.x, C = blockIdx.y, b = blockIdx.z;
    const int t = threadIdx.x, lane = t & 63, w = t >> 6;
    const int l15 = lane & 15, l4 = lane >> 4;

    const u16* Ag = f1t + (size_t)(b * 48 + R) * 8192;
    const u16* Bg = f2t + (size_t)(b * 48 + C) * 8192;

    #pragma unroll
    for (int rnd = 0; rnd < 4; ++rnd) {
        int c = rnd * 256 + t;
        *reinterpret_cast<uint4*>(&sA[c * 8]) = *reinterpret_cast<const uint4*>(Ag + c * 8);
        *reinterpret_cast<uint4*>(&sB[c * 8]) = *reinterpret_cast<const uint4*>(Bg + c * 8);
    }
    __syncthreads();

    floatx4 acc[2][8];
    #pragma unroll
    for (int i = 0; i < 2; ++i)
        #pragma unroll
        for (int j = 0; j < 8; ++j) acc[i][j] = (floatx4)(0.0f);

    #pragma unroll
    for (int kb = 0; kb < 2; ++kb) {
        short8_t afr[2];
        #pragma unroll
        for (int i = 0; i < 2; ++i)
            afr[i] = *reinterpret_cast<const short8_t*>(
                &sA[(((2 * w + i) * 2 + kb) * 64 + lane) * 8]);
        #pragma unroll
        for (int j = 0; j < 8; ++j) {
            short8_t bfr = *reinterpret_cast<const short8_t*>(
                &sB[((j * 2 + kb) * 64 + lane) * 8]);
            #pragma unroll
            for (int i = 0; i < 2; ++i)
                acc[i][j] = __builtin_amdgcn_mfma_f32_16x16x32_bf16(
                    afr[i], bfr, acc[i][j], 0, 0, 0);
        }
    }

    // row-max: fully wave-local (all 128 cols in-wave); 4-shfl over l15
    #pragma unroll
    for (int i = 0; i < 2; ++i) {
        #pragma unroll
        for (int reg = 0; reg < 4; ++reg) {
            float v = acc[i][0][reg];
            #pragma unroll
            for (int j = 1; j < 8; ++j) v = fmaxf(v, acc[i][j][reg]);
            v = fmaxf(v, __shfl_xor(v, 1));
            v = fmaxf(v, __shfl_xor(v, 2));
            v = fmaxf(v, __shfl_xor(v, 4));
            v = fmaxf(v, __shfl_xor(v, 8));
            if (l15 == 0) {
                int row = R * 128 + w * 32 + i * 16 + l4 * 4 + reg;
                rbm[((size_t)b * 48 + C) * NN + row] = (u16)(fkey(v) >> 16);
            }
        }
    }

    // col-max: in-lane over (i,reg), 2-shfl over l4, then 4-wave LDS merge
    #pragma unroll
    for (int j = 0; j < 8; ++j) {
        float v = acc[0][j][0];
        #pragma unroll
        for (int i = 0; i < 2; ++i)
            #pragma unroll
            for (int reg = 0; reg < 4; ++reg) v = fmaxf(v, acc[i][j][reg]);
        v = fmaxf(v, __shfl_xor(v, 16));
        v = fmaxf(v, __shfl_xor(v, 32));
        if (l4 == 0) cv[w][j * 16 + l15] = v;
    }
    __syncthreads();
    if (t < 128) {
        float v = fmaxf(fmaxf(cv[0][t], cv[1][t]), fmaxf(cv[2][t], cv[3][t]));
        cbm[((size_t)b * 48 + R) * NN + C * 128 + t] = (u16)(fkey(v) >> 16);
    }
}

// ---- scan (merged row/col via blockIdx.y): transposed bm reads,
//      block-aggregated candidate append ----
__global__ __launch_bounds__(256) void scan_kernel(
    const u16* __restrict__ rbm, const u16* __restrict__ cbm,
    int* __restrict__ cntR, int* __restrict__ cntC,
    int* __restrict__ listR, int* __restrict__ listC)
{
    const u16* bm = blockIdx.y ? cbm : rbm;
    int* cnt  = blockIdx.y ? cntC : cntR;
    int* list = blockIdx.y ? listC : listR;

    __shared__ int lcnt[48];
    __shared__ int lbase[48];
    const int t = threadIdx.x;
    if (t < 48) lcnt[t] = 0;
    const int idx = blockIdx.x * 256 + t;
    const int b = (blockIdx.x * 256) / NN;
    const int n = idx - b * NN;

    u16 ks[48];
    #pragma unroll
    for (int c = 0; c < 48; ++c)
        ks[c] = bm[((size_t)b * 48 + c) * NN + n];

    u16 mx = 0;
    #pragma unroll
    for (int c = 0; c < 48; ++c) mx = ks[c] > mx ? ks[c] : mx;
    // margin: worst-case bf16 sim error |S~-S| <= 2^-8 * sum|a_k b_k| <= 0.0039
    // (round-to-nearest f2bf, unit vectors); listing the true block needs
    // margin >= 2*0.0039 = 0.0078; 0.010 gives 28% cushion.
    float thr = inv16(mx) - 0.010f;
    u32 m0 = 0, m1 = 0;
    #pragma unroll
    for (int c = 0; c < 48; ++c) {
        if (inv16((u32)ks[c] + 1) >= thr) {
            if (c < 32) m0 |= 1u << c; else m1 |= 1u << (c - 32);
        }
    }
    __syncthreads();
    {
        u32 a = m0;
        while (a) { int c = __builtin_ctz(a); a &= a - 1; atomicAdd(&lcnt[c], 1); }
        a = m1;
        while (a) { int c = 32 + __builtin_ctz(a); a &= a - 1; atomicAdd(&lcnt[c], 1); }
    }
    __syncthreads();
    if (t < 48) { lbase[t] = atomicAdd(&cnt[b * 48 + t], lcnt[t]); lcnt[t] = 0; }
    __syncthreads();
    {
        u32 a = m0;
        while (a) {
            int c = __builtin_ctz(a); a &= a - 1;
            int pos = lbase[c] + atomicAdd(&lcnt[c], 1);
            if (pos < CAP) list[(b * 48 + c) * CAP + pos] = n;
        }
        a = m1;
        while (a) {
            int c = 32 + __builtin_ctz(a); a &= a - 1;
            int pos = lbase[c] + atomicAdd(&lcnt[c], 1);
            if (pos < CAP) list[(b * 48 + c) * CAP + pos] = n;
        }
    }
}

// ---- exact fp32 refine (merged row/col via blockIdx.z), LDS-staged queries ----
__global__ __launch_bounds__(256, 2) void refine_kernel(
    const float* __restrict__ f1, const float* __restrict__ f2,
    const int* __restrict__ cntR, const int* __restrict__ cntC,
    const int* __restrict__ listR, const int* __restrict__ listC,
    ull* __restrict__ rowfin, ull* __restrict__ colfin)
{
    const float* qfeat = blockIdx.z ? f2 : f1;
    const float* tfeat = blockIdx.z ? f1 : f2;
    const int* cnt  = blockIdx.z ? cntC : cntR;
    const int* list = blockIdx.z ? listC : listR;
    ull* fin = blockIdx.z ? colfin : rowfin;

    const int b = blockIdx.x / 48;
    const int C = blockIdx.x - b * 48;
    const int sub = blockIdx.y;
    int n_items = cnt[b * 48 + C];
    if (n_items > CAP) n_items = CAP;
    int chunk = (n_items + RSPLIT - 1) / RSPLIT;
    int lo = sub * chunk;
    int hi = lo + chunk; if (hi > n_items) hi = n_items;
    if (lo >= hi) return;

    __shared__ float s2f[128 * 68];
    __shared__ float sq[16 * 68];
    const int t = threadIdx.x;
    const float* tb = tfeat + ((size_t)b * NN + C * 128) * 64;
    #pragma unroll
    for (int p = 0; p < 8; ++p) {
        int idx = p * 256 + t;
        int row = idx >> 4, c4 = idx & 15;
        *reinterpret_cast<float4*>(&s2f[row * 68 + c4 * 4]) =
            *reinterpret_cast<const float4*>(tb + row * 64 + c4 * 4);
    }
    __syncthreads();
    const int rs = t >> 4, cg = t & 15;
    const int* mylist = list + (b * 48 + C) * CAP;
    for (int base = lo; base < hi; base += 16) {
        // stage 16 query rows (coalesced; one float4 per thread)
        {
            int lq = base + rs;
            int nn = (lq < hi) ? mylist[lq] : mylist[lo];
            *reinterpret_cast<float4*>(&sq[rs * 68 + cg * 4]) =
                *reinterpret_cast<const float4*>(qfeat + ((size_t)b * NN + nn) * 64 + cg * 4);
        }
        __syncthreads();

        int li = base + rs;
        bool valid = li < hi;
        int n = valid ? mylist[li] : mylist[lo];
        float dot[8];
        #pragma unroll
        for (int c8 = 0; c8 < 8; ++c8) dot[c8] = 0.0f;
        #pragma unroll 4
        for (int kq = 0; kq < 16; ++kq) {
            float4 a4 = *reinterpret_cast<const float4*>(&sq[rs * 68 + kq * 4]);
            #pragma unroll
            for (int c8 = 0; c8 < 8; ++c8) {
                float4 s4 = *reinterpret_cast<const float4*>(&s2f[(cg + 16 * c8) * 68 + kq * 4]);
                dot[c8] = fmaf(a4.x, s4.x, dot[c8]);
                dot[c8] = fmaf(a4.y, s4.y, dot[c8]);
                dot[c8] = fmaf(a4.z, s4.z, dot[c8]);
                dot[c8] = fmaf(a4.w, s4.w, dot[c8]);
            }
        }
        float bv = dot[0]; int bc = cg;
        #pragma unroll
        for (int c8 = 1; c8 < 8; ++c8) {
            if (dot[c8] > bv) { bv = dot[c8]; bc = cg + 16 * c8; }
        }
        ull pk = ((ull)fkey(bv) << 32) | (u32)(~(u32)(C * 128 + bc));
        ull qq;
        qq = __shfl_xor(pk, 1); pk = pk > qq ? pk : qq;
        qq = __shfl_xor(pk, 2); pk = pk > qq ? pk : qq;
        qq = __shfl_xor(pk, 4); pk = pk > qq ? pk : qq;
        qq = __shfl_xor(pk, 8); pk = pk > qq ? pk : qq;
        if (cg == 0 && valid) atomicMax(&fin[(size_t)b * NN + n], pk);
        __syncthreads();   // protect sq before next stage
    }
}

// ---- Kernel B: fp8 MFMA MLP, 96 pts/block, grid=256 (1 block/CU),
//      512 thr / 8 waves, 64ch/wave, stagger + setprio + 3-buf prefetch ----

#define MLP_STEP(BUF, KB)                                                        \
    {                                                                            \
        const int kb2 = ((KB) + woff) & (NKB - 1);                               \
        __builtin_amdgcn_s_setprio(1);                                           \
        _Pragma("unroll")                                                        \
        for (int jb = 0; jb < 6; ++jb) {                                         \
            const int pt = jb * 16 + l15;                                        \
            const int sp = (kb2 * 4 + l4) ^ (pt & 7);                            \
            long bfr = *reinterpret_cast<const long*>(act + pt * 512 + sp * 8);  \
            _Pragma("unroll")                                                    \
            for (int ia = 0; ia < 4; ++ia)                                       \
                acc[ia][jb] = __builtin_amdgcn_mfma_f32_16x16x32_fp8_fp8(        \
                    BUF[ia], bfr, acc[ia][jb], 0, 0, 0);                         \
        }                                                                        \
        __builtin_amdgcn_s_setprio(0);                                           \
        if ((KB) + 3 < NKB) {                                                    \
            const int kbp = ((KB) + 3 + woff) & (NKB - 1);                       \
            _Pragma("unroll")                                                    \
            for (int ia = 0; ia < 4; ++ia)                                       \
                BUF[ia] = *reinterpret_cast<const long*>(                        \
                    wt8 + (((size_t)(chBlk0 + ia) * NKB + kbp) * 64 + lane) * 8);\
        }                                                                        \
    }

template<int K>
__device__ __forceinline__ void mlp_layer8(
    u8* act, const u8* __restrict__ wt8,
    const float* __restrict__ bias, int lane, int wid)
{
    constexpr int NKB = K / 32;
    floatx4 acc[4][6];
    #pragma unroll
    for (int ia = 0; ia < 4; ++ia)
        #pragma unroll
        for (int jb = 0; jb < 6; ++jb)
            acc[ia][jb] = (floatx4)(0.0f);

    const int l15 = lane & 15, l4 = lane >> 4;
    const int chBlk0 = wid * 4;               // (wid*64)/16
    const int woff = (wid * 2) & (NKB - 1);   // per-wave kb stagger

    long a0[4], a1[4], a2[4];
    #pragma unroll
    for (int ia = 0; ia < 4; ++ia)
        a0[ia] = *reinterpret_cast<const long*>(
            wt8 + (((size_t)(chBlk0 + ia) * NKB + ((0 + woff) & (NKB - 1))) * 64 + lane) * 8);
    #pragma unroll
    for (int ia = 0; ia < 4; ++ia)
        a1[ia] = *reinterpret_cast<const long*>(
            wt8 + (((size_t)(chBlk0 + ia) * NKB + ((1 + woff) & (NKB - 1))) * 64 + lane) * 8);
    #pragma unroll
    for (int ia = 0; ia < 4; ++ia)
        a2[ia] = *reinterpret_cast<const long*>(
            wt8 + (((size_t)(chBlk0 + ia) * NKB + ((2 + woff) & (NKB - 1))) * 64 + lane) * 8);

    #pragma unroll
    for (int kb = 0; kb < NKB; ++kb) {
        if ((kb % 3) == 0)      MLP_STEP(a0, kb)
        else if ((kb % 3) == 1) MLP_STEP(a1, kb)
        else                    MLP_STEP(a2, kb)
    }
    __syncthreads();   // all reads done before in-place overwrite

    const int ch0 = wid * 64;
    #pragma unroll
    for (int ia = 0; ia < 4; ++ia) {
        int cb = ia * 16 + l4 * 4;
        float4 bv = *reinterpret_cast<const float4*>(bias + ch0 + cb);
        #pragma unroll
        for (int jb = 0; jb < 6; ++jb) {
            int pt = jb * 16 + l15;
            u32 pk0 = f2fp8x2(fmaxf(acc[ia][jb][0] + bv.x, 0.0f),
                              fmaxf(acc[ia][jb][1] + bv.y, 0.0f));
            u32 pk1 = f2fp8x2(fmaxf(acc[ia][jb][2] + bv.z, 0.0f),
                              fmaxf(acc[ia][jb][3] + bv.w, 0.0f));
            u32 word = pk0 | (pk1 << 16);
            int s = (ch0 + cb) >> 3;
            int sp = s ^ (pt & 7);
            *reinterpret_cast<u32*>(act + pt * 512 + sp * 8 + (cb & 4)) = word;
        }
    }
    __syncthreads();
}

__global__ __launch_bounds__(512, 2) void mlp_mfma_kernel(
    const float* __restrict__ f1, const float* __restrict__ f2,
    const float* __restrict__ kps1, const float* __restrict__ kps2,
    const float* __restrict__ scales1,
    const float* __restrict__ b1, const float* __restrict__ b2,
    const float* __restrict__ b3, const float* __restrict__ b4,
    const float* __restrict__ b5,
    const u8* __restrict__ wt8,
    const ull* __restrict__ rowfin, const ull* __restrict__ colfin,
    float* __restrict__ out)
{
    __shared__ __align__(16) unsigned char lds_raw[49152];   // 96 pts x 512 ch fp8
    u8* act = lds_raw;
    float* logf = reinterpret_cast<float*>(lds_raw);

    const int t = threadIdx.x;
    const int lane = t & 63, wid = t >> 6;
    const int base = blockIdx.x * 96;
    const int b = base / NN;
    const int n0 = base % NN;

    // stage concat(f1[n], f2[match12[n]]) as fp8, swizzled; 384 active threads
    if (t < 384) {
        const int pt = t >> 2, seg = t & 3;   // 4 segs * 32 dims
        const int n = n0 + pt;
        ull rm = rowfin[(size_t)b * NN + n];
        const int m = (int)(~(u32)(rm & 0xffffffffULL));
        const float* src = (seg < 2)
            ? (f1 + ((size_t)b * NN + n) * DD + seg * 32)
            : (f2 + ((size_t)b * NN + m) * DD + (seg - 2) * 32);
        #pragma unroll
        for (int q8 = 0; q8 < 4; ++q8) {
            float4 v0 = *reinterpret_cast<const float4*>(src + q8 * 8);
            float4 v1 = *reinterpret_cast<const float4*>(src + q8 * 8 + 4);
            ull w64 = (ull)f2fp8x2(v0.x, v0.y)
                    | ((ull)f2fp8x2(v0.z, v0.w) << 16)
                    | ((ull)f2fp8x2(v1.x, v1.y) << 32)
                    | ((ull)f2fp8x2(v1.z, v1.w) << 48);
            int s = seg * 4 + q8;
            int sp = s ^ (pt & 7);
            *reinterpret_cast<ull*>(act + pt * 512 + sp * 8) = w64;
        }
    }
    __syncthreads();

    mlp_layer8<128>(act, wt8 + WT1_OFF, b1, lane, wid);
    mlp_layer8<512>(act, wt8 + WT2_OFF, b2, lane, wid);
    mlp_layer8<512>(act, wt8 + WT3_OFF, b3, lane, wid);
    mlp_layer8<512>(act, wt8 + WT4_OFF, b4, lane, wid);

    // layer 5: 512 -> 64, no relu; waves 0-3 handle 16 out-ch each (staggered)
    {
        const int l15 = lane & 15, l4 = lane >> 4;
        floatx4 acc5[6];
        #pragma unroll
        for (int jb = 0; jb < 6; ++jb) acc5[jb] = (floatx4)(0.0f);
        if (wid < 4) {
            const int woff5 = (wid * 4) & 15;
            long a_cur = *reinterpret_cast<const long*>(
                wt8 + WT5_OFF + (((size_t)wid * 16 + woff5) * 64 + lane) * 8);
            long a_nxt;
            #pragma unroll
            for (int kb = 0; kb < 16; ++kb) {
                const int kb2 = (kb + woff5) & 15;
                if (kb + 1 < 16) {
                    const int kbn = (kb + 1 + woff5) & 15;
                    a_nxt = *reinterpret_cast<const long*>(
                        wt8 + WT5_OFF + (((size_t)wid * 16 + kbn) * 64 + lane) * 8);
                }
                __builtin_amdgcn_s_setprio(1);
                #pragma unroll
                for (int jb = 0; jb < 6; ++jb) {
                    const int pt = jb * 16 + l15;
                    const int sp = (kb2 * 4 + l4) ^ (pt & 7);
                    long bfr = *reinterpret_cast<const long*>(act + pt * 512 + sp * 8);
                    acc5[jb] = __builtin_amdgcn_mfma_f32_16x16x32_fp8_fp8(
                        a_cur, bfr, acc5[jb], 0, 0, 0);
                }
                __builtin_amdgcn_s_setprio(0);
                if (kb + 1 < 16) a_cur = a_nxt;
            }
        }
        __syncthreads();   // all act reads done; lds_raw becomes logits f32
        if (wid < 4) {
            int cb = wid * 16 + l4 * 4;
            float4 bv = *reinterpret_cast<const float4*>(b5 + cb);
            #pragma unroll
            for (int jb = 0; jb < 6; ++jb) {
                int pt = jb * 16 + l15;
                float4 o;
                o.x = acc5[jb][0] + bv.x;
                o.y = acc5[jb][1] + bv.y;
                o.z = acc5[jb][2] + bv.z;
                o.w = acc5[jb][3] + bv.w;
                *reinterpret_cast<float4*>(&logf[pt * 68 + cb]) = o;
            }
        }
        __syncthreads();
    }

    if (t < 96) {
        const int pt = t;
        const int n = n0 + pt;
        const float* lrow = &logf[pt * 68];
        float mx = -1e30f;
        #pragma unroll 8
        for (int j = 0; j < OUTD; ++j) mx = fmaxf(mx, 3.0f * lrow[j]);
        float s = 0.0f, cx = 0.0f, cy = 0.0f;
        #pragma unroll 8
        for (int j = 0; j < OUTD; ++j) {
            float e = __expf(3.0f * lrow[j] - mx);
            s  += e;
            cx += e * (float)((j & 7) - 4);
            cy += e * (float)((j >> 3) - 4);
        }
        float conf = 1.0f / s;
        cx /= s; cy /= s;
        ull rm = rowfin[(size_t)b * NN + n];
        int m = (int)(~(u32)(rm & 0xffffffffULL));
        ull cm = colfin[(size_t)b * NN + m];
        int back = (int)(~(u32)(cm & 0xffffffffULL));
        bool mutual = (back == n);
        float sc = scales1[(size_t)b * NN + n];
        float x0 = kps1[((size_t)b * NN + n) * 2 + 0] + cx * sc;
        float y0 = kps1[((size_t)b * NN + n) * 2 + 1] + cy * sc;
        float x1 = kps2[((size_t)b * NN + m) * 2 + 0];
        float y1 = kps2[((size_t)b * NN + m) * 2 + 1];
        float* mt = out + ((size_t)b * NN + n) * 4;
        mt[0] = x0; mt[1] = y0; mt[2] = x1; mt[3] = y1;
        out[(size_t)BB * NN * 4 + (size_t)b * NN + n] =
            (mutual && conf > 0.25f) ? 1.0f : 0.0f;
    }
}

extern "C" void kernel_launch(void* const* d_in, const int* in_sizes, int n_in,
                              void* d_out, int out_size, void* d_ws, size_t ws_size,
                              hipStream_t stream)
{
    const float* f1  = (const float*)d_in[0];
    const float* f2  = (const float*)d_in[1];
    const float* kp1 = (const float*)d_in[2];
    const float* kp2 = (const float*)d_in[3];
    const float* sc1 = (const float*)d_in[4];
    const float* w1  = (const float*)d_in[5];
    const float* b1  = (const float*)d_in[6];
    const float* w2  = (const float*)d_in[7];
    const float* b2  = (const float*)d_in[8];
    const float* w3  = (const float*)d_in[9];
    const float* b3  = (const float*)d_in[10];
    const float* w4  = (const float*)d_in[11];
    const float* b4  = (const float*)d_in[12];
    const float* w5  = (const float*)d_in[13];
    const float* b5  = (const float*)d_in[14];

    char* ws = (char*)d_ws;
    ull* rowfin = (ull*)(ws + OFF_ROWFIN);
    ull* colfin = (ull*)(ws + OFF_COLFIN);
    u8*  wt8    = (u8*)(ws + OFF_WT);
    u16* f1t    = (u16*)(ws + OFF_F1T);
    u16* f2t    = (u16*)(ws + OFF_F2T);
    u16* rbm    = (u16*)(ws + OFF_RBM);
    u16* cbm    = (u16*)(ws + OFF_CBM);
    int* cntR   = (int*)(ws + OFF_CNTR);
    int* cntC   = (int*)(ws + OFF_CNTC);
    int* listR  = (int*)(ws + OFF_LISTR);
    int* listC  = (int*)(ws + OFF_LISTC);
    float* out  = (float*)d_out;

    prep_kernel<<<(2 * BB * NN * DD) / 256, 256, 0, stream>>>(
        w1, w2, w3, w4, w5, f1, f2, wt8, f1t, f2t, rowfin, cntR);

    dim3 gS(48, 48, BB);
    simb_kernel<<<gS, 256, 0, stream>>>(f1t, f2t, rbm, cbm);

    dim3 gScan((BB * NN) / 256, 2);
    scan_kernel<<<gScan, 256, 0, stream>>>(rbm, cbm, cntR, cntC, listR, listC);

    dim3 gR(BB * 48, RSPLIT, 2);
    refine_kernel<<<gR, 256, 0, stream>>>(f1, f2, cntR, cntC, listR, listC,
                                          rowfin, colfin);

    mlp_mfma_kernel<<<(BB * NN) / 96, 512, 0, stream>>>(
        f1, f2, kp1, kp2, sc1, b1, b2, b3, b4, b5, wt8, rowfin, colfin, out);
}